// Round 4
// baseline (184.796 us; speedup 1.0000x reference)
//
#include <hip/hip_runtime.h>
#include <math.h>

#define LQ 4096
#define DD 512
#define NH 8
#define HS 64
#define HALF 32

typedef unsigned short u16;
typedef unsigned int u32;
typedef __attribute__((ext_vector_type(8)))  short s8v;   // 8 x bf16 (MFMA A/B frag)
typedef __attribute__((ext_vector_type(4)))  float f4v;
typedef __attribute__((ext_vector_type(4)))  u32  u32x4;
typedef __attribute__((ext_vector_type(16))) float f16v;  // 32x32 MFMA C/D

// workspace offsets (in floats)
#define WS_QH   0u          // later reused as gg_hi
#define WS_QL   1048576u    // later reused as gg_lo
#define WS_KH   2097152u
#define WS_KL   3145728u
#define WS_VT   4194304u
#define WS_XH   5242880u    // later reused as ret (spans XH+XL = 2097152 floats)
#define WS_XL   6291456u
#define WS_WTH  7340032u
#define WS_WTL  7995392u
#define WS_GATE 8650752u
#define WS_TAB  10747904u   // 524288 floats; first 4 bytes reused as task counter after k_fused

__device__ inline u16 f2bf(float x) {
    unsigned int u = __float_as_uint(x);
    return (u16)((u + 0x7fffu + ((u >> 16) & 1u)) >> 16);
}
__device__ inline float bf2f(u16 h) { return __uint_as_float(((unsigned int)h) << 16); }

__device__ __forceinline__ void gld16(void* lds, const void* g) {
    __builtin_amdgcn_global_load_lds(
        (const __attribute__((address_space(1))) void*)g,
        (__attribute__((address_space(3))) void*)lds, 16, 0, 0);
}

// ---------------- xPos tables ----------------
__global__ __launch_bounds__(256) void k_tables(float* __restrict__ tab) {
    int idx = blockIdx.x * 256 + threadIdx.x;
    if (idx >= LQ * HALF) return;
    int l = idx >> 5;
    int i = idx & 31;
    double sv  = (2.0 * i + 0.4 * (double)HS) / (1.4 * (double)HS);
    double s   = pow(sv, (double)l / 512.0);
    double invf = pow(10000.0, -(double)i / (double)HALF);
    double th  = (double)l * invf;
    double c = cos(th), sn = sin(th);
    tab[idx]                 = (float)(c * s);
    tab[LQ*HALF + idx]       = (float)(sn * s);
    tab[2*LQ*HALF + idx]     = (float)(c / s);
    tab[3*LQ*HALF + idx]     = (float)(sn / s);
}

// ---------------- weight transpose-pack ----------------
__global__ __launch_bounds__(256) void k_prep(
    const float* __restrict__ Wq, const float* __restrict__ Wk, const float* __restrict__ Wv,
    const float* __restrict__ Wg, const float* __restrict__ Wo,
    u16* __restrict__ Wth, u16* __restrict__ Wtl) {
    __shared__ float tile[32][33];
    const int t = threadIdx.x;
    const int d0 = blockIdx.x * 32;
    const int C0 = blockIdx.y * 32;
    const int proj = C0 >> 9;
    const int tc = t & 31;
    const int tr = t >> 5;
#pragma unroll
    for (int rr = 0; rr < 4; ++rr) {
        int dl = tr + rr * 8;
        int d = d0 + dl;
        int C = C0 + tc;
        float val;
        if (proj < 3) {
            const float* W = (proj == 0) ? Wq : ((proj == 1) ? Wk : Wv);
            int h = (C & 511) >> 6, hs = C & 63;
            val = W[(size_t)h * (DD * HS) + (size_t)d * HS + hs];
        } else if (proj == 3) {
            val = Wg[(size_t)d * DD + (C & 511)];
        } else {
            val = Wo[(size_t)d * DD + (C - 2048)];
        }
        tile[dl][tc] = val;
    }
    __syncthreads();
#pragma unroll
    for (int rr = 0; rr < 4; ++rr) {
        int cl = tr + rr * 8;
        float val = tile[tc][cl];
        u16 hb = f2bf(val);
        size_t o = (size_t)(C0 + cl) * DD + d0 + tc;
        Wth[o] = hb;
        Wtl[o] = f2bf(val - bf2f(hb));
    }
}

// ---------------- X -> hi/lo bf16 ----------------
__global__ __launch_bounds__(256) void k_packx(const float* __restrict__ X,
                                               u16* __restrict__ Xh, u16* __restrict__ Xl) {
    int idx = (blockIdx.x * 256 + threadIdx.x) * 4;
    f4v x = *(const f4v*)(X + idx);
    unsigned int h[4], l[4];
#pragma unroll
    for (int j = 0; j < 4; ++j) {
        u16 hb = f2bf(x[j]);
        h[j] = hb;
        l[j] = f2bf(x[j] - bf2f(hb));
    }
    uint2 ph, pl;
    ph.x = h[0] | (h[1] << 16); ph.y = h[2] | (h[3] << 16);
    pl.x = l[0] | (l[1] << 16); pl.y = l[2] | (l[3] << 16);
    *(uint2*)((void*)(Xh + idx)) = ph;
    *(uint2*)((void*)(Xl + idx)) = pl;
}

// ---------------- fused MFMA GEMM: X @ [Wq|Wk|Wv|Wg] ----------------
__global__ __launch_bounds__(256) void k_fused(
    const u16* __restrict__ Xh, const u16* __restrict__ Xl,
    const u16* __restrict__ Wth, const u16* __restrict__ Wtl,
    const float* __restrict__ tab,
    u16* __restrict__ qh, u16* __restrict__ ql,
    u16* __restrict__ kh, u16* __restrict__ kl,
    u16* __restrict__ vt, float* __restrict__ gate) {
    __shared__ __align__(16) char smem[49152];
    char* sAH = smem;
    char* sAL = smem + 16384;
    char* sBH = smem + 32768;
    char* sBL = smem + 40960;
    const int t = threadIdx.x;
    const int l0 = blockIdx.x * 128;
    const int c0 = blockIdx.y * 64;
    const int wv = t >> 6;
    const int lane = t & 63;
    const int c31 = lane & 31;
    const int hi = lane >> 5;

    f16v acc0, acc1;
#pragma unroll
    for (int i = 0; i < 16; ++i) { acc0[i] = 0.f; acc1[i] = 0.f; }

    for (int kt = 0; kt < 8; ++kt) {
#pragma unroll
        for (int it = 0; it < 4; ++it) {
            int o = t * 16 + it * 4096;
            int row = o >> 7, cb = o & 127;
            int sw = o ^ ((row & 7) << 4);
            size_t g = (size_t)(l0 + row) * 1024 + kt * 128 + cb;
            *(s8v*)(sAH + sw) = *(const s8v*)((const char*)Xh + g);
            *(s8v*)(sAL + sw) = *(const s8v*)((const char*)Xl + g);
        }
#pragma unroll
        for (int it = 0; it < 2; ++it) {
            int o = t * 16 + it * 4096;
            int row = o >> 7, cb = o & 127;
            int sw = o ^ ((row & 7) << 4);
            size_t g = (size_t)(c0 + row) * 1024 + kt * 128 + cb;
            *(s8v*)(sBH + sw) = *(const s8v*)((const char*)Wth + g);
            *(s8v*)(sBL + sw) = *(const s8v*)((const char*)Wtl + g);
        }
        __syncthreads();

        const int arow = wv * 32 + c31;
        const int aswz = (arow & 7) << 4;
        s8v ah[4], al[4];
#pragma unroll
        for (int ks = 0; ks < 4; ++ks) {
            int cb = (ks * 32 + hi * 16) ^ aswz;
            ah[ks] = *(const s8v*)(sAH + arow * 128 + cb);
            al[ks] = *(const s8v*)(sAL + arow * 128 + cb);
        }
#define DO_N(NN, ACC)                                                              \
        {                                                                          \
            int brow = NN * 32 + c31;                                              \
            int bswz = (brow & 7) << 4;                                            \
            _Pragma("unroll")                                                      \
            for (int ks = 0; ks < 4; ++ks) {                                       \
                int cb = (ks * 32 + hi * 16) ^ bswz;                               \
                s8v bh = *(const s8v*)(sBH + brow * 128 + cb);                     \
                s8v bl = *(const s8v*)(sBL + brow * 128 + cb);                     \
                ACC = __builtin_amdgcn_mfma_f32_32x32x16_bf16(ah[ks], bh, ACC, 0, 0, 0); \
                ACC = __builtin_amdgcn_mfma_f32_32x32x16_bf16(ah[ks], bl, ACC, 0, 0, 0); \
                ACC = __builtin_amdgcn_mfma_f32_32x32x16_bf16(al[ks], bh, ACC, 0, 0, 0); \
            }                                                                      \
        }
        DO_N(0, acc0)
        DO_N(1, acc1)
#undef DO_N
        __syncthreads();
    }

    const int proj = c0 >> 9;
    if (proj < 2) {
        const float* ct = tab + (proj ? 2 * LQ * HALF : 0);
        const float* st = tab + (proj ? 3 * LQ * HALF : LQ * HALF);
        u16* oh = proj ? kh : qh;
        u16* ol = proj ? kl : ql;
#pragma unroll
        for (int n = 0; n < 2; ++n) {
            const f16v acc = n ? acc1 : acc0;
            int C = c0 + n * 32 + c31;
            int h = (C & 511) >> 6, hs = C & 63, i2 = hs >> 1;
            float sgn = (hs & 1) ? 1.f : -1.f;
#pragma unroll
            for (int r = 0; r < 16; ++r) {
                int lrow = wv * 32 + (r & 3) + 8 * (r >> 2) + 4 * hi;
                int pos = l0 + lrow;
                float val = acc[r];
                float part = __shfl_xor(val, 1);
                float res = val * ct[pos * HALF + i2] + sgn * part * st[pos * HALF + i2];
                u16 hb = f2bf(res);
                size_t o = ((size_t)h * LQ + pos) * HS + hs;
                oh[o] = hb;
                ol[o] = f2bf(res - bf2f(hb));
            }
        }
    } else if (proj == 2) {
        __syncthreads();
        float* vbuf = (float*)smem;
#pragma unroll
        for (int n = 0; n < 2; ++n) {
            const f16v acc = n ? acc1 : acc0;
            int cl = n * 32 + c31;
#pragma unroll
            for (int r = 0; r < 16; ++r) {
                int lrow = wv * 32 + (r & 3) + 8 * (r >> 2) + 4 * hi;
                vbuf[cl * 129 + lrow] = acc[r];
            }
        }
        __syncthreads();
        int h = (c0 & 511) >> 6;
        int cl = t >> 2, lseg = (t & 3) * 32;
        size_t o = ((size_t)h * HS + cl) * LQ + l0 + lseg;
#pragma unroll
        for (int ch = 0; ch < 4; ++ch) {
            s8v pk;
#pragma unroll
            for (int j = 0; j < 8; ++j) pk[j] = (short)f2bf(vbuf[cl * 129 + lseg + ch * 8 + j]);
            *(s8v*)(vt + o + ch * 8) = pk;
        }
    } else {
#pragma unroll
        for (int n = 0; n < 2; ++n) {
            const f16v acc = n ? acc1 : acc0;
            int C = (c0 & 511) + n * 32 + c31;
#pragma unroll
            for (int r = 0; r < 16; ++r) {
                int lrow = wv * 32 + (r & 3) + 8 * (r >> 2) + 4 * hi;
                float vv = acc[r];
                gate[(size_t)(l0 + lrow) * DD + C] = vv / (1.f + expf(-vv));
            }
        }
    }
}

// ---------------- retention: pipelined MFMA flash with decay ----------------
// grid 512 blocks x 128 threads (2 waves). Dynamic task queue: 768 tasks.
// tau < 512: split tasks  qb = 63-(tau>>4) in [32,63], h = (tau>>1)&7, sub = tau&1
// tau >= 512: single tasks qb = 31-((tau-512)>>3), h = tau&7
// sub==1 writes partial O to `part` (= d_out scratch); k_gn adds it for l >= 2048.
__global__ __launch_bounds__(128) void k_ret(
    const u16* __restrict__ qh, const u16* __restrict__ ql,
    const u16* __restrict__ kh, const u16* __restrict__ kl,
    const u16* __restrict__ vt, float* __restrict__ ret,
    float* __restrict__ part, int* __restrict__ cnt) {
    __shared__ __align__(16) char sBuf[2][24576];   // [buf][KH 8K | KL 8K | VT 8K]
    __shared__ int s_task;
    const int t = threadIdx.x;
    const int wv = t >> 6;
    const int lane = t & 63;
    const int c31 = lane & 31;
    const int hi = lane >> 5;

    for (;;) {
        __syncthreads();
        if (t == 0) s_task = atomicAdd(cnt, 1);
        __syncthreads();
        const int tau = s_task;
        if (tau >= 768) return;

        int h, qb, sub;
        if (tau < 512) { qb = 63 - (tau >> 4); h = (tau >> 1) & 7; sub = tau & 1; }
        else           { int u = tau - 512; qb = 31 - (u >> 3); h = u & 7; sub = -1; }

        double lg = -3.4657359027997265 + (double)h * (-2.772588722239781 / 7.0);
        double gamma = 1.0 - exp(lg);
        float lgf = (float)(log(gamma) * 1.4426950408889634);
        float c1a[4], c8a[4];
#pragma unroll
        for (int m = 0; m < 4; ++m) { c1a[m] = exp2f(-lgf * (float)m); c8a[m] = exp2f(-lgf * (float)(8 * m)); }

        const int l0q = qb * 64;
        float dcut = -80.f / lgf;
        int kmin = (int)floorf(((float)(l0q - 63) - dcut) * (1.f / 64.f));
        if (kmin < 0) kmin = 0;
        int kb0 = kmin, kb1 = qb;
        if (sub >= 0) {
            int n = qb - kmin + 1, nA = n >> 1;
            if (sub == 0) kb1 = kmin + nA - 1; else kb0 = kmin + nA;
        }

        // Q fragments (B-operand)
        s8v qhf[4], qlf[4];
        {
            const u16* qph = qh + ((size_t)h * LQ + l0q + wv * 32 + c31) * HS + hi * 8;
            const u16* qpl = ql + ((size_t)h * LQ + l0q + wv * 32 + c31) * HS + hi * 8;
#pragma unroll
            for (int ks = 0; ks < 4; ++ks) {
                qhf[ks] = *(const s8v*)(qph + ks * 16);
                qlf[ks] = *(const s8v*)(qpl + ks * 16);
            }
        }

        f16v acc0, acc1;
#pragma unroll
        for (int i = 0; i < 16; ++i) { acc0[i] = 0.f; acc1[i] = 0.f; }

        const char* gKHb = (const char*)kh + ((size_t)h * LQ) * 128;
        const char* gKLb = (const char*)kl + ((size_t)h * LQ) * 128;
        const char* gVTb = (const char*)vt + ((size_t)h * 64) * 8192;

        // ---- staging: 12 x 16B gload_lds per thread, pre-swizzled source, linear LDS ----
#define STAGE(KB, B)                                                                   \
        {                                                                              \
            const char* bKH = gKHb + (size_t)(KB) * 8192;                              \
            const char* bKL = gKLb + (size_t)(KB) * 8192;                              \
            const char* bVT = gVTb + (size_t)(KB) * 128;                               \
            char* lb = &sBuf[B][wv * 12288];                                           \
            _Pragma("unroll")                                                          \
            for (int i_ = 0; i_ < 12; ++i_) {                                          \
                int boff = wv * 12288 + i_ * 1024 + lane * 16;                         \
                int seg = boff >> 13;                                                  \
                int o_ = boff & 8191;                                                  \
                int osrc = o_ ^ (((o_ >> 7) & 7) << 4);                                \
                const char* src = (seg == 0) ? bKH + osrc                              \
                                : (seg == 1) ? bKL + osrc                              \
                                : bVT + (size_t)(osrc >> 7) * 8192 + (osrc & 127);     \
                gld16(lb + i_ * 1024, src);                                            \
            }                                                                          \
        }

        STAGE(kb0, 0);
        int cur = 0;
        for (int kb = kb0; kb <= kb1; ++kb) {
            if (kb < kb1) {
                STAGE(kb + 1, cur ^ 1);
                asm volatile("s_waitcnt vmcnt(12)" ::: "memory");
            } else {
                asm volatile("s_waitcnt vmcnt(0)" ::: "memory");
            }
            __builtin_amdgcn_s_barrier();
            __builtin_amdgcn_sched_barrier(0);

            const char* bKH = sBuf[cur];
            const char* bKL = sBuf[cur] + 8192;
            const char* bVT = sBuf[cur] + 16384;
            const bool diag = (kb == qb);

#pragma unroll
            for (int jt = 0; jt < 2; ++jt) {
                if (diag && (wv * 32 + 31) < jt * 32) break;   // fully-masked strip on diag
                f16v sacc;
#pragma unroll
                for (int i = 0; i < 16; ++i) sacc[i] = 0.f;
#pragma unroll
                for (int ks = 0; ks < 4; ++ks) {
                    int krow = jt * 32 + c31;
                    int ph = krow * 128 + ((ks * 32 + hi * 16) ^ ((krow & 7) << 4));
                    s8v ah = *(const s8v*)(bKH + ph);
                    s8v al = *(const s8v*)(bKL + ph);
                    sacc = __builtin_amdgcn_mfma_f32_32x32x16_bf16(ah, qhf[ks], sacc, 0, 0, 0);
                    sacc = __builtin_amdgcn_mfma_f32_32x32x16_bf16(ah, qlf[ks], sacc, 0, 0, 0);
                    sacc = __builtin_amdgcn_mfma_f32_32x32x16_bf16(al, qhf[ks], sacc, 0, 0, 0);
                }
                // decay weight + pack to bf16 words (S'[j][i]: lane holds i=c31, j=jrel(r,hi))
                const int D0 = (l0q + wv * 32 + c31) - (kb * 64 + jt * 32);
                float base = exp2f(lgf * (float)(D0 - 4 * hi));
                u32 w[8];
#pragma unroll
                for (int g = 0; g < 4; ++g) {
                    float wg = base * c8a[g];
                    float v0 = sacc[4 * g + 0] * (wg * c1a[0]);
                    float v1 = sacc[4 * g + 1] * (wg * c1a[1]);
                    float v2 = sacc[4 * g + 2] * (wg * c1a[2]);
                    float v3 = sacc[4 * g + 3] * (wg * c1a[3]);
                    if (diag) {
                        int jr = 8 * g + 4 * hi;
                        if (D0 - (jr + 0) < 0) v0 = 0.f;
                        if (D0 - (jr + 1) < 0) v1 = 0.f;
                        if (D0 - (jr + 2) < 0) v2 = 0.f;
                        if (D0 - (jr + 3) < 0) v3 = 0.f;
                    }
                    w[2 * g]     = (u32)f2bf(v0) | ((u32)f2bf(v1) << 16);
                    w[2 * g + 1] = (u32)f2bf(v2) | ((u32)f2bf(v3) << 16);
                }
                // in-register transpose-exchange across hi halves -> PV A-frags
                u32 e0 = __shfl_xor(hi ? w[0] : w[2], 32);
                u32 e1 = __shfl_xor(hi ? w[1] : w[3], 32);
                u32 e2 = __shfl_xor(hi ? w[4] : w[6], 32);
                u32 e3 = __shfl_xor(hi ? w[5] : w[7], 32);
                u32x4 a0v = { hi ? e0 : w[0], hi ? e1 : w[1], hi ? w[2] : e0, hi ? w[3] : e1 };
                u32x4 a1v = { hi ? e2 : w[4], hi ? e3 : w[5], hi ? w[6] : e2, hi ? w[7] : e3 };
                s8v af0 = __builtin_bit_cast(s8v, a0v);
                s8v af1 = __builtin_bit_cast(s8v, a1v);
                // PV: O[i][c] += S[i][j] V[j][c]
#pragma unroll
                for (int ksl = 0; ksl < 2; ++ksl) {
                    s8v af = ksl ? af1 : af0;
                    int cb = (jt * 2 + ksl) * 32 + hi * 16;
                    int r0 = c31;
                    s8v vb0 = *(const s8v*)(bVT + r0 * 128 + (cb ^ ((r0 & 7) << 4)));
                    int r1 = 32 + c31;
                    s8v vb1 = *(const s8v*)(bVT + r1 * 128 + (cb ^ ((r1 & 7) << 4)));
                    acc0 = __builtin_amdgcn_mfma_f32_32x32x16_bf16(af, vb0, acc0, 0, 0, 0);
                    acc1 = __builtin_amdgcn_mfma_f32_32x32x16_bf16(af, vb1, acc1, 0, 0, 0);
                }
            }
            asm volatile("s_waitcnt lgkmcnt(0)" ::: "memory");
            __builtin_amdgcn_s_barrier();
            __builtin_amdgcn_sched_barrier(0);
            cur ^= 1;
        }
#undef STAGE

        // store: lane holds O[row=crow(r,hi)][ch = n*32 + c31]
        float* outp = (sub == 1) ? part : ret;
        size_t rbase = (sub == 1) ? (size_t)(l0q - 2048 + wv * 32) : (size_t)(l0q + wv * 32);
#pragma unroll
        for (int r = 0; r < 16; ++r) {
            int row = (r & 3) + 8 * (r >> 2) + 4 * hi;
            size_t o = (rbase + row) * DD + h * HS;
            outp[o + c31]      = acc0[r];
            outp[o + 32 + c31] = acc1[r];
        }
    }
}

// ---------------- GroupNorm * gate -> gg hi/lo bf16 (adds split partials) ----------------
__global__ __launch_bounds__(256) void k_gn(
    const float* __restrict__ ret, const float* __restrict__ part,
    const float* __restrict__ gate,
    const float* __restrict__ gw, const float* __restrict__ gb,
    u16* __restrict__ ggh, u16* __restrict__ ggl) {
    const int t = threadIdx.x;
    const int w = t >> 6;
    const int lane = t & 63;
    const int grp = blockIdx.x * 4 + w;
    const int l = grp >> 3;
    const int h = grp & 7;
    const size_t idx = (size_t)l * DD + h * HS + lane;

    float val = ret[idx];
    if (l >= 2048) val += part[(size_t)(l - 2048) * DD + h * HS + lane];
    float s = val;
#pragma unroll
    for (int off = 1; off < 64; off <<= 1) s += __shfl_xor(s, off);
    float mean = s * (1.f / 64.f);
    float d = val - mean;
    float ss = d * d;
#pragma unroll
    for (int off = 1; off < 64; off <<= 1) ss += __shfl_xor(ss, off);
    float var = ss * (1.f / 64.f);
    float g = d * rsqrtf(var + 1e-5f);
    g = fmaf(g, gw[h * HS + lane], gb[h * HS + lane]);
    float vv = g * gate[idx];
    u16 hb = f2bf(vv);
    ggh[idx] = hb;
    ggl[idx] = f2bf(vv - bf2f(hb));
}

// ---------------- out = gg @ W_O ----------------
__global__ __launch_bounds__(256) void k_out(
    const u16* __restrict__ Ah, const u16* __restrict__ Al,
    const u16* __restrict__ Wth, const u16* __restrict__ Wtl,
    float* __restrict__ out) {
    __shared__ __align__(16) char smem[49152];
    char* sAH = smem;
    char* sAL = smem + 16384;
    char* sBH = smem + 32768;
    char* sBL = smem + 40960;
    const int t = threadIdx.x;
    const int l0 = blockIdx.x * 128;
    const int c0 = blockIdx.y * 64;
    const int wv = t >> 6;
    const int lane = t & 63;
    const int c31 = lane & 31;
    const int hi = lane >> 5;

    f16v acc0, acc1;
#pragma unroll
    for (int i = 0; i < 16; ++i) { acc0[i] = 0.f; acc1[i] = 0.f; }

    for (int kt = 0; kt < 8; ++kt) {
#pragma unroll
        for (int it = 0; it < 4; ++it) {
            int o = t * 16 + it * 4096;
            int row = o >> 7, cb = o & 127;
            int sw = o ^ ((row & 7) << 4);
            size_t g = (size_t)(l0 + row) * 1024 + kt * 128 + cb;
            *(s8v*)(sAH + sw) = *(const s8v*)((const char*)Ah + g);
            *(s8v*)(sAL + sw) = *(const s8v*)((const char*)Al + g);
        }
#pragma unroll
        for (int it = 0; it < 2; ++it) {
            int o = t * 16 + it * 4096;
            int row = o >> 7, cb = o & 127;
            int sw = o ^ ((row & 7) << 4);
            size_t g = (size_t)(2048 + c0 + row) * 1024 + kt * 128 + cb;
            *(s8v*)(sBH + sw) = *(const s8v*)((const char*)Wth + g);
            *(s8v*)(sBL + sw) = *(const s8v*)((const char*)Wtl + g);
        }
        __syncthreads();

        const int arow = wv * 32 + c31;
        const int aswz = (arow & 7) << 4;
        s8v ah[4], al[4];
#pragma unroll
        for (int ks = 0; ks < 4; ++ks) {
            int cb = (ks * 32 + hi * 16) ^ aswz;
            ah[ks] = *(const s8v*)(sAH + arow * 128 + cb);
            al[ks] = *(const s8v*)(sAL + arow * 128 + cb);
        }
#define DO_N(NN, ACC)                                                              \
        {                                                                          \
            int brow = NN * 32 + c31;                                              \
            int bswz = (brow & 7) << 4;                                            \
            _Pragma("unroll")                                                      \
            for (int ks = 0; ks < 4; ++ks) {                                       \
                int cb = (ks * 32 + hi * 16) ^ bswz;                               \
                s8v bh = *(const s8v*)(sBH + brow * 128 + cb);                     \
                s8v bl = *(const s8v*)(sBL + brow * 128 + cb);                     \
                ACC = __builtin_amdgcn_mfma_f32_32x32x16_bf16(ah[ks], bh, ACC, 0, 0, 0); \
                ACC = __builtin_amdgcn_mfma_f32_32x32x16_bf16(ah[ks], bl, ACC, 0, 0, 0); \
                ACC = __builtin_amdgcn_mfma_f32_32x32x16_bf16(al[ks], bh, ACC, 0, 0, 0); \
            }                                                                      \
        }
        DO_N(0, acc0)
        DO_N(1, acc1)
#undef DO_N
        __syncthreads();
    }

#pragma unroll
    for (int n = 0; n < 2; ++n) {
        const f16v acc = n ? acc1 : acc0;
        int C = c0 + n * 32 + c31;
#pragma unroll
        for (int r = 0; r < 16; ++r) {
            int lrow = wv * 32 + (r & 3) + 8 * (r >> 2) + 4 * hi;
            out[(size_t)(l0 + lrow) * DD + C] = acc[r];
        }
    }
}

extern "C" void kernel_launch(void* const* d_in, const int* in_sizes, int n_in,
                              void* d_out, int out_size, void* d_ws, size_t ws_size,
                              hipStream_t stream) {
    const float* X   = (const float*)d_in[0];
    const float* W_Q = (const float*)d_in[1];
    const float* W_K = (const float*)d_in[2];
    const float* W_V = (const float*)d_in[3];
    const float* W_G = (const float*)d_in[4];
    const float* W_O = (const float*)d_in[5];
    const float* gnw = (const float*)d_in[6];
    const float* gnb = (const float*)d_in[7];

    float* ws   = (float*)d_ws;
    u16* qhp  = (u16*)(ws + WS_QH);
    u16* qlp  = (u16*)(ws + WS_QL);
    u16* khp  = (u16*)(ws + WS_KH);
    u16* klp  = (u16*)(ws + WS_KL);
    u16* vtp  = (u16*)(ws + WS_VT);
    u16* xhp  = (u16*)(ws + WS_XH);
    u16* xlp  = (u16*)(ws + WS_XL);
    u16* wth  = (u16*)(ws + WS_WTH);
    u16* wtl  = (u16*)(ws + WS_WTL);
    float* gate = ws + WS_GATE;
    float* tab  = ws + WS_TAB;
    float* ret  = ws + WS_XH;          // reuse X region after k_fused
    u16* ggh  = (u16*)(ws + WS_QH);    // reuse q region after k_ret
    u16* ggl  = (u16*)(ws + WS_QL);
    int* cnt  = (int*)(ws + WS_TAB);   // reuse tab region after k_fused
    float* part = (float*)d_out;       // d_out as scratch for split partials
    float* out  = (float*)d_out;

    k_tables<<<512, 256, 0, stream>>>(tab);
    k_packx<<<2048, 256, 0, stream>>>(X, xhp, xlp);
    k_prep<<<dim3(16, 80), 256, 0, stream>>>(W_Q, W_K, W_V, W_G, W_O, wth, wtl);
    k_fused<<<dim3(32, 32), 256, 0, stream>>>(xhp, xlp, wth, wtl, tab, qhp, qlp, khp, klp, vtp, gate);
    hipMemsetAsync(cnt, 0, 4, stream);
    k_ret<<<512, 128, 0, stream>>>(qhp, qlp, khp, klp, vtp, ret, part, cnt);
    k_gn<<<(LQ * NH) / 4, 256, 0, stream>>>(ret, part, gate, gnw, gnb, ggh, ggl);
    k_out<<<dim3(32, 8), 256, 0, stream>>>(ggh, ggl, wth, wtl, out);
}

// Round 5
// 116.816 us; speedup vs baseline: 1.5819x; 1.5819x over previous
//
#include <hip/hip_runtime.h>
#include <math.h>

#define LQ 4096
#define DD 512
#define NH 8
#define HS 64
#define HALF 32

typedef unsigned short u16;
typedef unsigned int u32;
typedef __attribute__((ext_vector_type(8)))  short s8v;   // 8 x bf16 (MFMA A/B frag)
typedef __attribute__((ext_vector_type(4)))  float f4v;
typedef __attribute__((ext_vector_type(4)))  u32  u32x4;
typedef __attribute__((ext_vector_type(16))) float f16v;  // 32x32 MFMA C/D

// workspace offsets (in floats)
#define WS_QH   0u          // later reused as gg_hi
#define WS_QL   1048576u    // later reused as gg_lo
#define WS_KH   2097152u
#define WS_KL   3145728u
#define WS_VT   4194304u
#define WS_XH   5242880u    // xh -> A_state (2M floats, spans XH+XL) -> ret
#define WS_XL   6291456u
#define WS_WTH  7340032u
#define WS_WTL  7995392u
#define WS_GATE 8650752u
#define WS_TAB  10747904u   // 524288 floats
#define WS_KTWH 11272192u   // ktw_hi (1M float slots); later reused as St_hi
#define WS_KTWL 12320768u   // ktw_lo; later reused as St_lo

__device__ inline u16 f2bf(float x) {
    unsigned int u = __float_as_uint(x);
    return (u16)((u + 0x7fffu + ((u >> 16) & 1u)) >> 16);
}
__device__ inline float bf2f(u16 h) { return __uint_as_float(((unsigned int)h) << 16); }

__device__ __forceinline__ void gld16(void* lds, const void* g) {
    __builtin_amdgcn_global_load_lds(
        (const __attribute__((address_space(1))) void*)g,
        (__attribute__((address_space(3))) void*)lds, 16, 0, 0);
}

// ---------------- xPos tables ----------------
__global__ __launch_bounds__(256) void k_tables(float* __restrict__ tab) {
    int idx = blockIdx.x * 256 + threadIdx.x;
    if (idx >= LQ * HALF) return;
    int l = idx >> 5;
    int i = idx & 31;
    double sv  = (2.0 * i + 0.4 * (double)HS) / (1.4 * (double)HS);
    double s   = pow(sv, (double)l / 512.0);
    double invf = pow(10000.0, -(double)i / (double)HALF);
    double th  = (double)l * invf;
    double c = cos(th), sn = sin(th);
    tab[idx]                 = (float)(c * s);
    tab[LQ*HALF + idx]       = (float)(sn * s);
    tab[2*LQ*HALF + idx]     = (float)(c / s);
    tab[3*LQ*HALF + idx]     = (float)(sn / s);
}

// ---------------- weight transpose-pack ----------------
__global__ __launch_bounds__(256) void k_prep(
    const float* __restrict__ Wq, const float* __restrict__ Wk, const float* __restrict__ Wv,
    const float* __restrict__ Wg, const float* __restrict__ Wo,
    u16* __restrict__ Wth, u16* __restrict__ Wtl) {
    __shared__ float tile[32][33];
    const int t = threadIdx.x;
    const int d0 = blockIdx.x * 32;
    const int C0 = blockIdx.y * 32;
    const int proj = C0 >> 9;
    const int tc = t & 31;
    const int tr = t >> 5;
#pragma unroll
    for (int rr = 0; rr < 4; ++rr) {
        int dl = tr + rr * 8;
        int d = d0 + dl;
        int C = C0 + tc;
        float val;
        if (proj < 3) {
            const float* W = (proj == 0) ? Wq : ((proj == 1) ? Wk : Wv);
            int h = (C & 511) >> 6, hs = C & 63;
            val = W[(size_t)h * (DD * HS) + (size_t)d * HS + hs];
        } else if (proj == 3) {
            val = Wg[(size_t)d * DD + (C & 511)];
        } else {
            val = Wo[(size_t)d * DD + (C - 2048)];
        }
        tile[dl][tc] = val;
    }
    __syncthreads();
#pragma unroll
    for (int rr = 0; rr < 4; ++rr) {
        int cl = tr + rr * 8;
        float val = tile[tc][cl];
        u16 hb = f2bf(val);
        size_t o = (size_t)(C0 + cl) * DD + d0 + tc;
        Wth[o] = hb;
        Wtl[o] = f2bf(val - bf2f(hb));
    }
}

// ---------------- X -> hi/lo bf16 ----------------
__global__ __launch_bounds__(256) void k_packx(const float* __restrict__ X,
                                               u16* __restrict__ Xh, u16* __restrict__ Xl) {
    int idx = (blockIdx.x * 256 + threadIdx.x) * 4;
    f4v x = *(const f4v*)(X + idx);
    unsigned int h[4], l[4];
#pragma unroll
    for (int j = 0; j < 4; ++j) {
        u16 hb = f2bf(x[j]);
        h[j] = hb;
        l[j] = f2bf(x[j] - bf2f(hb));
    }
    uint2 ph, pl;
    ph.x = h[0] | (h[1] << 16); ph.y = h[2] | (h[3] << 16);
    pl.x = l[0] | (l[1] << 16); pl.y = l[2] | (l[3] << 16);
    *(uint2*)((void*)(Xh + idx)) = ph;
    *(uint2*)((void*)(Xl + idx)) = pl;
}

// ---------------- fused MFMA GEMM: X @ [Wq|Wk|Wv|Wg] with per-proj epilogue ----------------
// proj==1 additionally emits decay-weighted transposed K (hi/lo) for the chunked state pass.
__global__ __launch_bounds__(256) void k_fused(
    const u16* __restrict__ Xh, const u16* __restrict__ Xl,
    const u16* __restrict__ Wth, const u16* __restrict__ Wtl,
    const float* __restrict__ tab,
    u16* __restrict__ qh, u16* __restrict__ ql,
    u16* __restrict__ kh, u16* __restrict__ kl,
    u16* __restrict__ vt, float* __restrict__ gate,
    u16* __restrict__ ktwh, u16* __restrict__ ktwl) {
    __shared__ __align__(16) char smem[49152];
    char* sAH = smem;
    char* sAL = smem + 16384;
    char* sBH = smem + 32768;
    char* sBL = smem + 40960;
    const int t = threadIdx.x;
    const int l0 = blockIdx.x * 128;
    const int c0 = blockIdx.y * 64;
    const int wv = t >> 6;
    const int lane = t & 63;
    const int c31 = lane & 31;
    const int hi = lane >> 5;

    f16v acc0, acc1;
#pragma unroll
    for (int i = 0; i < 16; ++i) { acc0[i] = 0.f; acc1[i] = 0.f; }

    for (int kt = 0; kt < 8; ++kt) {
#pragma unroll
        for (int it = 0; it < 4; ++it) {
            int o = t * 16 + it * 4096;
            int row = o >> 7, cb = o & 127;
            int sw = o ^ ((row & 7) << 4);
            size_t g = (size_t)(l0 + row) * 1024 + kt * 128 + cb;
            *(s8v*)(sAH + sw) = *(const s8v*)((const char*)Xh + g);
            *(s8v*)(sAL + sw) = *(const s8v*)((const char*)Xl + g);
        }
#pragma unroll
        for (int it = 0; it < 2; ++it) {
            int o = t * 16 + it * 4096;
            int row = o >> 7, cb = o & 127;
            int sw = o ^ ((row & 7) << 4);
            size_t g = (size_t)(c0 + row) * 1024 + kt * 128 + cb;
            *(s8v*)(sBH + sw) = *(const s8v*)((const char*)Wth + g);
            *(s8v*)(sBL + sw) = *(const s8v*)((const char*)Wtl + g);
        }
        __syncthreads();

        const int arow = wv * 32 + c31;
        const int aswz = (arow & 7) << 4;
        s8v ah[4], al[4];
#pragma unroll
        for (int ks = 0; ks < 4; ++ks) {
            int cb = (ks * 32 + hi * 16) ^ aswz;
            ah[ks] = *(const s8v*)(sAH + arow * 128 + cb);
            al[ks] = *(const s8v*)(sAL + arow * 128 + cb);
        }
#define DO_N(NN, ACC)                                                              \
        {                                                                          \
            int brow = NN * 32 + c31;                                              \
            int bswz = (brow & 7) << 4;                                            \
            _Pragma("unroll")                                                      \
            for (int ks = 0; ks < 4; ++ks) {                                       \
                int cb = (ks * 32 + hi * 16) ^ bswz;                               \
                s8v bh = *(const s8v*)(sBH + brow * 128 + cb);                     \
                s8v bl = *(const s8v*)(sBL + brow * 128 + cb);                     \
                ACC = __builtin_amdgcn_mfma_f32_32x32x16_bf16(ah[ks], bh, ACC, 0, 0, 0); \
                ACC = __builtin_amdgcn_mfma_f32_32x32x16_bf16(ah[ks], bl, ACC, 0, 0, 0); \
                ACC = __builtin_amdgcn_mfma_f32_32x32x16_bf16(al[ks], bh, ACC, 0, 0, 0); \
            }                                                                      \
        }
        DO_N(0, acc0)
        DO_N(1, acc1)
#undef DO_N
        __syncthreads();
    }

    const int proj = c0 >> 9;
    if (proj < 2) {
        const float* ct = tab + (proj ? 2 * LQ * HALF : 0);
        const float* st = tab + (proj ? 3 * LQ * HALF : LQ * HALF);
        u16* oh = proj ? kh : qh;
        u16* ol = proj ? kl : ql;
        const int hh = (c0 & 511) >> 6;
        float lgf = 0.f;
        if (proj == 1) {
            double lg = -3.4657359027997265 + (double)hh * (-2.772588722239781 / 7.0);
            lgf = (float)(log(1.0 - exp(lg)) * 1.4426950408889634);
        }
        float* vbuf = (float*)smem;   // [64][129] fp32, written only for proj==1
#pragma unroll
        for (int n = 0; n < 2; ++n) {
            const f16v acc = n ? acc1 : acc0;
            int C = c0 + n * 32 + c31;
            int hs = C & 63, i2 = hs >> 1;
            float sgn = (hs & 1) ? 1.f : -1.f;
#pragma unroll
            for (int r = 0; r < 16; ++r) {
                int lrow = wv * 32 + (r & 3) + 8 * (r >> 2) + 4 * hi;
                int pos = l0 + lrow;
                float val = acc[r];
                float part = __shfl_xor(val, 1);
                float res = val * ct[pos * HALF + i2] + sgn * part * st[pos * HALF + i2];
                u16 hb = f2bf(res);
                size_t o = ((size_t)hh * LQ + pos) * HS + hs;
                oh[o] = hb;
                ol[o] = f2bf(res - bf2f(hb));
                if (proj == 1) {
                    float wf = exp2f(lgf * (float)(64 - (pos & 63)));   // gamma^(64-m')
                    vbuf[(n * 32 + c31) * 129 + lrow] = res * wf;
                }
            }
        }
        if (proj == 1) {
            __syncthreads();
            int cl = t >> 2, lseg = (t & 3) * 32;
            size_t o = ((size_t)hh * HS + cl) * LQ + l0 + lseg;
#pragma unroll
            for (int ch4 = 0; ch4 < 4; ++ch4) {
                s8v pkh, pkl;
#pragma unroll
                for (int j = 0; j < 8; ++j) {
                    float v = vbuf[cl * 129 + lseg + ch4 * 8 + j];
                    u16 hb = f2bf(v);
                    pkh[j] = (short)hb;
                    pkl[j] = (short)f2bf(v - bf2f(hb));
                }
                *(s8v*)(ktwh + o + ch4 * 8) = pkh;
                *(s8v*)(ktwl + o + ch4 * 8) = pkl;
            }
        }
    } else if (proj == 2) {
        __syncthreads();
        float* vbuf = (float*)smem;
#pragma unroll
        for (int n = 0; n < 2; ++n) {
            const f16v acc = n ? acc1 : acc0;
            int cl = n * 32 + c31;
#pragma unroll
            for (int r = 0; r < 16; ++r) {
                int lrow = wv * 32 + (r & 3) + 8 * (r >> 2) + 4 * hi;
                vbuf[cl * 129 + lrow] = acc[r];
            }
        }
        __syncthreads();
        int h = (c0 & 511) >> 6;
        int cl = t >> 2, lseg = (t & 3) * 32;
        size_t o = ((size_t)h * HS + cl) * LQ + l0 + lseg;
#pragma unroll
        for (int ch = 0; ch < 4; ++ch) {
            s8v pk;
#pragma unroll
            for (int j = 0; j < 8; ++j) pk[j] = (short)f2bf(vbuf[cl * 129 + lseg + ch * 8 + j]);
            *(s8v*)(vt + o + ch * 8) = pk;
        }
    } else {
#pragma unroll
        for (int n = 0; n < 2; ++n) {
            const f16v acc = n ? acc1 : acc0;
            int C = (c0 & 511) + n * 32 + c31;
#pragma unroll
            for (int r = 0; r < 16; ++r) {
                int lrow = wv * 32 + (r & 3) + 8 * (r >> 2) + 4 * hi;
                float vv = acc[r];
                gate[(size_t)(l0 + lrow) * DD + C] = vv / (1.f + expf(-vv));
            }
        }
    }
}

// ---------------- pass1: per-chunk state contribution A^T[ch][d] = sum_m g^(64-m) v[m][ch] k[m][d] ----------------
// grid (64 chunks, 8 heads), block 128 (2 waves; wave = 32-ch half)
__global__ __launch_bounds__(128) void k_ret1(
    const u16* __restrict__ vt, const u16* __restrict__ ktwh, const u16* __restrict__ ktwl,
    float* __restrict__ A) {
    const int t = threadIdx.x;
    const int c = blockIdx.x;
    const int h = blockIdx.y;
    const int wv = t >> 6, lane = t & 63, c31 = lane & 31, hi = lane >> 5;

    s8v va[4];
    const u16* vp = vt + ((size_t)h * 64 + wv * 32 + c31) * LQ + c * 64 + hi * 8;
#pragma unroll
    for (int ks = 0; ks < 4; ++ks) va[ks] = *(const s8v*)(vp + ks * 16);

    f16v a0, a1;
#pragma unroll
    for (int i = 0; i < 16; ++i) { a0[i] = 0.f; a1[i] = 0.f; }

    const size_t kbase = ((size_t)h * 64 + c31) * LQ + c * 64 + hi * 8;
#pragma unroll
    for (int ks = 0; ks < 4; ++ks) {
        s8v b0h = *(const s8v*)(ktwh + kbase + ks * 16);
        s8v b0l = *(const s8v*)(ktwl + kbase + ks * 16);
        s8v b1h = *(const s8v*)(ktwh + kbase + (size_t)32 * LQ + ks * 16);
        s8v b1l = *(const s8v*)(ktwl + kbase + (size_t)32 * LQ + ks * 16);
        a0 = __builtin_amdgcn_mfma_f32_32x32x16_bf16(va[ks], b0h, a0, 0, 0, 0);
        a0 = __builtin_amdgcn_mfma_f32_32x32x16_bf16(va[ks], b0l, a0, 0, 0, 0);
        a1 = __builtin_amdgcn_mfma_f32_32x32x16_bf16(va[ks], b1h, a1, 0, 0, 0);
        a1 = __builtin_amdgcn_mfma_f32_32x32x16_bf16(va[ks], b1l, a1, 0, 0, 0);
    }

    float* Ab = A + ((size_t)h * 64 + c) * 4096;
#pragma unroll
    for (int r = 0; r < 16; ++r) {
        int ch = wv * 32 + (r & 3) + 8 * (r >> 2) + 4 * hi;
        Ab[ch * 64 + c31]      = a0[r];
        Ab[ch * 64 + 32 + c31] = a1[r];
    }
}

// ---------------- pass2: weighted prefix scan over chunks -> S^T hi/lo bf16 ----------------
// grid 128 blocks x 256 (8 heads x 16 elem-tiles of 256)
__global__ __launch_bounds__(256) void k_scan(
    const float* __restrict__ A, u16* __restrict__ sth, u16* __restrict__ stl) {
    const int bx = blockIdx.x;
    const int h = bx >> 4;
    const int e = (bx & 15) * 256 + threadIdx.x;
    double lg = -3.4657359027997265 + (double)h * (-2.772588722239781 / 7.0);
    double gamma = 1.0 - exp(lg);
    float g64 = (float)pow(gamma, 64.0);
    const float* Ab = A + (size_t)h * 64 * 4096 + e;
    u16* shb = sth + (size_t)h * 64 * 4096 + e;
    u16* slb = stl + (size_t)h * 64 * 4096 + e;
    float s = 0.f;
    for (int cc = 0; cc < 64; ++cc) {
        if (cc) {
            u16 hb = f2bf(s);
            shb[(size_t)cc * 4096] = hb;
            slb[(size_t)cc * 4096] = f2bf(s - bf2f(hb));
        }
        s = fmaf(g64, s, Ab[(size_t)cc * 4096]);
    }
}

// ---------------- pass3: O = diag(g^n') Q S_c + intra-chunk masked QK^T V ----------------
// grid (64 chunks, 8 heads), block 128 (2 waves; wave = 32 q-rows)
__global__ __launch_bounds__(128) void k_ret3(
    const u16* __restrict__ qh, const u16* __restrict__ ql,
    const u16* __restrict__ kh, const u16* __restrict__ kl,
    const u16* __restrict__ vt,
    const u16* __restrict__ sth, const u16* __restrict__ stl,
    float* __restrict__ ret) {
    __shared__ __align__(16) char sBuf[24576];   // KH 8K | KL 8K | VT 8K (XOR-swizzled)
    const int t = threadIdx.x;
    const int c = blockIdx.x;
    const int h = blockIdx.y;
    const int wv = t >> 6, lane = t & 63, c31 = lane & 31, hi = lane >> 5;
    const int l0q = c * 64;

    double lg = -3.4657359027997265 + (double)h * (-2.772588722239781 / 7.0);
    double gamma = 1.0 - exp(lg);
    float lgf = (float)(log(gamma) * 1.4426950408889634);
    float c1a[4], c8a[4];
#pragma unroll
    for (int m = 0; m < 4; ++m) { c1a[m] = exp2f(-lgf * (float)m); c8a[m] = exp2f(-lgf * (float)(8 * m)); }

    // Q fragments
    s8v qhf[4], qlf[4];
    {
        const u16* qph = qh + ((size_t)h * LQ + l0q + wv * 32 + c31) * HS + hi * 8;
        const u16* qpl = ql + ((size_t)h * LQ + l0q + wv * 32 + c31) * HS + hi * 8;
#pragma unroll
        for (int ks = 0; ks < 4; ++ks) {
            qhf[ks] = *(const s8v*)(qph + ks * 16);
            qlf[ks] = *(const s8v*)(qpl + ks * 16);
        }
    }

    // stage K hi/lo + VT for this chunk (pre-swizzled source, linear LDS)
    {
        const char* gKH = (const char*)kh + ((size_t)h * LQ + l0q) * 128;
        const char* gKL = (const char*)kl + ((size_t)h * LQ + l0q) * 128;
        const char* gVT = (const char*)vt + ((size_t)h * 64) * 8192 + l0q * 2;
#pragma unroll
        for (int i_ = 0; i_ < 12; ++i_) {
            int boff = wv * 12288 + i_ * 1024 + lane * 16;
            int seg = boff >> 13;
            int o_ = boff & 8191;
            int osrc = o_ ^ (((o_ >> 7) & 7) << 4);
            const char* src = (seg == 0) ? gKH + osrc
                            : (seg == 1) ? gKL + osrc
                            : gVT + (size_t)(osrc >> 7) * 8192 + (osrc & 127);
            gld16(sBuf + wv * 12288 + i_ * 1024, src);
        }
    }

    // inter-chunk: qs = Q @ S^T (hi/lo 3-mfma), overlapped with staging latency
    f16v qs0, qs1;
#pragma unroll
    for (int i = 0; i < 16; ++i) { qs0[i] = 0.f; qs1[i] = 0.f; }
    if (c > 0) {
        const u16* sbh = sth + ((size_t)h * 64 + c) * 4096;
        const u16* sbl = stl + ((size_t)h * 64 + c) * 4096;
#pragma unroll
        for (int ks = 0; ks < 4; ++ks) {
            int off0 = c31 * 64 + ks * 16 + hi * 8;
            int off1 = (32 + c31) * 64 + ks * 16 + hi * 8;
            s8v b0h = *(const s8v*)(sbh + off0);
            s8v b0l = *(const s8v*)(sbl + off0);
            s8v b1h = *(const s8v*)(sbh + off1);
            s8v b1l = *(const s8v*)(sbl + off1);
            qs0 = __builtin_amdgcn_mfma_f32_32x32x16_bf16(qhf[ks], b0h, qs0, 0, 0, 0);
            qs0 = __builtin_amdgcn_mfma_f32_32x32x16_bf16(qhf[ks], b0l, qs0, 0, 0, 0);
            qs0 = __builtin_amdgcn_mfma_f32_32x32x16_bf16(qlf[ks], b0h, qs0, 0, 0, 0);
            qs1 = __builtin_amdgcn_mfma_f32_32x32x16_bf16(qhf[ks], b1h, qs1, 0, 0, 0);
            qs1 = __builtin_amdgcn_mfma_f32_32x32x16_bf16(qhf[ks], b1l, qs1, 0, 0, 0);
            qs1 = __builtin_amdgcn_mfma_f32_32x32x16_bf16(qlf[ks], b1h, qs1, 0, 0, 0);
        }
    }

    asm volatile("s_waitcnt vmcnt(0)" ::: "memory");
    __syncthreads();

    // intra-chunk masked tile
    f16v acc0, acc1;
#pragma unroll
    for (int i = 0; i < 16; ++i) { acc0[i] = 0.f; acc1[i] = 0.f; }
    const char* bKH = sBuf;
    const char* bKL = sBuf + 8192;
    const char* bVT = sBuf + 16384;

#pragma unroll
    for (int jt = 0; jt < 2; ++jt) {
        if (wv == 0 && jt == 1) break;   // fully-masked strip
        f16v sacc;
#pragma unroll
        for (int i = 0; i < 16; ++i) sacc[i] = 0.f;
#pragma unroll
        for (int ks = 0; ks < 4; ++ks) {
            int krow = jt * 32 + c31;
            int ph = krow * 128 + ((ks * 32 + hi * 16) ^ ((krow & 7) << 4));
            s8v ah = *(const s8v*)(bKH + ph);
            s8v al = *(const s8v*)(bKL + ph);
            sacc = __builtin_amdgcn_mfma_f32_32x32x16_bf16(ah, qhf[ks], sacc, 0, 0, 0);
            sacc = __builtin_amdgcn_mfma_f32_32x32x16_bf16(ah, qlf[ks], sacc, 0, 0, 0);
            sacc = __builtin_amdgcn_mfma_f32_32x32x16_bf16(al, qhf[ks], sacc, 0, 0, 0);
        }
        const int D0 = (wv * 32 + c31) - jt * 32;
        float base = exp2f(lgf * (float)(D0 - 4 * hi));
        u32 w[8];
#pragma unroll
        for (int g = 0; g < 4; ++g) {
            float wg = base * c8a[g];
            float v0 = sacc[4 * g + 0] * (wg * c1a[0]);
            float v1 = sacc[4 * g + 1] * (wg * c1a[1]);
            float v2 = sacc[4 * g + 2] * (wg * c1a[2]);
            float v3 = sacc[4 * g + 3] * (wg * c1a[3]);
            int jr = 8 * g + 4 * hi;
            if (D0 - (jr + 0) < 0) v0 = 0.f;
            if (D0 - (jr + 1) < 0) v1 = 0.f;
            if (D0 - (jr + 2) < 0) v2 = 0.f;
            if (D0 - (jr + 3) < 0) v3 = 0.f;
            w[2 * g]     = (u32)f2bf(v0) | ((u32)f2bf(v1) << 16);
            w[2 * g + 1] = (u32)f2bf(v2) | ((u32)f2bf(v3) << 16);
        }
        u32 e0 = __shfl_xor(hi ? w[0] : w[2], 32);
        u32 e1 = __shfl_xor(hi ? w[1] : w[3], 32);
        u32 e2 = __shfl_xor(hi ? w[4] : w[6], 32);
        u32 e3 = __shfl_xor(hi ? w[5] : w[7], 32);
        u32x4 a0v = { hi ? e0 : w[0], hi ? e1 : w[1], hi ? w[2] : e0, hi ? w[3] : e1 };
        u32x4 a1v = { hi ? e2 : w[4], hi ? e3 : w[5], hi ? w[6] : e2, hi ? w[7] : e3 };
        s8v af0 = __builtin_bit_cast(s8v, a0v);
        s8v af1 = __builtin_bit_cast(s8v, a1v);
#pragma unroll
        for (int ksl = 0; ksl < 2; ++ksl) {
            s8v af = ksl ? af1 : af0;
            int cb = (jt * 2 + ksl) * 32 + hi * 16;
            int r0 = c31;
            s8v vb0 = *(const s8v*)(bVT + r0 * 128 + (cb ^ ((r0 & 7) << 4)));
            int r1 = 32 + c31;
            s8v vb1 = *(const s8v*)(bVT + r1 * 128 + (cb ^ ((r1 & 7) << 4)));
            acc0 = __builtin_amdgcn_mfma_f32_32x32x16_bf16(af, vb0, acc0, 0, 0, 0);
            acc1 = __builtin_amdgcn_mfma_f32_32x32x16_bf16(af, vb1, acc1, 0, 0, 0);
        }
    }

    // combine: O = intra + gamma^{n'} * (Q S)
#pragma unroll
    for (int r = 0; r < 16; ++r) {
        int row = (r & 3) + 8 * (r >> 2) + 4 * hi;
        int nloc = wv * 32 + row;
        float sc = exp2f(lgf * (float)nloc);
        size_t o = (size_t)(l0q + nloc) * DD + h * HS;
        ret[o + c31]      = acc0[r] + sc * qs0[r];
        ret[o + 32 + c31] = acc1[r] + sc * qs1[r];
    }
}

// ---------------- GroupNorm * gate -> gg hi/lo bf16 ----------------
__global__ __launch_bounds__(256) void k_gn(
    const float* __restrict__ ret, const float* __restrict__ gate,
    const float* __restrict__ gw, const float* __restrict__ gb,
    u16* __restrict__ ggh, u16* __restrict__ ggl) {
    const int t = threadIdx.x;
    const int w = t >> 6;
    const int lane = t & 63;
    const int grp = blockIdx.x * 4 + w;
    const int l = grp >> 3;
    const int h = grp & 7;
    const size_t idx = (size_t)l * DD + h * HS + lane;

    float val = ret[idx];
    float s = val;
#pragma unroll
    for (int off = 1; off < 64; off <<= 1) s += __shfl_xor(s, off);
    float mean = s * (1.f / 64.f);
    float d = val - mean;
    float ss = d * d;
#pragma unroll
    for (int off = 1; off < 64; off <<= 1) ss += __shfl_xor(ss, off);
    float var = ss * (1.f / 64.f);
    float g = d * rsqrtf(var + 1e-5f);
    g = fmaf(g, gw[h * HS + lane], gb[h * HS + lane]);
    float vv = g * gate[idx];
    u16 hb = f2bf(vv);
    ggh[idx] = hb;
    ggl[idx] = f2bf(vv - bf2f(hb));
}

// ---------------- out = gg @ W_O ----------------
__global__ __launch_bounds__(256) void k_out(
    const u16* __restrict__ Ah, const u16* __restrict__ Al,
    const u16* __restrict__ Wth, const u16* __restrict__ Wtl,
    float* __restrict__ out) {
    __shared__ __align__(16) char smem[49152];
    char* sAH = smem;
    char* sAL = smem + 16384;
    char* sBH = smem + 32768;
    char* sBL = smem + 40960;
    const int t = threadIdx.x;
    const int l0 = blockIdx.x * 128;
    const int c0 = blockIdx.y * 64;
    const int wv = t >> 6;
    const int lane = t & 63;
    const int c31 = lane & 31;
    const int hi = lane >> 5;

    f16v acc0, acc1;
#pragma unroll
    for (int i = 0; i < 16; ++i) { acc0[i] = 0.f; acc1[i] = 0.f; }

    for (int kt = 0; kt < 8; ++kt) {
#pragma unroll
        for (int it = 0; it < 4; ++it) {
            int o = t * 16 + it * 4096;
            int row = o >> 7, cb = o & 127;
            int sw = o ^ ((row & 7) << 4);
            size_t g = (size_t)(l0 + row) * 1024 + kt * 128 + cb;
            *(s8v*)(sAH + sw) = *(const s8v*)((const char*)Ah + g);
            *(s8v*)(sAL + sw) = *(const s8v*)((const char*)Al + g);
        }
#pragma unroll
        for (int it = 0; it < 2; ++it) {
            int o = t * 16 + it * 4096;
            int row = o >> 7, cb = o & 127;
            int sw = o ^ ((row & 7) << 4);
            size_t g = (size_t)(2048 + c0 + row) * 1024 + kt * 128 + cb;
            *(s8v*)(sBH + sw) = *(const s8v*)((const char*)Wth + g);
            *(s8v*)(sBL + sw) = *(const s8v*)((const char*)Wtl + g);
        }
        __syncthreads();

        const int arow = wv * 32 + c31;
        const int aswz = (arow & 7) << 4;
        s8v ah[4], al[4];
#pragma unroll
        for (int ks = 0; ks < 4; ++ks) {
            int cb = (ks * 32 + hi * 16) ^ aswz;
            ah[ks] = *(const s8v*)(sAH + arow * 128 + cb);
            al[ks] = *(const s8v*)(sAL + arow * 128 + cb);
        }
#define DO_N(NN, ACC)                                                              \
        {                                                                          \
            int brow = NN * 32 + c31;                                              \
            int bswz = (brow & 7) << 4;                                            \
            _Pragma("unroll")                                                      \
            for (int ks = 0; ks < 4; ++ks) {                                       \
                int cb = (ks * 32 + hi * 16) ^ bswz;                               \
                s8v bh = *(const s8v*)(sBH + brow * 128 + cb);                     \
                s8v bl = *(const s8v*)(sBL + brow * 128 + cb);                     \
                ACC = __builtin_amdgcn_mfma_f32_32x32x16_bf16(ah[ks], bh, ACC, 0, 0, 0); \
                ACC = __builtin_amdgcn_mfma_f32_32x32x16_bf16(ah[ks], bl, ACC, 0, 0, 0); \
                ACC = __builtin_amdgcn_mfma_f32_32x32x16_bf16(al[ks], bh, ACC, 0, 0, 0); \
            }                                                                      \
        }
        DO_N(0, acc0)
        DO_N(1, acc1)
#undef DO_N
        __syncthreads();
    }

#pragma unroll
    for (int n = 0; n < 2; ++n) {
        const f16v acc = n ? acc1 : acc0;
        int C = c0 + n * 32 + c31;
#pragma unroll
        for (int r = 0; r < 16; ++r) {
            int lrow = wv * 32 + (r & 3) + 8 * (r >> 2) + 4 * hi;
            out[(size_t)(l0 + lrow) * DD + C] = acc[r];
        }
    }
}

extern "C" void kernel_launch(void* const* d_in, const int* in_sizes, int n_in,
                              void* d_out, int out_size, void* d_ws, size_t ws_size,
                              hipStream_t stream) {
    const float* X   = (const float*)d_in[0];
    const float* W_Q = (const float*)d_in[1];
    const float* W_K = (const float*)d_in[2];
    const float* W_V = (const float*)d_in[3];
    const float* W_G = (const float*)d_in[4];
    const float* W_O = (const float*)d_in[5];
    const float* gnw = (const float*)d_in[6];
    const float* gnb = (const float*)d_in[7];

    float* ws   = (float*)d_ws;
    u16* qhp  = (u16*)(ws + WS_QH);
    u16* qlp  = (u16*)(ws + WS_QL);
    u16* khp  = (u16*)(ws + WS_KH);
    u16* klp  = (u16*)(ws + WS_KL);
    u16* vtp  = (u16*)(ws + WS_VT);
    u16* xhp  = (u16*)(ws + WS_XH);
    u16* xlp  = (u16*)(ws + WS_XL);
    u16* wth  = (u16*)(ws + WS_WTH);
    u16* wtl  = (u16*)(ws + WS_WTL);
    float* gate = ws + WS_GATE;
    float* tab  = ws + WS_TAB;
    u16* ktwh = (u16*)(ws + WS_KTWH);
    u16* ktwl = (u16*)(ws + WS_KTWL);
    float* Abuf = ws + WS_XH;          // A_state over dead xh/xl (2M floats)
    u16* sthp = (u16*)(ws + WS_KTWH);  // St over dead ktw
    u16* stlp = (u16*)(ws + WS_KTWL);
    float* ret  = ws + WS_XH;          // ret over dead A_state
    u16* ggh  = (u16*)(ws + WS_QH);    // gg over dead q
    u16* ggl  = (u16*)(ws + WS_QL);
    float* out  = (float*)d_out;

    k_tables<<<512, 256, 0, stream>>>(tab);
    k_packx<<<2048, 256, 0, stream>>>(X, xhp, xlp);
    k_prep<<<dim3(16, 80), 256, 0, stream>>>(W_Q, W_K, W_V, W_G, W_O, wth, wtl);
    k_fused<<<dim3(32, 32), 256, 0, stream>>>(xhp, xlp, wth, wtl, tab,
                                              qhp, qlp, khp, klp, vtp, gate, ktwh, ktwl);
    k_ret1<<<dim3(64, 8), 128, 0, stream>>>(vtp, ktwh, ktwl, Abuf);
    k_scan<<<128, 256, 0, stream>>>(Abuf, sthp, stlp);
    k_ret3<<<dim3(64, 8), 128, 0, stream>>>(qhp, qlp, khp, klp, vtp, sthp, stlp, ret);
    k_gn<<<(LQ * NH) / 4, 256, 0, stream>>>(ret, gate, gnw, gnb, ggh, ggl);
    k_out<<<dim3(32, 8), 256, 0, stream>>>(ggh, ggl, wth, wtl, out);
}

// Round 6
// 106.461 us; speedup vs baseline: 1.7358x; 1.0973x over previous
//
#include <hip/hip_runtime.h>
#include <math.h>

#define LQ 4096
#define DD 512
#define NH 8
#define HS 64
#define HALF 32

typedef unsigned short u16;
typedef unsigned int u32;
typedef __attribute__((ext_vector_type(8)))  short s8v;   // 8 x bf16 (MFMA A/B frag)
typedef __attribute__((ext_vector_type(4)))  float f4v;
typedef __attribute__((ext_vector_type(4)))  u32  u32x4;
typedef __attribute__((ext_vector_type(16))) float f16v;  // 32x32 MFMA C/D

// workspace offsets (in floats)
#define WS_QH   0u
#define WS_QL   1048576u
#define WS_KH   2097152u
#define WS_KL   3145728u
#define WS_VT   4194304u
#define WS_XFH  5242880u    // frag-packed X hi; later A_state spans XFH+XFL; later ggh
#define WS_XFL  6291456u    // frag-packed X lo; later ggl
#define WS_WF   7340032u    // frag-packed W single bf16 (640K float slots)
#define WS_GATE 8650752u
#define WS_TAB  10747904u
#define WS_KTWH 11272192u   // ktw_hi; later St_hi
#define WS_KTWL 12320768u   // ktw_lo; later St_lo

__device__ inline u16 f2bf(float x) {
    unsigned int u = __float_as_uint(x);
    return (u16)((u + 0x7fffu + ((u >> 16) & 1u)) >> 16);
}
__device__ inline float bf2f(u16 h) { return __uint_as_float(((unsigned int)h) << 16); }

__device__ __forceinline__ void gld16(void* lds, const void* g) {
    __builtin_amdgcn_global_load_lds(
        (const __attribute__((address_space(1))) void*)g,
        (__attribute__((address_space(3))) void*)lds, 16, 0, 0);
}

// ---------------- merged prep: xPos tables | X->frag hi/lo | W->frag single bf16 ----------------
// grid 2816: [0,512) tables, [512,1536) packx, [1536,2816) weight pack
__global__ __launch_bounds__(256) void k_pre(
    const float* __restrict__ X,
    const float* __restrict__ Wq, const float* __restrict__ Wk, const float* __restrict__ Wv,
    const float* __restrict__ Wg, const float* __restrict__ Wo,
    float* __restrict__ tab, u16* __restrict__ Xfh, u16* __restrict__ Xfl,
    u16* __restrict__ Wf) {
    __shared__ float tile[32][33];
    const int b = blockIdx.x;
    const int t = threadIdx.x;
    if (b < 512) {
        int idx = b * 256 + t;   // LQ*HALF = 131072
        if (idx >= LQ * HALF) return;
        int l = idx >> 5;
        int i = idx & 31;
        double sv  = (2.0 * i + 0.4 * (double)HS) / (1.4 * (double)HS);
        double s   = pow(sv, (double)l / 512.0);
        double invf = pow(10000.0, -(double)i / (double)HALF);
        double th  = (double)l * invf;
        double c = cos(th), sn = sin(th);
        tab[idx]                 = (float)(c * s);
        tab[LQ*HALF + idx]       = (float)(sn * s);
        tab[2*LQ*HALF + idx]     = (float)(c / s);
        tab[3*LQ*HALF + idx]     = (float)(sn / s);
    } else if (b < 1536) {
        // X -> fragment-packed hi/lo: Xf[rb:128][kt:8][ks:4][lane:64][8]
        int g = (b - 512) * 256 + t;          // 262144 items
        int l = g >> 6;
        int d = (g & 63) * 8;
        const float* xp = X + (size_t)l * DD + d;
        f4v x0 = *(const f4v*)xp;
        f4v x1 = *(const f4v*)(xp + 4);
        s8v ph, pl;
#pragma unroll
        for (int j = 0; j < 4; ++j) {
            u16 hb = f2bf(x0[j]);
            ph[j] = (short)hb; pl[j] = (short)f2bf(x0[j] - bf2f(hb));
            u16 hb2 = f2bf(x1[j]);
            ph[j+4] = (short)hb2; pl[j+4] = (short)f2bf(x1[j] - bf2f(hb2));
        }
        int rb = l >> 5, kt = d >> 6, ks = (d >> 4) & 3, kh2 = (d >> 3) & 1;
        int lane = kh2 * 32 + (l & 31);
        size_t off = (((size_t)(rb * 8 + kt) * 4 + ks) * 64 + lane) * 8;
        *(s8v*)(Xfh + off) = ph;
        *(s8v*)(Xfl + off) = pl;
    } else {
        // weights -> fragment-packed single bf16: Wf[nb:80][kt:8][ks:4][lane:64][8]
        int bb = b - 1536;                    // 0..1279
        int d0 = (bb & 15) * 32, C0 = (bb >> 4) * 32;
        int proj = C0 >> 9;
        int tc = t & 31, tr = t >> 5;
#pragma unroll
        for (int rr = 0; rr < 4; ++rr) {
            int dl = tr + rr * 8;
            int d = d0 + dl;
            int C = C0 + tc;
            float val;
            if (proj < 3) {
                const float* W = (proj == 0) ? Wq : ((proj == 1) ? Wk : Wv);
                int h = (C & 511) >> 6, hs = C & 63;
                val = W[(size_t)h * (DD * HS) + (size_t)d * HS + hs];
            } else if (proj == 3) {
                val = Wg[(size_t)d * DD + (C & 511)];
            } else {
                val = Wo[(size_t)d * DD + (C - 2048)];
            }
            tile[dl][tc] = val;
        }
        __syncthreads();
        if (t < 128) {
            int cl = t & 31, dgq = t >> 5;    // dgq: 0..3 (8 d each)
            int dl = dgq * 8;
            s8v pk;
#pragma unroll
            for (int j = 0; j < 8; ++j) pk[j] = (short)f2bf(tile[dl + j][cl]);
            int C = C0 + cl;
            int da = d0 + dl;
            int nb = C >> 5, kt = da >> 6, ks = (da >> 4) & 3, kh2 = (da >> 3) & 1;
            int lane = kh2 * 32 + (C & 31);
            size_t off = (((size_t)(nb * 8 + kt) * 4 + ks) * 64 + lane) * 8;
            *(s8v*)(Wf + off) = pk;
        }
    }
}

// ---------------- fused MFMA GEMM (no LDS main loop): X @ [Wq|Wk|Wv|Wg] ----------------
// grid 1024 (chunked XCD swizzle), block 256 (4 waves, each 32l x 64c). A hi/lo, W single bf16.
__global__ __launch_bounds__(256) void k_fused(
    const u16* __restrict__ Xfh, const u16* __restrict__ Xfl,
    const u16* __restrict__ Wf,
    const float* __restrict__ tab,
    u16* __restrict__ qh, u16* __restrict__ ql,
    u16* __restrict__ kh, u16* __restrict__ kl,
    u16* __restrict__ vt, float* __restrict__ gate,
    u16* __restrict__ ktwh, u16* __restrict__ ktwl) {
    __shared__ float vbuf[64 * 129];
    const int t = threadIdx.x;
    const int b = blockIdx.x;
    // chunked swizzle: XCD = b&7 gets contiguous mb range -> X tiles stay L2-local
    const int mb = (b & 7) * 4 + (b >> 8);   // 0..31
    const int cb = (b >> 3) & 31;            // 0..31
    const int l0 = mb * 128;
    const int c0 = cb * 64;
    const int wv = t >> 6;
    const int lane = t & 63;
    const int c31 = lane & 31;
    const int hi = lane >> 5;

    const int rb = mb * 4 + wv;
    const u16* pAh = Xfh + (size_t)rb * 16384 + lane * 8;
    const u16* pAl = Xfl + (size_t)rb * 16384 + lane * 8;
    const u16* pB0 = Wf + (size_t)(cb * 2) * 16384 + lane * 8;
    const u16* pB1 = pB0 + 16384;

    f16v acc0, acc1;
#pragma unroll
    for (int i = 0; i < 16; ++i) { acc0[i] = 0.f; acc1[i] = 0.f; }

    s8v ah[2][4], al[2][4], bf0[2][4], bf1[2][4];
#pragma unroll
    for (int ks = 0; ks < 4; ++ks) {
        ah[0][ks]  = *(const s8v*)(pAh + ks * 512);
        al[0][ks]  = *(const s8v*)(pAl + ks * 512);
        bf0[0][ks] = *(const s8v*)(pB0 + ks * 512);
        bf1[0][ks] = *(const s8v*)(pB1 + ks * 512);
    }
#pragma unroll
    for (int kt = 0; kt < 8; ++kt) {
        const int cur = kt & 1, nxt = cur ^ 1;
        if (kt < 7) {
            const int ko = (kt + 1) * 2048;
#pragma unroll
            for (int ks = 0; ks < 4; ++ks) {
                ah[nxt][ks]  = *(const s8v*)(pAh + ko + ks * 512);
                al[nxt][ks]  = *(const s8v*)(pAl + ko + ks * 512);
                bf0[nxt][ks] = *(const s8v*)(pB0 + ko + ks * 512);
                bf1[nxt][ks] = *(const s8v*)(pB1 + ko + ks * 512);
            }
        }
#pragma unroll
        for (int ks = 0; ks < 4; ++ks) {
            acc0 = __builtin_amdgcn_mfma_f32_32x32x16_bf16(ah[cur][ks], bf0[cur][ks], acc0, 0, 0, 0);
            acc0 = __builtin_amdgcn_mfma_f32_32x32x16_bf16(al[cur][ks], bf0[cur][ks], acc0, 0, 0, 0);
            acc1 = __builtin_amdgcn_mfma_f32_32x32x16_bf16(ah[cur][ks], bf1[cur][ks], acc1, 0, 0, 0);
            acc1 = __builtin_amdgcn_mfma_f32_32x32x16_bf16(al[cur][ks], bf1[cur][ks], acc1, 0, 0, 0);
        }
    }

    const int proj = c0 >> 9;
    if (proj < 2) {
        const float* ct = tab + (proj ? 2 * LQ * HALF : 0);
        const float* st = tab + (proj ? 3 * LQ * HALF : LQ * HALF);
        u16* oh = proj ? kh : qh;
        u16* ol = proj ? kl : ql;
        const int hh = (c0 & 511) >> 6;
        float lgf = 0.f;
        if (proj == 1) {
            double lg = -3.4657359027997265 + (double)hh * (-2.772588722239781 / 7.0);
            lgf = (float)(log(1.0 - exp(lg)) * 1.4426950408889634);
        }
#pragma unroll
        for (int n = 0; n < 2; ++n) {
            const f16v acc = n ? acc1 : acc0;
            int C = c0 + n * 32 + c31;
            int hs = C & 63, i2 = hs >> 1;
            float sgn = (hs & 1) ? 1.f : -1.f;
#pragma unroll
            for (int r = 0; r < 16; ++r) {
                int lrow = wv * 32 + (r & 3) + 8 * (r >> 2) + 4 * hi;
                int pos = l0 + lrow;
                float val = acc[r];
                float part = __shfl_xor(val, 1);
                float res = val * ct[pos * HALF + i2] + sgn * part * st[pos * HALF + i2];
                u16 hb = f2bf(res);
                size_t o = ((size_t)hh * LQ + pos) * HS + hs;
                oh[o] = hb;
                ol[o] = f2bf(res - bf2f(hb));
                if (proj == 1) {
                    float wf = exp2f(lgf * (float)(64 - (pos & 63)));   // gamma^(64-m')
                    vbuf[(n * 32 + c31) * 129 + lrow] = res * wf;
                }
            }
        }
        if (proj == 1) {
            __syncthreads();
            int cl = t >> 2, lseg = (t & 3) * 32;
            size_t o = ((size_t)hh * HS + cl) * LQ + l0 + lseg;
#pragma unroll
            for (int ch4 = 0; ch4 < 4; ++ch4) {
                s8v pkh, pkl;
#pragma unroll
                for (int j = 0; j < 8; ++j) {
                    float v = vbuf[cl * 129 + lseg + ch4 * 8 + j];
                    u16 hb = f2bf(v);
                    pkh[j] = (short)hb;
                    pkl[j] = (short)f2bf(v - bf2f(hb));
                }
                *(s8v*)(ktwh + o + ch4 * 8) = pkh;
                *(s8v*)(ktwl + o + ch4 * 8) = pkl;
            }
        }
    } else if (proj == 2) {
#pragma unroll
        for (int n = 0; n < 2; ++n) {
            const f16v acc = n ? acc1 : acc0;
            int cl = n * 32 + c31;
#pragma unroll
            for (int r = 0; r < 16; ++r) {
                int lrow = wv * 32 + (r & 3) + 8 * (r >> 2) + 4 * hi;
                vbuf[cl * 129 + lrow] = acc[r];
            }
        }
        __syncthreads();
        int h = (c0 & 511) >> 6;
        int cl = t >> 2, lseg = (t & 3) * 32;
        size_t o = ((size_t)h * HS + cl) * LQ + l0 + lseg;
#pragma unroll
        for (int ch = 0; ch < 4; ++ch) {
            s8v pk;
#pragma unroll
            for (int j = 0; j < 8; ++j) pk[j] = (short)f2bf(vbuf[cl * 129 + lseg + ch * 8 + j]);
            *(s8v*)(vt + o + ch * 8) = pk;
        }
    } else {
#pragma unroll
        for (int n = 0; n < 2; ++n) {
            const f16v acc = n ? acc1 : acc0;
            int C = (c0 & 511) + n * 32 + c31;
#pragma unroll
            for (int r = 0; r < 16; ++r) {
                int lrow = wv * 32 + (r & 3) + 8 * (r >> 2) + 4 * hi;
                float vv = acc[r];
                gate[(size_t)(l0 + lrow) * DD + C] = vv / (1.f + expf(-vv));
            }
        }
    }
}

// ---------------- pass1: per-chunk state A^T[ch][d] = sum_m g^(64-m) v[m][ch] k[m][d] ----------------
__global__ __launch_bounds__(128) void k_ret1(
    const u16* __restrict__ vt, const u16* __restrict__ ktwh, const u16* __restrict__ ktwl,
    float* __restrict__ A) {
    const int t = threadIdx.x;
    const int c = blockIdx.x;
    const int h = blockIdx.y;
    const int wv = t >> 6, lane = t & 63, c31 = lane & 31, hi = lane >> 5;

    s8v va[4];
    const u16* vp = vt + ((size_t)h * 64 + wv * 32 + c31) * LQ + c * 64 + hi * 8;
#pragma unroll
    for (int ks = 0; ks < 4; ++ks) va[ks] = *(const s8v*)(vp + ks * 16);

    f16v a0, a1;
#pragma unroll
    for (int i = 0; i < 16; ++i) { a0[i] = 0.f; a1[i] = 0.f; }

    const size_t kbase = ((size_t)h * 64 + c31) * LQ + c * 64 + hi * 8;
#pragma unroll
    for (int ks = 0; ks < 4; ++ks) {
        s8v b0h = *(const s8v*)(ktwh + kbase + ks * 16);
        s8v b0l = *(const s8v*)(ktwl + kbase + ks * 16);
        s8v b1h = *(const s8v*)(ktwh + kbase + (size_t)32 * LQ + ks * 16);
        s8v b1l = *(const s8v*)(ktwl + kbase + (size_t)32 * LQ + ks * 16);
        a0 = __builtin_amdgcn_mfma_f32_32x32x16_bf16(va[ks], b0h, a0, 0, 0, 0);
        a0 = __builtin_amdgcn_mfma_f32_32x32x16_bf16(va[ks], b0l, a0, 0, 0, 0);
        a1 = __builtin_amdgcn_mfma_f32_32x32x16_bf16(va[ks], b1h, a1, 0, 0, 0);
        a1 = __builtin_amdgcn_mfma_f32_32x32x16_bf16(va[ks], b1l, a1, 0, 0, 0);
    }

    float* Ab = A + ((size_t)h * 64 + c) * 4096;
#pragma unroll
    for (int r = 0; r < 16; ++r) {
        int ch = wv * 32 + (r & 3) + 8 * (r >> 2) + 4 * hi;
        Ab[ch * 64 + c31]      = a0[r];
        Ab[ch * 64 + 32 + c31] = a1[r];
    }
}

// ---------------- pass2: weighted prefix scan over chunks -> S^T hi/lo bf16 ----------------
__global__ __launch_bounds__(256) void k_scan(
    const float* __restrict__ A, u16* __restrict__ sth, u16* __restrict__ stl) {
    const int bx = blockIdx.x;
    const int h = bx >> 4;
    const int e = (bx & 15) * 256 + threadIdx.x;
    double lg = -3.4657359027997265 + (double)h * (-2.772588722239781 / 7.0);
    double gamma = 1.0 - exp(lg);
    float g64 = (float)pow(gamma, 64.0);
    const float* Ab = A + (size_t)h * 64 * 4096 + e;
    u16* shb = sth + (size_t)h * 64 * 4096 + e;
    u16* slb = stl + (size_t)h * 64 * 4096 + e;
    float s = 0.f;
    for (int cc = 0; cc < 64; ++cc) {
        if (cc) {
            u16 hb = f2bf(s);
            shb[(size_t)cc * 4096] = hb;
            slb[(size_t)cc * 4096] = f2bf(s - bf2f(hb));
        }
        s = fmaf(g64, s, Ab[(size_t)cc * 4096]);
    }
}

// ---------------- pass3: O = diag(g^n') Q S_c + intra tile; fused GroupNorm*gate -> gg ----------------
__global__ __launch_bounds__(128) void k_ret3(
    const u16* __restrict__ qh, const u16* __restrict__ ql,
    const u16* __restrict__ kh, const u16* __restrict__ kl,
    const u16* __restrict__ vt,
    const u16* __restrict__ sth, const u16* __restrict__ stl,
    const float* __restrict__ gate,
    const float* __restrict__ gw, const float* __restrict__ gb,
    u16* __restrict__ ggh, u16* __restrict__ ggl) {
    __shared__ __align__(16) char sBuf[24576];   // KH 8K | KL 8K | VT 8K (XOR-swizzled)
    const int t = threadIdx.x;
    const int c = blockIdx.x;
    const int h = blockIdx.y;
    const int wv = t >> 6, lane = t & 63, c31 = lane & 31, hi = lane >> 5;
    const int l0q = c * 64;

    double lg = -3.4657359027997265 + (double)h * (-2.772588722239781 / 7.0);
    double gamma = 1.0 - exp(lg);
    float lgf = (float)(log(gamma) * 1.4426950408889634);
    float c1a[4], c8a[4];
#pragma unroll
    for (int m = 0; m < 4; ++m) { c1a[m] = exp2f(-lgf * (float)m); c8a[m] = exp2f(-lgf * (float)(8 * m)); }

    s8v qhf[4], qlf[4];
    {
        const u16* qph = qh + ((size_t)h * LQ + l0q + wv * 32 + c31) * HS + hi * 8;
        const u16* qpl = ql + ((size_t)h * LQ + l0q + wv * 32 + c31) * HS + hi * 8;
#pragma unroll
        for (int ks = 0; ks < 4; ++ks) {
            qhf[ks] = *(const s8v*)(qph + ks * 16);
            qlf[ks] = *(const s8v*)(qpl + ks * 16);
        }
    }

    {
        const char* gKH = (const char*)kh + ((size_t)h * LQ + l0q) * 128;
        const char* gKL = (const char*)kl + ((size_t)h * LQ + l0q) * 128;
        const char* gVT = (const char*)vt + ((size_t)h * 64) * 8192 + l0q * 2;
#pragma unroll
        for (int i_ = 0; i_ < 12; ++i_) {
            int boff = wv * 12288 + i_ * 1024 + lane * 16;
            int seg = boff >> 13;
            int o_ = boff & 8191;
            int osrc = o_ ^ (((o_ >> 7) & 7) << 4);
            const char* src = (seg == 0) ? gKH + osrc
                            : (seg == 1) ? gKL + osrc
                            : gVT + (size_t)(osrc >> 7) * 8192 + (osrc & 127);
            gld16(sBuf + wv * 12288 + i_ * 1024, src);
        }
    }

    f16v qs0, qs1;
#pragma unroll
    for (int i = 0; i < 16; ++i) { qs0[i] = 0.f; qs1[i] = 0.f; }
    if (c > 0) {
        const u16* sbh = sth + ((size_t)h * 64 + c) * 4096;
        const u16* sbl = stl + ((size_t)h * 64 + c) * 4096;
#pragma unroll
        for (int ks = 0; ks < 4; ++ks) {
            int off0 = c31 * 64 + ks * 16 + hi * 8;
            int off1 = (32 + c31) * 64 + ks * 16 + hi * 8;
            s8v b0h = *(const s8v*)(sbh + off0);
            s8v b0l = *(const s8v*)(sbl + off0);
            s8v b1h = *(const s8v*)(sbh + off1);
            s8v b1l = *(const s8v*)(sbl + off1);
            qs0 = __builtin_amdgcn_mfma_f32_32x32x16_bf16(qhf[ks], b0h, qs0, 0, 0, 0);
            qs0 = __builtin_amdgcn_mfma_f32_32x32x16_bf16(qhf[ks], b0l, qs0, 0, 0, 0);
            qs0 = __builtin_amdgcn_mfma_f32_32x32x16_bf16(qlf[ks], b0h, qs0, 0, 0, 0);
            qs1 = __builtin_amdgcn_mfma_f32_32x32x16_bf16(qhf[ks], b1h, qs1, 0, 0, 0);
            qs1 = __builtin_amdgcn_mfma_f32_32x32x16_bf16(qhf[ks], b1l, qs1, 0, 0, 0);
            qs1 = __builtin_amdgcn_mfma_f32_32x32x16_bf16(qlf[ks], b1h, qs1, 0, 0, 0);
        }
    }

    asm volatile("s_waitcnt vmcnt(0)" ::: "memory");
    __syncthreads();

    f16v acc0, acc1;
#pragma unroll
    for (int i = 0; i < 16; ++i) { acc0[i] = 0.f; acc1[i] = 0.f; }
    const char* bKH = sBuf;
    const char* bKL = sBuf + 8192;
    const char* bVT = sBuf + 16384;

#pragma unroll
    for (int jt = 0; jt < 2; ++jt) {
        if (wv == 0 && jt == 1) break;
        f16v sacc;
#pragma unroll
        for (int i = 0; i < 16; ++i) sacc[i] = 0.f;
#pragma unroll
        for (int ks = 0; ks < 4; ++ks) {
            int krow = jt * 32 + c31;
            int ph = krow * 128 + ((ks * 32 + hi * 16) ^ ((krow & 7) << 4));
            s8v ah = *(const s8v*)(bKH + ph);
            s8v al = *(const s8v*)(bKL + ph);
            sacc = __builtin_amdgcn_mfma_f32_32x32x16_bf16(ah, qhf[ks], sacc, 0, 0, 0);
            sacc = __builtin_amdgcn_mfma_f32_32x32x16_bf16(ah, qlf[ks], sacc, 0, 0, 0);
            sacc = __builtin_amdgcn_mfma_f32_32x32x16_bf16(al, qhf[ks], sacc, 0, 0, 0);
        }
        const int D0 = (wv * 32 + c31) - jt * 32;
        float base = exp2f(lgf * (float)(D0 - 4 * hi));
        u32 w[8];
#pragma unroll
        for (int g = 0; g < 4; ++g) {
            float wg = base * c8a[g];
            float v0 = sacc[4 * g + 0] * (wg * c1a[0]);
            float v1 = sacc[4 * g + 1] * (wg * c1a[1]);
            float v2 = sacc[4 * g + 2] * (wg * c1a[2]);
            float v3 = sacc[4 * g + 3] * (wg * c1a[3]);
            int jr = 8 * g + 4 * hi;
            if (D0 - (jr + 0) < 0) v0 = 0.f;
            if (D0 - (jr + 1) < 0) v1 = 0.f;
            if (D0 - (jr + 2) < 0) v2 = 0.f;
            if (D0 - (jr + 3) < 0) v3 = 0.f;
            w[2 * g]     = (u32)f2bf(v0) | ((u32)f2bf(v1) << 16);
            w[2 * g + 1] = (u32)f2bf(v2) | ((u32)f2bf(v3) << 16);
        }
        u32 e0 = __shfl_xor(hi ? w[0] : w[2], 32);
        u32 e1 = __shfl_xor(hi ? w[1] : w[3], 32);
        u32 e2 = __shfl_xor(hi ? w[4] : w[6], 32);
        u32 e3 = __shfl_xor(hi ? w[5] : w[7], 32);
        u32x4 a0v = { hi ? e0 : w[0], hi ? e1 : w[1], hi ? w[2] : e0, hi ? w[3] : e1 };
        u32x4 a1v = { hi ? e2 : w[4], hi ? e3 : w[5], hi ? w[6] : e2, hi ? w[7] : e3 };
        s8v af0 = __builtin_bit_cast(s8v, a0v);
        s8v af1 = __builtin_bit_cast(s8v, a1v);
#pragma unroll
        for (int ksl = 0; ksl < 2; ++ksl) {
            s8v af = ksl ? af1 : af0;
            int cb = (jt * 2 + ksl) * 32 + hi * 16;
            int r0 = c31;
            s8v vb0 = *(const s8v*)(bVT + r0 * 128 + (cb ^ ((r0 & 7) << 4)));
            int r1 = 32 + c31;
            s8v vb1 = *(const s8v*)(bVT + r1 * 128 + (cb ^ ((r1 & 7) << 4)));
            acc0 = __builtin_amdgcn_mfma_f32_32x32x16_bf16(af, vb0, acc0, 0, 0, 0);
            acc1 = __builtin_amdgcn_mfma_f32_32x32x16_bf16(af, vb1, acc1, 0, 0, 0);
        }
    }

    // epilogue: combine inter+intra, GroupNorm over 64 ch, * gate, write gg hi/lo
    const float gw0 = gw[h * HS + c31],      gw1 = gw[h * HS + 32 + c31];
    const float gb0 = gb[h * HS + c31],      gb1 = gb[h * HS + 32 + c31];
#pragma unroll
    for (int r = 0; r < 16; ++r) {
        int row = (r & 3) + 8 * (r >> 2) + 4 * hi;
        int nloc = wv * 32 + row;
        float sc = exp2f(lgf * (float)nloc);
        float v0 = acc0[r] + sc * qs0[r];
        float v1 = acc1[r] + sc * qs1[r];
        float s = v0 + v1, ss = v0 * v0 + v1 * v1;
#pragma unroll
        for (int off = 1; off < 32; off <<= 1) {
            s  += __shfl_xor(s, off);
            ss += __shfl_xor(ss, off);
        }
        float mean = s * (1.f / 64.f);
        float var = ss * (1.f / 64.f) - mean * mean;
        float inv = rsqrtf(var + 1e-5f);
        int l = l0q + nloc;
        size_t o = (size_t)l * DD + h * HS;
        float gt0 = gate[o + c31];
        float gt1 = gate[o + 32 + c31];
        float g0 = ((v0 - mean) * inv * gw0 + gb0) * gt0;
        float g1 = ((v1 - mean) * inv * gw1 + gb1) * gt1;
        u16 h0 = f2bf(g0);
        ggh[o + c31] = h0;
        ggl[o + c31] = f2bf(g0 - bf2f(h0));
        u16 h1 = f2bf(g1);
        ggh[o + 32 + c31] = h1;
        ggl[o + 32 + c31] = f2bf(g1 - bf2f(h1));
    }
}

// ---------------- out = gg @ W_O (A hi/lo LDS-staged, B single bf16 frag-direct) ----------------
__global__ __launch_bounds__(256) void k_out(
    const u16* __restrict__ Ah, const u16* __restrict__ Al,
    const u16* __restrict__ Wf,
    float* __restrict__ out) {
    __shared__ __align__(16) char smem[32768];
    char* sAH = smem;
    char* sAL = smem + 16384;
    const int t = threadIdx.x;
    const int l0 = blockIdx.x * 128;
    const int c0 = blockIdx.y * 64;
    const int wv = t >> 6;
    const int lane = t & 63;
    const int c31 = lane & 31;
    const int hi = lane >> 5;

    const u16* pB0 = Wf + (size_t)(64 + (c0 >> 5)) * 16384 + lane * 8;
    const u16* pB1 = pB0 + 16384;

    f16v acc0, acc1;
#pragma unroll
    for (int i = 0; i < 16; ++i) { acc0[i] = 0.f; acc1[i] = 0.f; }

    for (int kt = 0; kt < 8; ++kt) {
#pragma unroll
        for (int it = 0; it < 4; ++it) {
            int o = t * 16 + it * 4096;
            int row = o >> 7, cb = o & 127;
            int sw = o ^ ((row & 7) << 4);
            size_t g = (size_t)(l0 + row) * 1024 + kt * 128 + cb;
            *(s8v*)(sAH + sw) = *(const s8v*)((const char*)Ah + g);
            *(s8v*)(sAL + sw) = *(const s8v*)((const char*)Al + g);
        }
        __syncthreads();

        const int arow = wv * 32 + c31;
        const int aswz = (arow & 7) << 4;
#pragma unroll
        for (int ks = 0; ks < 4; ++ks) {
            int cb = (ks * 32 + hi * 16) ^ aswz;
            s8v a_h = *(const s8v*)(sAH + arow * 128 + cb);
            s8v a_l = *(const s8v*)(sAL + arow * 128 + cb);
            s8v b0 = *(const s8v*)(pB0 + kt * 2048 + ks * 512);
            s8v b1 = *(const s8v*)(pB1 + kt * 2048 + ks * 512);
            acc0 = __builtin_amdgcn_mfma_f32_32x32x16_bf16(a_h, b0, acc0, 0, 0, 0);
            acc0 = __builtin_amdgcn_mfma_f32_32x32x16_bf16(a_l, b0, acc0, 0, 0, 0);
            acc1 = __builtin_amdgcn_mfma_f32_32x32x16_bf16(a_h, b1, acc1, 0, 0, 0);
            acc1 = __builtin_amdgcn_mfma_f32_32x32x16_bf16(a_l, b1, acc1, 0, 0, 0);
        }
        __syncthreads();
    }

#pragma unroll
    for (int n = 0; n < 2; ++n) {
        const f16v acc = n ? acc1 : acc0;
        int C = c0 + n * 32 + c31;
#pragma unroll
        for (int r = 0; r < 16; ++r) {
            int lrow = wv * 32 + (r & 3) + 8 * (r >> 2) + 4 * hi;
            out[(size_t)(l0 + lrow) * DD + C] = acc[r];
        }
    }
}

extern "C" void kernel_launch(void* const* d_in, const int* in_sizes, int n_in,
                              void* d_out, int out_size, void* d_ws, size_t ws_size,
                              hipStream_t stream) {
    const float* X   = (const float*)d_in[0];
    const float* W_Q = (const float*)d_in[1];
    const float* W_K = (const float*)d_in[2];
    const float* W_V = (const float*)d_in[3];
    const float* W_G = (const float*)d_in[4];
    const float* W_O = (const float*)d_in[5];
    const float* gnw = (const float*)d_in[6];
    const float* gnb = (const float*)d_in[7];

    float* ws   = (float*)d_ws;
    u16* qhp  = (u16*)(ws + WS_QH);
    u16* qlp  = (u16*)(ws + WS_QL);
    u16* khp  = (u16*)(ws + WS_KH);
    u16* klp  = (u16*)(ws + WS_KL);
    u16* vtp  = (u16*)(ws + WS_VT);
    u16* xfh  = (u16*)(ws + WS_XFH);
    u16* xfl  = (u16*)(ws + WS_XFL);
    u16* wf   = (u16*)(ws + WS_WF);
    float* gate = ws + WS_GATE;
    float* tab  = ws + WS_TAB;
    u16* ktwh = (u16*)(ws + WS_KTWH);
    u16* ktwl = (u16*)(ws + WS_KTWL);
    float* Abuf = ws + WS_XFH;         // A_state over dead Xf (2M floats)
    u16* sthp = (u16*)(ws + WS_KTWH);  // St over dead ktw
    u16* stlp = (u16*)(ws + WS_KTWL);
    u16* ggh  = (u16*)(ws + WS_XFH);   // gg over dead A_state
    u16* ggl  = (u16*)(ws + WS_XFL);
    float* out  = (float*)d_out;

    k_pre<<<2816, 256, 0, stream>>>(X, W_Q, W_K, W_V, W_G, W_O, tab, xfh, xfl, wf);
    k_fused<<<1024, 256, 0, stream>>>(xfh, xfl, wf, tab, qhp, qlp, khp, klp, vtp, gate, ktwh, ktwl);
    k_ret1<<<dim3(64, 8), 128, 0, stream>>>(vtp, ktwh, ktwl, Abuf);
    k_scan<<<128, 256, 0, stream>>>(Abuf, sthp, stlp);
    k_ret3<<<dim3(64, 8), 128, 0, stream>>>(qhp, qlp, khp, klp, vtp, sthp, stlp,
                                            gate, gnw, gnb, ggh, ggl);
    k_out<<<dim3(32, 8), 256, 0, stream>>>(ggh, ggl, wf, out);
}

// Round 7
// 92.811 us; speedup vs baseline: 1.9911x; 1.1471x over previous
//
#include <hip/hip_runtime.h>
#include <math.h>

#define LQ 4096
#define DD 512
#define NH 8
#define HS 64
#define HALF 32

typedef unsigned short u16;
typedef unsigned int u32;
typedef __attribute__((ext_vector_type(8)))  short s8v;   // 8 x bf16 (MFMA A/B frag)
typedef __attribute__((ext_vector_type(4)))  float f4v;
typedef __attribute__((ext_vector_type(4)))  u32  u32x4;
typedef __attribute__((ext_vector_type(16))) float f16v;  // 32x32 MFMA C/D

// workspace offsets (in floats)
#define WS_QH   0u
#define WS_QL   1048576u
#define WS_KH   2097152u
#define WS_KL   3145728u
#define WS_VT   4194304u
#define WS_XFH  5242880u    // frag-packed X hi; later A_state spans XFH+XFL; later Gf (frag-packed gg)
#define WS_XFL  6291456u    // frag-packed X lo
#define WS_WF   7340032u    // frag-packed W single bf16
#define WS_GATE 8650752u
#define WS_TAB  10747904u
#define WS_KTWH 11272192u   // ktw_hi; later St_hi
#define WS_KTWL 12320768u   // ktw_lo; later St_lo

__device__ inline u16 f2bf(float x) {
    unsigned int u = __float_as_uint(x);
    return (u16)((u + 0x7fffu + ((u >> 16) & 1u)) >> 16);
}
__device__ inline float bf2f(u16 h) { return __uint_as_float(((unsigned int)h) << 16); }

__device__ __forceinline__ void gld16(void* lds, const void* g) {
    __builtin_amdgcn_global_load_lds(
        (const __attribute__((address_space(1))) void*)g,
        (__attribute__((address_space(3))) void*)lds, 16, 0, 0);
}

// ---------------- merged prep: xPos tables | X->frag hi/lo | W->frag single bf16 ----------------
__global__ __launch_bounds__(256) void k_pre(
    const float* __restrict__ X,
    const float* __restrict__ Wq, const float* __restrict__ Wk, const float* __restrict__ Wv,
    const float* __restrict__ Wg, const float* __restrict__ Wo,
    float* __restrict__ tab, u16* __restrict__ Xfh, u16* __restrict__ Xfl,
    u16* __restrict__ Wf) {
    __shared__ float tile[32][33];
    const int b = blockIdx.x;
    const int t = threadIdx.x;
    if (b < 512) {
        int idx = b * 256 + t;
        if (idx >= LQ * HALF) return;
        int l = idx >> 5;
        int i = idx & 31;
        double sv  = (2.0 * i + 0.4 * (double)HS) / (1.4 * (double)HS);
        double s   = pow(sv, (double)l / 512.0);
        double invf = pow(10000.0, -(double)i / (double)HALF);
        double th  = (double)l * invf;
        double c = cos(th), sn = sin(th);
        tab[idx]                 = (float)(c * s);
        tab[LQ*HALF + idx]       = (float)(sn * s);
        tab[2*LQ*HALF + idx]     = (float)(c / s);
        tab[3*LQ*HALF + idx]     = (float)(sn / s);
    } else if (b < 1536) {
        // X -> fragment-packed hi/lo: Xf[rb:128][kt:8][ks:4][lane:64][8]
        int g = (b - 512) * 256 + t;
        int l = g >> 6;
        int d = (g & 63) * 8;
        const float* xp = X + (size_t)l * DD + d;
        f4v x0 = *(const f4v*)xp;
        f4v x1 = *(const f4v*)(xp + 4);
        s8v ph, pl;
#pragma unroll
        for (int j = 0; j < 4; ++j) {
            u16 hb = f2bf(x0[j]);
            ph[j] = (short)hb; pl[j] = (short)f2bf(x0[j] - bf2f(hb));
            u16 hb2 = f2bf(x1[j]);
            ph[j+4] = (short)hb2; pl[j+4] = (short)f2bf(x1[j] - bf2f(hb2));
        }
        int rb = l >> 5, kt = d >> 6, ks = (d >> 4) & 3, kh2 = (d >> 3) & 1;
        int lane = kh2 * 32 + (l & 31);
        size_t off = (((size_t)(rb * 8 + kt) * 4 + ks) * 64 + lane) * 8;
        *(s8v*)(Xfh + off) = ph;
        *(s8v*)(Xfl + off) = pl;
    } else {
        // weights -> fragment-packed single bf16: Wf[nb:80][kt:8][ks:4][lane:64][8]
        int bb = b - 1536;
        int d0 = (bb & 15) * 32, C0 = (bb >> 4) * 32;
        int proj = C0 >> 9;
        int tc = t & 31, tr = t >> 5;
#pragma unroll
        for (int rr = 0; rr < 4; ++rr) {
            int dl = tr + rr * 8;
            int d = d0 + dl;
            int C = C0 + tc;
            float val;
            if (proj < 3) {
                const float* W = (proj == 0) ? Wq : ((proj == 1) ? Wk : Wv);
                int h = (C & 511) >> 6, hs = C & 63;
                val = W[(size_t)h * (DD * HS) + (size_t)d * HS + hs];
            } else if (proj == 3) {
                val = Wg[(size_t)d * DD + (C & 511)];
            } else {
                val = Wo[(size_t)d * DD + (C - 2048)];
            }
            tile[dl][tc] = val;
        }
        __syncthreads();
        if (t < 128) {
            int cl = t & 31, dgq = t >> 5;
            int dl = dgq * 8;
            s8v pk;
#pragma unroll
            for (int j = 0; j < 8; ++j) pk[j] = (short)f2bf(tile[dl + j][cl]);
            int C = C0 + cl;
            int da = d0 + dl;
            int nb = C >> 5, kt = da >> 6, ks = (da >> 4) & 3, kh2 = (da >> 3) & 1;
            int lane = kh2 * 32 + (C & 31);
            size_t off = (((size_t)(nb * 8 + kt) * 4 + ks) * 64 + lane) * 8;
            *(s8v*)(Wf + off) = pk;
        }
    }
}

// ---------------- fused MFMA GEMM (frag-direct, sched-pinned pipeline) ----------------
// grid 1024 (chunked XCD swizzle), block 256 (4 waves, each 32l x 64c).
// Q,K columns (c0<1024): X hi/lo (16 MFMA/kt).  V,G columns: X hi only (8 MFMA/kt).
__global__ __launch_bounds__(256) void k_fused(
    const u16* __restrict__ Xfh, const u16* __restrict__ Xfl,
    const u16* __restrict__ Wf,
    const float* __restrict__ tab,
    u16* __restrict__ qh, u16* __restrict__ ql,
    u16* __restrict__ kh, u16* __restrict__ kl,
    u16* __restrict__ vt, float* __restrict__ gate,
    u16* __restrict__ ktwh, u16* __restrict__ ktwl) {
    __shared__ float vbuf[64 * 129];
    const int t = threadIdx.x;
    const int b = blockIdx.x;
    const int mb = (b & 7) * 4 + (b >> 8);   // 0..31
    const int cb = (b >> 3) & 31;            // 0..31
    const int l0 = mb * 128;
    const int c0 = cb * 64;
    const int wv = t >> 6;
    const int lane = t & 63;
    const int c31 = lane & 31;
    const int hi = lane >> 5;

    const int rb = mb * 4 + wv;
    const u16* pAh = Xfh + (size_t)rb * 16384 + lane * 8;
    const u16* pAl = Xfl + (size_t)rb * 16384 + lane * 8;
    const u16* pB0 = Wf + (size_t)(cb * 2) * 16384 + lane * 8;
    const u16* pB1 = pB0 + 16384;

    f16v acc0, acc1;
#pragma unroll
    for (int i = 0; i < 16; ++i) { acc0[i] = 0.f; acc1[i] = 0.f; }

    if (c0 < 1024) {
        // ---- Q,K: hi/lo A ----
        s8v ahA[4], alA[4], b0A[4], b1A[4], ahB[4], alB[4], b0B[4], b1B[4];
#define LOADQ(S, KT)                                                      \
        { _Pragma("unroll") for (int ks = 0; ks < 4; ++ks) {              \
            ah##S[ks] = *(const s8v*)(pAh + (KT) * 2048 + ks * 512);      \
            al##S[ks] = *(const s8v*)(pAl + (KT) * 2048 + ks * 512);      \
            b0##S[ks] = *(const s8v*)(pB0 + (KT) * 2048 + ks * 512);      \
            b1##S[ks] = *(const s8v*)(pB1 + (KT) * 2048 + ks * 512); } }
#define MFMAQ(S)                                                                            \
        { _Pragma("unroll") for (int ks = 0; ks < 4; ++ks) {                                \
            acc0 = __builtin_amdgcn_mfma_f32_32x32x16_bf16(ah##S[ks], b0##S[ks], acc0, 0, 0, 0); \
            acc0 = __builtin_amdgcn_mfma_f32_32x32x16_bf16(al##S[ks], b0##S[ks], acc0, 0, 0, 0); \
            acc1 = __builtin_amdgcn_mfma_f32_32x32x16_bf16(ah##S[ks], b1##S[ks], acc1, 0, 0, 0); \
            acc1 = __builtin_amdgcn_mfma_f32_32x32x16_bf16(al##S[ks], b1##S[ks], acc1, 0, 0, 0); } }
        LOADQ(A, 0)
#pragma unroll
        for (int kp = 0; kp < 4; ++kp) {
            LOADQ(B, 2 * kp + 1)
            __builtin_amdgcn_sched_barrier(0);
            MFMAQ(A)
            if (kp < 3) { LOADQ(A, 2 * kp + 2) }
            __builtin_amdgcn_sched_barrier(0);
            MFMAQ(B)
        }
#undef LOADQ
#undef MFMAQ
    } else {
        // ---- V,G: single-bf16 A ----
        s8v ahA[4], b0A[4], b1A[4], ahB[4], b0B[4], b1B[4];
#define LOADS(S, KT)                                                      \
        { _Pragma("unroll") for (int ks = 0; ks < 4; ++ks) {              \
            ah##S[ks] = *(const s8v*)(pAh + (KT) * 2048 + ks * 512);      \
            b0##S[ks] = *(const s8v*)(pB0 + (KT) * 2048 + ks * 512);      \
            b1##S[ks] = *(const s8v*)(pB1 + (KT) * 2048 + ks * 512); } }
#define MFMAS(S)                                                                            \
        { _Pragma("unroll") for (int ks = 0; ks < 4; ++ks) {                                \
            acc0 = __builtin_amdgcn_mfma_f32_32x32x16_bf16(ah##S[ks], b0##S[ks], acc0, 0, 0, 0); \
            acc1 = __builtin_amdgcn_mfma_f32_32x32x16_bf16(ah##S[ks], b1##S[ks], acc1, 0, 0, 0); } }
        LOADS(A, 0)
#pragma unroll
        for (int kp = 0; kp < 4; ++kp) {
            LOADS(B, 2 * kp + 1)
            __builtin_amdgcn_sched_barrier(0);
            MFMAS(A)
            if (kp < 3) { LOADS(A, 2 * kp + 2) }
            __builtin_amdgcn_sched_barrier(0);
            MFMAS(B)
        }
#undef LOADS
#undef MFMAS
    }

    const int proj = c0 >> 9;
    if (proj < 2) {
        const float* ct = tab + (proj ? 2 * LQ * HALF : 0);
        const float* st = tab + (proj ? 3 * LQ * HALF : LQ * HALF);
        u16* oh = proj ? kh : qh;
        u16* ol = proj ? kl : ql;
        const int hh = (c0 & 511) >> 6;
        float lgf = 0.f;
        if (proj == 1) {
            double lg = -3.4657359027997265 + (double)hh * (-2.772588722239781 / 7.0);
            lgf = (float)(log(1.0 - exp(lg)) * 1.4426950408889634);
        }
#pragma unroll
        for (int n = 0; n < 2; ++n) {
            const f16v acc = n ? acc1 : acc0;
            int C = c0 + n * 32 + c31;
            int hs = C & 63, i2 = hs >> 1;
            float sgn = (hs & 1) ? 1.f : -1.f;
#pragma unroll
            for (int r = 0; r < 16; ++r) {
                int lrow = wv * 32 + (r & 3) + 8 * (r >> 2) + 4 * hi;
                int pos = l0 + lrow;
                float val = acc[r];
                float part = __shfl_xor(val, 1);
                float res = val * ct[pos * HALF + i2] + sgn * part * st[pos * HALF + i2];
                u16 hb = f2bf(res);
                size_t o = ((size_t)hh * LQ + pos) * HS + hs;
                oh[o] = hb;
                ol[o] = f2bf(res - bf2f(hb));
                if (proj == 1) {
                    float wf = exp2f(lgf * (float)(64 - (pos & 63)));   // gamma^(64-m')
                    vbuf[(n * 32 + c31) * 129 + lrow] = res * wf;
                }
            }
        }
        if (proj == 1) {
            __syncthreads();
            int cl = t >> 2, lseg = (t & 3) * 32;
            size_t o = ((size_t)hh * HS + cl) * LQ + l0 + lseg;
#pragma unroll
            for (int ch4 = 0; ch4 < 4; ++ch4) {
                s8v pkh, pkl;
#pragma unroll
                for (int j = 0; j < 8; ++j) {
                    float v = vbuf[cl * 129 + lseg + ch4 * 8 + j];
                    u16 hb = f2bf(v);
                    pkh[j] = (short)hb;
                    pkl[j] = (short)f2bf(v - bf2f(hb));
                }
                *(s8v*)(ktwh + o + ch4 * 8) = pkh;
                *(s8v*)(ktwl + o + ch4 * 8) = pkl;
            }
        }
    } else if (proj == 2) {
#pragma unroll
        for (int n = 0; n < 2; ++n) {
            const f16v acc = n ? acc1 : acc0;
            int cl = n * 32 + c31;
#pragma unroll
            for (int r = 0; r < 16; ++r) {
                int lrow = wv * 32 + (r & 3) + 8 * (r >> 2) + 4 * hi;
                vbuf[cl * 129 + lrow] = acc[r];
            }
        }
        __syncthreads();
        int h = (c0 & 511) >> 6;
        int cl = t >> 2, lseg = (t & 3) * 32;
        size_t o = ((size_t)h * HS + cl) * LQ + l0 + lseg;
#pragma unroll
        for (int ch = 0; ch < 4; ++ch) {
            s8v pk;
#pragma unroll
            for (int j = 0; j < 8; ++j) pk[j] = (short)f2bf(vbuf[cl * 129 + lseg + ch * 8 + j]);
            *(s8v*)(vt + o + ch * 8) = pk;
        }
    } else {
#pragma unroll
        for (int n = 0; n < 2; ++n) {
            const f16v acc = n ? acc1 : acc0;
            int C = (c0 & 511) + n * 32 + c31;
#pragma unroll
            for (int r = 0; r < 16; ++r) {
                int lrow = wv * 32 + (r & 3) + 8 * (r >> 2) + 4 * hi;
                float vv = acc[r];
                gate[(size_t)(l0 + lrow) * DD + C] = vv / (1.f + expf(-vv));
            }
        }
    }
}

// ---------------- pass1: per-chunk state A^T[ch][d] = sum_m g^(64-m) v[m][ch] k[m][d] ----------------
__global__ __launch_bounds__(128) void k_ret1(
    const u16* __restrict__ vt, const u16* __restrict__ ktwh, const u16* __restrict__ ktwl,
    float* __restrict__ A) {
    const int t = threadIdx.x;
    const int c = blockIdx.x;
    const int h = blockIdx.y;
    const int wv = t >> 6, lane = t & 63, c31 = lane & 31, hi = lane >> 5;

    s8v va[4];
    const u16* vp = vt + ((size_t)h * 64 + wv * 32 + c31) * LQ + c * 64 + hi * 8;
#pragma unroll
    for (int ks = 0; ks < 4; ++ks) va[ks] = *(const s8v*)(vp + ks * 16);

    f16v a0, a1;
#pragma unroll
    for (int i = 0; i < 16; ++i) { a0[i] = 0.f; a1[i] = 0.f; }

    const size_t kbase = ((size_t)h * 64 + c31) * LQ + c * 64 + hi * 8;
#pragma unroll
    for (int ks = 0; ks < 4; ++ks) {
        s8v b0h = *(const s8v*)(ktwh + kbase + ks * 16);
        s8v b0l = *(const s8v*)(ktwl + kbase + ks * 16);
        s8v b1h = *(const s8v*)(ktwh + kbase + (size_t)32 * LQ + ks * 16);
        s8v b1l = *(const s8v*)(ktwl + kbase + (size_t)32 * LQ + ks * 16);
        a0 = __builtin_amdgcn_mfma_f32_32x32x16_bf16(va[ks], b0h, a0, 0, 0, 0);
        a0 = __builtin_amdgcn_mfma_f32_32x32x16_bf16(va[ks], b0l, a0, 0, 0, 0);
        a1 = __builtin_amdgcn_mfma_f32_32x32x16_bf16(va[ks], b1h, a1, 0, 0, 0);
        a1 = __builtin_amdgcn_mfma_f32_32x32x16_bf16(va[ks], b1l, a1, 0, 0, 0);
    }

    float* Ab = A + ((size_t)h * 64 + c) * 4096;
#pragma unroll
    for (int r = 0; r < 16; ++r) {
        int ch = wv * 32 + (r & 3) + 8 * (r >> 2) + 4 * hi;
        Ab[ch * 64 + c31]      = a0[r];
        Ab[ch * 64 + 32 + c31] = a1[r];
    }
}

// ---------------- pass2: weighted prefix scan over chunks -> S^T hi/lo bf16 ----------------
__global__ __launch_bounds__(256) void k_scan(
    const float* __restrict__ A, u16* __restrict__ sth, u16* __restrict__ stl) {
    const int bx = blockIdx.x;
    const int h = bx >> 4;
    const int e = (bx & 15) * 256 + threadIdx.x;
    double lg = -3.4657359027997265 + (double)h * (-2.772588722239781 / 7.0);
    double gamma = 1.0 - exp(lg);
    float g64 = (float)pow(gamma, 64.0);
    const float* Ab = A + (size_t)h * 64 * 4096 + e;
    u16* shb = sth + (size_t)h * 64 * 4096 + e;
    u16* slb = stl + (size_t)h * 64 * 4096 + e;
    float s = 0.f;
    for (int cc = 0; cc < 64; ++cc) {
        if (cc) {
            u16 hb = f2bf(s);
            shb[(size_t)cc * 4096] = hb;
            slb[(size_t)cc * 4096] = f2bf(s - bf2f(hb));
        }
        s = fmaf(g64, s, Ab[(size_t)cc * 4096]);
    }
}

// ---------------- pass3: retention chunk + fused GroupNorm*gate -> frag-packed gg (single bf16) ----------------
__global__ __launch_bounds__(128) void k_ret3(
    const u16* __restrict__ qh, const u16* __restrict__ ql,
    const u16* __restrict__ kh, const u16* __restrict__ kl,
    const u16* __restrict__ vt,
    const u16* __restrict__ sth, const u16* __restrict__ stl,
    const float* __restrict__ gate,
    const float* __restrict__ gw, const float* __restrict__ gb,
    u16* __restrict__ Gf) {
    __shared__ __align__(16) char sBuf[24576];   // KH 8K | KL 8K | VT 8K; later gT[64][65] f32
    const int t = threadIdx.x;
    const int c = blockIdx.x;
    const int h = blockIdx.y;
    const int wv = t >> 6, lane = t & 63, c31 = lane & 31, hi = lane >> 5;
    const int l0q = c * 64;

    double lg = -3.4657359027997265 + (double)h * (-2.772588722239781 / 7.0);
    double gamma = 1.0 - exp(lg);
    float lgf = (float)(log(gamma) * 1.4426950408889634);
    float c1a[4], c8a[4];
#pragma unroll
    for (int m = 0; m < 4; ++m) { c1a[m] = exp2f(-lgf * (float)m); c8a[m] = exp2f(-lgf * (float)(8 * m)); }

    s8v qhf[4], qlf[4];
    {
        const u16* qph = qh + ((size_t)h * LQ + l0q + wv * 32 + c31) * HS + hi * 8;
        const u16* qpl = ql + ((size_t)h * LQ + l0q + wv * 32 + c31) * HS + hi * 8;
#pragma unroll
        for (int ks = 0; ks < 4; ++ks) {
            qhf[ks] = *(const s8v*)(qph + ks * 16);
            qlf[ks] = *(const s8v*)(qpl + ks * 16);
        }
    }

    {
        const char* gKH = (const char*)kh + ((size_t)h * LQ + l0q) * 128;
        const char* gKL = (const char*)kl + ((size_t)h * LQ + l0q) * 128;
        const char* gVT = (const char*)vt + ((size_t)h * 64) * 8192 + l0q * 2;
#pragma unroll
        for (int i_ = 0; i_ < 12; ++i_) {
            int boff = wv * 12288 + i_ * 1024 + lane * 16;
            int seg = boff >> 13;
            int o_ = boff & 8191;
            int osrc = o_ ^ (((o_ >> 7) & 7) << 4);
            const char* src = (seg == 0) ? gKH + osrc
                            : (seg == 1) ? gKL + osrc
                            : gVT + (size_t)(osrc >> 7) * 8192 + (osrc & 127);
            gld16(sBuf + wv * 12288 + i_ * 1024, src);
        }
    }

    f16v qs0, qs1;
#pragma unroll
    for (int i = 0; i < 16; ++i) { qs0[i] = 0.f; qs1[i] = 0.f; }
    if (c > 0) {
        const u16* sbh = sth + ((size_t)h * 64 + c) * 4096;
        const u16* sbl = stl + ((size_t)h * 64 + c) * 4096;
#pragma unroll
        for (int ks = 0; ks < 4; ++ks) {
            int off0 = c31 * 64 + ks * 16 + hi * 8;
            int off1 = (32 + c31) * 64 + ks * 16 + hi * 8;
            s8v b0h = *(const s8v*)(sbh + off0);
            s8v b0l = *(const s8v*)(sbl + off0);
            s8v b1h = *(const s8v*)(sbh + off1);
            s8v b1l = *(const s8v*)(sbl + off1);
            qs0 = __builtin_amdgcn_mfma_f32_32x32x16_bf16(qhf[ks], b0h, qs0, 0, 0, 0);
            qs0 = __builtin_amdgcn_mfma_f32_32x32x16_bf16(qhf[ks], b0l, qs0, 0, 0, 0);
            qs0 = __builtin_amdgcn_mfma_f32_32x32x16_bf16(qlf[ks], b0h, qs0, 0, 0, 0);
            qs1 = __builtin_amdgcn_mfma_f32_32x32x16_bf16(qhf[ks], b1h, qs1, 0, 0, 0);
            qs1 = __builtin_amdgcn_mfma_f32_32x32x16_bf16(qhf[ks], b1l, qs1, 0, 0, 0);
            qs1 = __builtin_amdgcn_mfma_f32_32x32x16_bf16(qlf[ks], b1h, qs1, 0, 0, 0);
        }
    }

    asm volatile("s_waitcnt vmcnt(0)" ::: "memory");
    __syncthreads();

    f16v acc0, acc1;
#pragma unroll
    for (int i = 0; i < 16; ++i) { acc0[i] = 0.f; acc1[i] = 0.f; }
    const char* bKH = sBuf;
    const char* bKL = sBuf + 8192;
    const char* bVT = sBuf + 16384;

#pragma unroll
    for (int jt = 0; jt < 2; ++jt) {
        if (wv == 0 && jt == 1) break;
        f16v sacc;
#pragma unroll
        for (int i = 0; i < 16; ++i) sacc[i] = 0.f;
#pragma unroll
        for (int ks = 0; ks < 4; ++ks) {
            int krow = jt * 32 + c31;
            int ph = krow * 128 + ((ks * 32 + hi * 16) ^ ((krow & 7) << 4));
            s8v ah = *(const s8v*)(bKH + ph);
            s8v al = *(const s8v*)(bKL + ph);
            sacc = __builtin_amdgcn_mfma_f32_32x32x16_bf16(ah, qhf[ks], sacc, 0, 0, 0);
            sacc = __builtin_amdgcn_mfma_f32_32x32x16_bf16(ah, qlf[ks], sacc, 0, 0, 0);
            sacc = __builtin_amdgcn_mfma_f32_32x32x16_bf16(al, qhf[ks], sacc, 0, 0, 0);
        }
        const int D0 = (wv * 32 + c31) - jt * 32;
        float base = exp2f(lgf * (float)(D0 - 4 * hi));
        u32 w[8];
#pragma unroll
        for (int g = 0; g < 4; ++g) {
            float wg = base * c8a[g];
            float v0 = sacc[4 * g + 0] * (wg * c1a[0]);
            float v1 = sacc[4 * g + 1] * (wg * c1a[1]);
            float v2 = sacc[4 * g + 2] * (wg * c1a[2]);
            float v3 = sacc[4 * g + 3] * (wg * c1a[3]);
            int jr = 8 * g + 4 * hi;
            if (D0 - (jr + 0) < 0) v0 = 0.f;
            if (D0 - (jr + 1) < 0) v1 = 0.f;
            if (D0 - (jr + 2) < 0) v2 = 0.f;
            if (D0 - (jr + 3) < 0) v3 = 0.f;
            w[2 * g]     = (u32)f2bf(v0) | ((u32)f2bf(v1) << 16);
            w[2 * g + 1] = (u32)f2bf(v2) | ((u32)f2bf(v3) << 16);
        }
        u32 e0 = __shfl_xor(hi ? w[0] : w[2], 32);
        u32 e1 = __shfl_xor(hi ? w[1] : w[3], 32);
        u32 e2 = __shfl_xor(hi ? w[4] : w[6], 32);
        u32 e3 = __shfl_xor(hi ? w[5] : w[7], 32);
        u32x4 a0v = { hi ? e0 : w[0], hi ? e1 : w[1], hi ? w[2] : e0, hi ? w[3] : e1 };
        u32x4 a1v = { hi ? e2 : w[4], hi ? e3 : w[5], hi ? w[6] : e2, hi ? w[7] : e3 };
        s8v af0 = __builtin_bit_cast(s8v, a0v);
        s8v af1 = __builtin_bit_cast(s8v, a1v);
#pragma unroll
        for (int ksl = 0; ksl < 2; ++ksl) {
            s8v af = ksl ? af1 : af0;
            int cb = (jt * 2 + ksl) * 32 + hi * 16;
            int r0 = c31;
            s8v vb0 = *(const s8v*)(bVT + r0 * 128 + (cb ^ ((r0 & 7) << 4)));
            int r1 = 32 + c31;
            s8v vb1 = *(const s8v*)(bVT + r1 * 128 + (cb ^ ((r1 & 7) << 4)));
            acc0 = __builtin_amdgcn_mfma_f32_32x32x16_bf16(af, vb0, acc0, 0, 0, 0);
            acc1 = __builtin_amdgcn_mfma_f32_32x32x16_bf16(af, vb1, acc1, 0, 0, 0);
        }
    }

    // epilogue: combine inter+intra, GroupNorm, *gate -> LDS transpose -> frag-packed single-bf16 gg
    __syncthreads();                    // all sBuf (K/V) reads done before alias
    float* gT = (float*)sBuf;           // [64][65] f32
    const float gw0 = gw[h * HS + c31],      gw1 = gw[h * HS + 32 + c31];
    const float gb0 = gb[h * HS + c31],      gb1 = gb[h * HS + 32 + c31];
#pragma unroll
    for (int r = 0; r < 16; ++r) {
        int row = (r & 3) + 8 * (r >> 2) + 4 * hi;
        int nloc = wv * 32 + row;
        float sc = exp2f(lgf * (float)nloc);
        float v0 = acc0[r] + sc * qs0[r];
        float v1 = acc1[r] + sc * qs1[r];
        float s = v0 + v1, ss = v0 * v0 + v1 * v1;
#pragma unroll
        for (int off = 1; off < 32; off <<= 1) {
            s  += __shfl_xor(s, off);
            ss += __shfl_xor(ss, off);
        }
        float mean = s * (1.f / 64.f);
        float var = ss * (1.f / 64.f) - mean * mean;
        float inv = rsqrtf(var + 1e-5f);
        size_t o = (size_t)(l0q + nloc) * DD + h * HS;
        float g0 = ((v0 - mean) * inv * gw0 + gb0) * gate[o + c31];
        float g1 = ((v1 - mean) * inv * gw1 + gb1) * gate[o + 32 + c31];
        gT[nloc * 65 + c31]      = g0;
        gT[nloc * 65 + 32 + c31] = g1;
    }
    __syncthreads();
#pragma unroll
    for (int i = 0; i < 4; ++i) {
        int u = t + i * 128;            // 0..511
        int rbl = u >> 8;
        int ks = (u >> 6) & 3;
        int ln = u & 63;
        int row = rbl * 32 + (ln & 31);
        int ch = ks * 16 + (ln >> 5) * 8;
        s8v pk;
#pragma unroll
        for (int j = 0; j < 8; ++j) pk[j] = (short)f2bf(gT[row * 65 + ch + j]);
        size_t off = ((((size_t)(c * 2 + rbl) * 8 + h) * 4 + ks) * 64 + ln) * 8;
        *(s8v*)(Gf + off) = pk;
    }
}

// ---------------- out = gg @ W_O (both operands frag-direct, sched-pinned) ----------------
__global__ __launch_bounds__(256) void k_out(
    const u16* __restrict__ Gf, const u16* __restrict__ Wf,
    float* __restrict__ out) {
    const int t = threadIdx.x;
    const int l0 = blockIdx.x * 128;
    const int c0 = blockIdx.y * 64;
    const int wv = t >> 6;
    const int lane = t & 63;
    const int c31 = lane & 31;
    const int hi = lane >> 5;

    const int rb = blockIdx.x * 4 + wv;
    const u16* pA  = Gf + (size_t)rb * 16384 + lane * 8;
    const u16* pB0 = Wf + (size_t)(64 + (c0 >> 5)) * 16384 + lane * 8;
    const u16* pB1 = pB0 + 16384;

    f16v acc0, acc1;
#pragma unroll
    for (int i = 0; i < 16; ++i) { acc0[i] = 0.f; acc1[i] = 0.f; }

    s8v aA[4], b0A[4], b1A[4], aB[4], b0B[4], b1B[4];
#define LOADO(S, KT)                                                      \
    { _Pragma("unroll") for (int ks = 0; ks < 4; ++ks) {                  \
        a##S[ks]  = *(const s8v*)(pA  + (KT) * 2048 + ks * 512);          \
        b0##S[ks] = *(const s8v*)(pB0 + (KT) * 2048 + ks * 512);          \
        b1##S[ks] = *(const s8v*)(pB1 + (KT) * 2048 + ks * 512); } }
#define MFMAO(S)                                                                            \
    { _Pragma("unroll") for (int ks = 0; ks < 4; ++ks) {                                    \
        acc0 = __builtin_amdgcn_mfma_f32_32x32x16_bf16(a##S[ks], b0##S[ks], acc0, 0, 0, 0); \
        acc1 = __builtin_amdgcn_mfma_f32_32x32x16_bf16(a##S[ks], b1##S[ks], acc1, 0, 0, 0); } }
    LOADO(A, 0)
#pragma unroll
    for (int kp = 0; kp < 4; ++kp) {
        LOADO(B, 2 * kp + 1)
        __builtin_amdgcn_sched_barrier(0);
        MFMAO(A)
        if (kp < 3) { LOADO(A, 2 * kp + 2) }
        __builtin_amdgcn_sched_barrier(0);
        MFMAO(B)
    }
#undef LOADO
#undef MFMAO

#pragma unroll
    for (int n = 0; n < 2; ++n) {
        const f16v acc = n ? acc1 : acc0;
        int C = c0 + n * 32 + c31;
#pragma unroll
        for (int r = 0; r < 16; ++r) {
            int lrow = wv * 32 + (r & 3) + 8 * (r >> 2) + 4 * hi;
            out[(size_t)(l0 + lrow) * DD + C] = acc[r];
        }
    }
}

extern "C" void kernel_launch(void* const* d_in, const int* in_sizes, int n_in,
                              void* d_out, int out_size, void* d_ws, size_t ws_size,
                              hipStream_t stream) {
    const float* X   = (const float*)d_in[0];
    const float* W_Q = (const float*)d_in[1];
    const float* W_K = (const float*)d_in[2];
    const float* W_V = (const float*)d_in[3];
    const float* W_G = (const float*)d_in[4];
    const float* W_O = (const float*)d_in[5];
    const float* gnw = (const float*)d_in[6];
    const float* gnb = (const float*)d_in[7];

    float* ws   = (float*)d_ws;
    u16* qhp  = (u16*)(ws + WS_QH);
    u16* qlp  = (u16*)(ws + WS_QL);
    u16* khp  = (u16*)(ws + WS_KH);
    u16* klp  = (u16*)(ws + WS_KL);
    u16* vtp  = (u16*)(ws + WS_VT);
    u16* xfh  = (u16*)(ws + WS_XFH);
    u16* xfl  = (u16*)(ws + WS_XFL);
    u16* wf   = (u16*)(ws + WS_WF);
    float* gate = ws + WS_GATE;
    float* tab  = ws + WS_TAB;
    u16* ktwh = (u16*)(ws + WS_KTWH);
    u16* ktwl = (u16*)(ws + WS_KTWL);
    float* Abuf = ws + WS_XFH;         // A_state over dead Xf (2M floats)
    u16* sthp = (u16*)(ws + WS_KTWH);  // St over dead ktw
    u16* stlp = (u16*)(ws + WS_KTWL);
    u16* Gfp  = (u16*)(ws + WS_XFH);   // frag-packed gg over dead A_state
    float* out  = (float*)d_out;

    k_pre<<<2816, 256, 0, stream>>>(X, W_Q, W_K, W_V, W_G, W_O, tab, xfh, xfl, wf);
    k_fused<<<1024, 256, 0, stream>>>(xfh, xfl, wf, tab, qhp, qlp, khp, klp, vtp, gate, ktwh, ktwl);
    k_ret1<<<dim3(64, 8), 128, 0, stream>>>(vtp, ktwh, ktwl, Abuf);
    k_scan<<<128, 256, 0, stream>>>(Abuf, sthp, stlp);
    k_ret3<<<dim3(64, 8), 128, 0, stream>>>(qhp, qlp, khp, klp, vtp, sthp, stlp,
                                            gate, gnw, gnb, Gfp);
    k_out<<<dim3(32, 8), 256, 0, stream>>>(Gfp, wf, out);
}

// Round 8
// 84.759 us; speedup vs baseline: 2.1802x; 1.0950x over previous
//
#include <hip/hip_runtime.h>
#include <math.h>

#define LQ 4096
#define DD 512
#define NH 8
#define HS 64
#define HALF 32

typedef unsigned short u16;
typedef unsigned int u32;
typedef __attribute__((ext_vector_type(8)))  short s8v;   // 8 x bf16 (MFMA A/B frag)
typedef __attribute__((ext_vector_type(4)))  float f4v;
typedef __attribute__((ext_vector_type(4)))  u32  u32x4;
typedef __attribute__((ext_vector_type(16))) float f16v;  // 32x32 MFMA C/D

// workspace offsets (in floats)
#define WS_QH   0u
#define WS_QL   1048576u
#define WS_KH   2097152u
#define WS_KL   3145728u
#define WS_VT   4194304u
#define WS_XFH  5242880u    // frag-packed X hi; later A_state spans XFH+XFL; later Gf
#define WS_XFL  6291456u    // frag-packed X lo
#define WS_WF   7340032u    // frag-packed W single bf16
#define WS_GATE 8650752u    // gate as bf16 (u16), 2M u16
#define WS_TAB  10747904u
#define WS_KTWH 11272192u   // ktw_hi; later St_hi
#define WS_KTWL 12320768u   // ktw_lo; later St_lo

__device__ inline u16 f2bf(float x) {
    unsigned int u = __float_as_uint(x);
    return (u16)((u + 0x7fffu + ((u >> 16) & 1u)) >> 16);
}
__device__ inline float bf2f(u16 h) { return __uint_as_float(((unsigned int)h) << 16); }

__device__ __forceinline__ void gld16(void* lds, const void* g) {
    __builtin_amdgcn_global_load_lds(
        (const __attribute__((address_space(1))) void*)g,
        (__attribute__((address_space(3))) void*)lds, 16, 0, 0);
}

// ---------------- merged prep: xPos tables | X->frag hi/lo | W->frag single bf16 ----------------
__global__ __launch_bounds__(256) void k_pre(
    const float* __restrict__ X,
    const float* __restrict__ Wq, const float* __restrict__ Wk, const float* __restrict__ Wv,
    const float* __restrict__ Wg, const float* __restrict__ Wo,
    float* __restrict__ tab, u16* __restrict__ Xfh, u16* __restrict__ Xfl,
    u16* __restrict__ Wf) {
    __shared__ float tile[32][33];
    const int b = blockIdx.x;
    const int t = threadIdx.x;
    if (b < 512) {
        int idx = b * 256 + t;
        if (idx >= LQ * HALF) return;
        int l = idx >> 5;
        int i = idx & 31;
        double sv  = (2.0 * i + 0.4 * (double)HS) / (1.4 * (double)HS);
        double s   = pow(sv, (double)l / 512.0);
        double invf = pow(10000.0, -(double)i / (double)HALF);
        double th  = (double)l * invf;
        double c = cos(th), sn = sin(th);
        tab[idx]                 = (float)(c * s);
        tab[LQ*HALF + idx]       = (float)(sn * s);
        tab[2*LQ*HALF + idx]     = (float)(c / s);
        tab[3*LQ*HALF + idx]     = (float)(sn / s);
    } else if (b < 1536) {
        // X -> fragment-packed hi/lo: Xf[rb:128][kt:8][ks:4][lane:64][8]
        int g = (b - 512) * 256 + t;
        int l = g >> 6;
        int d = (g & 63) * 8;
        const float* xp = X + (size_t)l * DD + d;
        f4v x0 = *(const f4v*)xp;
        f4v x1 = *(const f4v*)(xp + 4);
        s8v ph, pl;
#pragma unroll
        for (int j = 0; j < 4; ++j) {
            u16 hb = f2bf(x0[j]);
            ph[j] = (short)hb; pl[j] = (short)f2bf(x0[j] - bf2f(hb));
            u16 hb2 = f2bf(x1[j]);
            ph[j+4] = (short)hb2; pl[j+4] = (short)f2bf(x1[j] - bf2f(hb2));
        }
        int rb = l >> 5, kt = d >> 6, ks = (d >> 4) & 3, kh2 = (d >> 3) & 1;
        int lane = kh2 * 32 + (l & 31);
        size_t off = (((size_t)(rb * 8 + kt) * 4 + ks) * 64 + lane) * 8;
        *(s8v*)(Xfh + off) = ph;
        *(s8v*)(Xfl + off) = pl;
    } else {
        // weights -> fragment-packed single bf16: Wf[nb:80][kt:8][ks:4][lane:64][8]
        int bb = b - 1536;
        int d0 = (bb & 15) * 32, C0 = (bb >> 4) * 32;
        int proj = C0 >> 9;
        int tc = t & 31, tr = t >> 5;
#pragma unroll
        for (int rr = 0; rr < 4; ++rr) {
            int dl = tr + rr * 8;
            int d = d0 + dl;
            int C = C0 + tc;
            float val;
            if (proj < 3) {
                const float* W = (proj == 0) ? Wq : ((proj == 1) ? Wk : Wv);
                int h = (C & 511) >> 6, hs = C & 63;
                val = W[(size_t)h * (DD * HS) + (size_t)d * HS + hs];
            } else if (proj == 3) {
                val = Wg[(size_t)d * DD + (C & 511)];
            } else {
                val = Wo[(size_t)d * DD + (C - 2048)];
            }
            tile[dl][tc] = val;
        }
        __syncthreads();
        if (t < 128) {
            int cl = t & 31, dgq = t >> 5;
            int dl = dgq * 8;
            s8v pk;
#pragma unroll
            for (int j = 0; j < 8; ++j) pk[j] = (short)f2bf(tile[dl + j][cl]);
            int C = C0 + cl;
            int da = d0 + dl;
            int nb = C >> 5, kt = da >> 6, ks = (da >> 4) & 3, kh2 = (da >> 3) & 1;
            int lane = kh2 * 32 + (C & 31);
            size_t off = (((size_t)(nb * 8 + kt) * 4 + ks) * 64 + lane) * 8;
            *(s8v*)(Wf + off) = pk;
        }
    }
}

// ---------------- fused MFMA GEMM (frag-direct, sched-pinned pipeline) ----------------
__global__ __launch_bounds__(256) void k_fused(
    const u16* __restrict__ Xfh, const u16* __restrict__ Xfl,
    const u16* __restrict__ Wf,
    const float* __restrict__ tab,
    u16* __restrict__ qh, u16* __restrict__ ql,
    u16* __restrict__ kh, u16* __restrict__ kl,
    u16* __restrict__ vt, u16* __restrict__ gate16,
    u16* __restrict__ ktwh, u16* __restrict__ ktwl) {
    __shared__ float vbuf[64 * 129];
    const int t = threadIdx.x;
    const int b = blockIdx.x;
    const int mb = (b & 7) * 4 + (b >> 8);   // 0..31
    const int cb = (b >> 3) & 31;            // 0..31
    const int l0 = mb * 128;
    const int c0 = cb * 64;
    const int wv = t >> 6;
    const int lane = t & 63;
    const int c31 = lane & 31;
    const int hi = lane >> 5;

    const int rb = mb * 4 + wv;
    const u16* pAh = Xfh + (size_t)rb * 16384 + lane * 8;
    const u16* pAl = Xfl + (size_t)rb * 16384 + lane * 8;
    const u16* pB0 = Wf + (size_t)(cb * 2) * 16384 + lane * 8;
    const u16* pB1 = pB0 + 16384;

    f16v acc0, acc1;
#pragma unroll
    for (int i = 0; i < 16; ++i) { acc0[i] = 0.f; acc1[i] = 0.f; }

    if (c0 < 1024) {
        s8v ahA[4], alA[4], b0A[4], b1A[4], ahB[4], alB[4], b0B[4], b1B[4];
#define LOADQ(S, KT)                                                      \
        { _Pragma("unroll") for (int ks = 0; ks < 4; ++ks) {              \
            ah##S[ks] = *(const s8v*)(pAh + (KT) * 2048 + ks * 512);      \
            al##S[ks] = *(const s8v*)(pAl + (KT) * 2048 + ks * 512);      \
            b0##S[ks] = *(const s8v*)(pB0 + (KT) * 2048 + ks * 512);      \
            b1##S[ks] = *(const s8v*)(pB1 + (KT) * 2048 + ks * 512); } }
#define MFMAQ(S)                                                                            \
        { _Pragma("unroll") for (int ks = 0; ks < 4; ++ks) {                                \
            acc0 = __builtin_amdgcn_mfma_f32_32x32x16_bf16(ah##S[ks], b0##S[ks], acc0, 0, 0, 0); \
            acc0 = __builtin_amdgcn_mfma_f32_32x32x16_bf16(al##S[ks], b0##S[ks], acc0, 0, 0, 0); \
            acc1 = __builtin_amdgcn_mfma_f32_32x32x16_bf16(ah##S[ks], b1##S[ks], acc1, 0, 0, 0); \
            acc1 = __builtin_amdgcn_mfma_f32_32x32x16_bf16(al##S[ks], b1##S[ks], acc1, 0, 0, 0); } }
        LOADQ(A, 0)
#pragma unroll
        for (int kp = 0; kp < 4; ++kp) {
            LOADQ(B, 2 * kp + 1)
            __builtin_amdgcn_sched_barrier(0);
            MFMAQ(A)
            if (kp < 3) { LOADQ(A, 2 * kp + 2) }
            __builtin_amdgcn_sched_barrier(0);
            MFMAQ(B)
        }
#undef LOADQ
#undef MFMAQ
    } else {
        s8v ahA[4], b0A[4], b1A[4], ahB[4], b0B[4], b1B[4];
#define LOADS(S, KT)                                                      \
        { _Pragma("unroll") for (int ks = 0; ks < 4; ++ks) {              \
            ah##S[ks] = *(const s8v*)(pAh + (KT) * 2048 + ks * 512);      \
            b0##S[ks] = *(const s8v*)(pB0 + (KT) * 2048 + ks * 512);      \
            b1##S[ks] = *(const s8v*)(pB1 + (KT) * 2048 + ks * 512); } }
#define MFMAS(S)                                                                            \
        { _Pragma("unroll") for (int ks = 0; ks < 4; ++ks) {                                \
            acc0 = __builtin_amdgcn_mfma_f32_32x32x16_bf16(ah##S[ks], b0##S[ks], acc0, 0, 0, 0); \
            acc1 = __builtin_amdgcn_mfma_f32_32x32x16_bf16(ah##S[ks], b1##S[ks], acc1, 0, 0, 0); } }
        LOADS(A, 0)
#pragma unroll
        for (int kp = 0; kp < 4; ++kp) {
            LOADS(B, 2 * kp + 1)
            __builtin_amdgcn_sched_barrier(0);
            MFMAS(A)
            if (kp < 3) { LOADS(A, 2 * kp + 2) }
            __builtin_amdgcn_sched_barrier(0);
            MFMAS(B)
        }
#undef LOADS
#undef MFMAS
    }

    const int proj = c0 >> 9;
    if (proj < 2) {
        const float* ct = tab + (proj ? 2 * LQ * HALF : 0);
        const float* st = tab + (proj ? 3 * LQ * HALF : LQ * HALF);
        u16* oh = proj ? kh : qh;
        u16* ol = proj ? kl : ql;
        const int hh = (c0 & 511) >> 6;
        float lgf = 0.f;
        if (proj == 1) {
            double lg = -3.4657359027997265 + (double)hh * (-2.772588722239781 / 7.0);
            lgf = (float)(log(1.0 - exp(lg)) * 1.4426950408889634);
        }
#pragma unroll
        for (int n = 0; n < 2; ++n) {
            const f16v acc = n ? acc1 : acc0;
            int C = c0 + n * 32 + c31;
            int hs = C & 63, i2 = hs >> 1;
            float sgn = (hs & 1) ? 1.f : -1.f;
#pragma unroll
            for (int r = 0; r < 16; ++r) {
                int lrow = wv * 32 + (r & 3) + 8 * (r >> 2) + 4 * hi;
                int pos = l0 + lrow;
                float val = acc[r];
                float part = __shfl_xor(val, 1);
                float res = val * ct[pos * HALF + i2] + sgn * part * st[pos * HALF + i2];
                u16 hb = f2bf(res);
                size_t o = ((size_t)hh * LQ + pos) * HS + hs;
                oh[o] = hb;
                ol[o] = f2bf(res - bf2f(hb));
                if (proj == 1) {
                    float wf = exp2f(lgf * (float)(64 - (pos & 63)));   // gamma^(64-m')
                    vbuf[(n * 32 + c31) * 129 + lrow] = res * wf;
                }
            }
        }
        if (proj == 1) {
            __syncthreads();
            int cl = t >> 2, lseg = (t & 3) * 32;
            size_t o = ((size_t)hh * HS + cl) * LQ + l0 + lseg;
#pragma unroll
            for (int ch4 = 0; ch4 < 4; ++ch4) {
                s8v pkh, pkl;
#pragma unroll
                for (int j = 0; j < 8; ++j) {
                    float v = vbuf[cl * 129 + lseg + ch4 * 8 + j];
                    u16 hb = f2bf(v);
                    pkh[j] = (short)hb;
                    pkl[j] = (short)f2bf(v - bf2f(hb));
                }
                *(s8v*)(ktwh + o + ch4 * 8) = pkh;
                *(s8v*)(ktwl + o + ch4 * 8) = pkl;
            }
        }
    } else if (proj == 2) {
#pragma unroll
        for (int n = 0; n < 2; ++n) {
            const f16v acc = n ? acc1 : acc0;
            int cl = n * 32 + c31;
#pragma unroll
            for (int r = 0; r < 16; ++r) {
                int lrow = wv * 32 + (r & 3) + 8 * (r >> 2) + 4 * hi;
                vbuf[cl * 129 + lrow] = acc[r];
            }
        }
        __syncthreads();
        int h = (c0 & 511) >> 6;
        int cl = t >> 2, lseg = (t & 3) * 32;
        size_t o = ((size_t)h * HS + cl) * LQ + l0 + lseg;
#pragma unroll
        for (int ch = 0; ch < 4; ++ch) {
            s8v pk;
#pragma unroll
            for (int j = 0; j < 8; ++j) pk[j] = (short)f2bf(vbuf[cl * 129 + lseg + ch * 8 + j]);
            *(s8v*)(vt + o + ch * 8) = pk;
        }
    } else {
#pragma unroll
        for (int n = 0; n < 2; ++n) {
            const f16v acc = n ? acc1 : acc0;
            int C = (c0 & 511) + n * 32 + c31;
#pragma unroll
            for (int r = 0; r < 16; ++r) {
                int lrow = wv * 32 + (r & 3) + 8 * (r >> 2) + 4 * hi;
                float vv = acc[r];
                gate16[(size_t)(l0 + lrow) * DD + C] = f2bf(vv / (1.f + expf(-vv)));
            }
        }
    }
}

// ---------------- pass1: per-chunk state A^T[ch][d], 4 waves/chunk ----------------
// grid (64, 8), block 256. wave = (wch = v-row half, wd = d half); each computes one 32x32 tile.
__global__ __launch_bounds__(256) void k_ret1(
    const u16* __restrict__ vt, const u16* __restrict__ ktwh, const u16* __restrict__ ktwl,
    float* __restrict__ A) {
    const int t = threadIdx.x;
    const int c = blockIdx.x;
    const int h = blockIdx.y;
    const int wv = t >> 6, lane = t & 63, c31 = lane & 31, hi = lane >> 5;
    const int wch = wv >> 1, wd = wv & 1;

    s8v va[4];
    const u16* vp = vt + ((size_t)h * 64 + wch * 32 + c31) * LQ + c * 64 + hi * 8;
#pragma unroll
    for (int ks = 0; ks < 4; ++ks) va[ks] = *(const s8v*)(vp + ks * 16);

    f16v a;
#pragma unroll
    for (int i = 0; i < 16; ++i) a[i] = 0.f;

    const size_t kbase = ((size_t)h * 64 + wd * 32 + c31) * LQ + c * 64 + hi * 8;
#pragma unroll
    for (int ks = 0; ks < 4; ++ks) {
        s8v b_h = *(const s8v*)(ktwh + kbase + ks * 16);
        s8v b_l = *(const s8v*)(ktwl + kbase + ks * 16);
        a = __builtin_amdgcn_mfma_f32_32x32x16_bf16(va[ks], b_h, a, 0, 0, 0);
        a = __builtin_amdgcn_mfma_f32_32x32x16_bf16(va[ks], b_l, a, 0, 0, 0);
    }

    float* Ab = A + ((size_t)h * 64 + c) * 4096;
#pragma unroll
    for (int r = 0; r < 16; ++r) {
        int ch = wch * 32 + (r & 3) + 8 * (r >> 2) + 4 * hi;
        Ab[ch * 64 + wd * 32 + c31] = a[r];
    }
}

// ---------------- pass2: weighted prefix scan over chunks (register-prefetched) ----------------
__global__ __launch_bounds__(256) void k_scan(
    const float* __restrict__ A, u16* __restrict__ sth, u16* __restrict__ stl) {
    const int bx = blockIdx.x;
    const int h = bx >> 4;
    const int e = (bx & 15) * 256 + threadIdx.x;
    double lg = -3.4657359027997265 + (double)h * (-2.772588722239781 / 7.0);
    double gamma = 1.0 - exp(lg);
    float g64 = (float)pow(gamma, 64.0);
    const float* Ab = A + (size_t)h * 64 * 4096 + e;
    u16* shb = sth + (size_t)h * 64 * 4096 + e;
    u16* slb = stl + (size_t)h * 64 * 4096 + e;
    float av[64];
#pragma unroll
    for (int cc = 0; cc < 64; ++cc) av[cc] = Ab[(size_t)cc * 4096];
    float s = 0.f;
#pragma unroll
    for (int cc = 0; cc < 64; ++cc) {
        if (cc) {
            u16 hb = f2bf(s);
            shb[(size_t)cc * 4096] = hb;
            slb[(size_t)cc * 4096] = f2bf(s - bf2f(hb));
        }
        s = fmaf(g64, s, av[cc]);
    }
}

// ---------------- pass3: retention chunk + fused GroupNorm*gate -> frag-packed gg ----------------
// grid (64, 8), block 256 (4 waves). wave = (ws = row strip, wc = output col half).
__global__ __launch_bounds__(256) void k_ret3(
    const u16* __restrict__ qh, const u16* __restrict__ ql,
    const u16* __restrict__ kh, const u16* __restrict__ kl,
    const u16* __restrict__ vt,
    const u16* __restrict__ sth, const u16* __restrict__ stl,
    const u16* __restrict__ gate16,
    const float* __restrict__ gw, const float* __restrict__ gb,
    u16* __restrict__ Gf) {
    __shared__ __align__(16) char sBuf[24576];   // KH 8K | KL 8K | VT 8K; later gT[64][65] f32
    __shared__ float stats[64][2][2];            // [row][wc][s,ss]
    const int t = threadIdx.x;
    const int c = blockIdx.x;
    const int h = blockIdx.y;
    const int wv = t >> 6, lane = t & 63, c31 = lane & 31, hi = lane >> 5;
    const int ws = wv >> 1, wc = wv & 1;
    const int l0q = c * 64;

    double lg = -3.4657359027997265 + (double)h * (-2.772588722239781 / 7.0);
    double gamma = 1.0 - exp(lg);
    float lgf = (float)(log(gamma) * 1.4426950408889634);
    float c1a[4], c8a[4];
#pragma unroll
    for (int m = 0; m < 4; ++m) { c1a[m] = exp2f(-lgf * (float)m); c8a[m] = exp2f(-lgf * (float)(8 * m)); }

    // Q fragments for this wave's row strip
    s8v qhf[4], qlf[4];
    {
        const u16* qph = qh + ((size_t)h * LQ + l0q + ws * 32 + c31) * HS + hi * 8;
        const u16* qpl = ql + ((size_t)h * LQ + l0q + ws * 32 + c31) * HS + hi * 8;
#pragma unroll
        for (int ks = 0; ks < 4; ++ks) {
            qhf[ks] = *(const s8v*)(qph + ks * 16);
            qlf[ks] = *(const s8v*)(qpl + ks * 16);
        }
    }

    // stage K hi/lo + VT (pre-swizzled source, linear LDS dest), 6 x 16B per thread
    {
        const char* gKH = (const char*)kh + ((size_t)h * LQ + l0q) * 128;
        const char* gKL = (const char*)kl + ((size_t)h * LQ + l0q) * 128;
        const char* gVT = (const char*)vt + ((size_t)h * 64) * 8192 + l0q * 2;
#pragma unroll
        for (int i_ = 0; i_ < 6; ++i_) {
            int boff = i_ * 4096 + t * 16;
            int seg = boff >> 13;
            int o_ = boff & 8191;
            int osrc = o_ ^ (((o_ >> 7) & 7) << 4);
            const char* src = (seg == 0) ? gKH + osrc
                            : (seg == 1) ? gKL + osrc
                            : gVT + (size_t)(osrc >> 7) * 8192 + (osrc & 127);
            gld16(sBuf + boff, src);
        }
    }

    // inter-chunk: qs = Q @ S^T for this wave's col half
    f16v qs;
#pragma unroll
    for (int i = 0; i < 16; ++i) qs[i] = 0.f;
    if (c > 0) {
        const u16* sbh = sth + ((size_t)h * 64 + c) * 4096;
        const u16* sbl = stl + ((size_t)h * 64 + c) * 4096;
#pragma unroll
        for (int ks = 0; ks < 4; ++ks) {
            int off = (wc * 32 + c31) * 64 + ks * 16 + hi * 8;
            s8v b_h = *(const s8v*)(sbh + off);
            s8v b_l = *(const s8v*)(sbl + off);
            qs = __builtin_amdgcn_mfma_f32_32x32x16_bf16(qhf[ks], b_h, qs, 0, 0, 0);
            qs = __builtin_amdgcn_mfma_f32_32x32x16_bf16(qhf[ks], b_l, qs, 0, 0, 0);
            qs = __builtin_amdgcn_mfma_f32_32x32x16_bf16(qlf[ks], b_h, qs, 0, 0, 0);
        }
    }

    asm volatile("s_waitcnt vmcnt(0)" ::: "memory");
    __syncthreads();

    // intra-chunk masked tile (QK^T duplicated across wc; PV split by wc)
    f16v acc;
#pragma unroll
    for (int i = 0; i < 16; ++i) acc[i] = 0.f;
    const char* bKH = sBuf;
    const char* bKL = sBuf + 8192;
    const char* bVT = sBuf + 16384;

#pragma unroll
    for (int jt = 0; jt < 2; ++jt) {
        if (ws == 0 && jt == 1) break;
        f16v sacc;
#pragma unroll
        for (int i = 0; i < 16; ++i) sacc[i] = 0.f;
#pragma unroll
        for (int ks = 0; ks < 4; ++ks) {
            int krow = jt * 32 + c31;
            int ph = krow * 128 + ((ks * 32 + hi * 16) ^ ((krow & 7) << 4));
            s8v ah = *(const s8v*)(bKH + ph);
            s8v al = *(const s8v*)(bKL + ph);
            sacc = __builtin_amdgcn_mfma_f32_32x32x16_bf16(ah, qhf[ks], sacc, 0, 0, 0);
            sacc = __builtin_amdgcn_mfma_f32_32x32x16_bf16(ah, qlf[ks], sacc, 0, 0, 0);
            sacc = __builtin_amdgcn_mfma_f32_32x32x16_bf16(al, qhf[ks], sacc, 0, 0, 0);
        }
        const int D0 = (ws * 32 + c31) - jt * 32;
        float base = exp2f(lgf * (float)(D0 - 4 * hi));
        u32 w[8];
#pragma unroll
        for (int g = 0; g < 4; ++g) {
            float wg = base * c8a[g];
            float v0 = sacc[4 * g + 0] * (wg * c1a[0]);
            float v1 = sacc[4 * g + 1] * (wg * c1a[1]);
            float v2 = sacc[4 * g + 2] * (wg * c1a[2]);
            float v3 = sacc[4 * g + 3] * (wg * c1a[3]);
            int jr = 8 * g + 4 * hi;
            if (D0 - (jr + 0) < 0) v0 = 0.f;
            if (D0 - (jr + 1) < 0) v1 = 0.f;
            if (D0 - (jr + 2) < 0) v2 = 0.f;
            if (D0 - (jr + 3) < 0) v3 = 0.f;
            w[2 * g]     = (u32)f2bf(v0) | ((u32)f2bf(v1) << 16);
            w[2 * g + 1] = (u32)f2bf(v2) | ((u32)f2bf(v3) << 16);
        }
        u32 e0 = __shfl_xor(hi ? w[0] : w[2], 32);
        u32 e1 = __shfl_xor(hi ? w[1] : w[3], 32);
        u32 e2 = __shfl_xor(hi ? w[4] : w[6], 32);
        u32 e3 = __shfl_xor(hi ? w[5] : w[7], 32);
        u32x4 a0v = { hi ? e0 : w[0], hi ? e1 : w[1], hi ? w[2] : e0, hi ? w[3] : e1 };
        u32x4 a1v = { hi ? e2 : w[4], hi ? e3 : w[5], hi ? w[6] : e2, hi ? w[7] : e3 };
        s8v af0 = __builtin_bit_cast(s8v, a0v);
        s8v af1 = __builtin_bit_cast(s8v, a1v);
#pragma unroll
        for (int ksl = 0; ksl < 2; ++ksl) {
            s8v af = ksl ? af1 : af0;
            int cb = (jt * 2 + ksl) * 32 + hi * 16;
            int rv = wc * 32 + c31;
            s8v vb = *(const s8v*)(bVT + rv * 128 + (cb ^ ((rv & 7) << 4)));
            acc = __builtin_amdgcn_mfma_f32_32x32x16_bf16(af, vb, acc, 0, 0, 0);
        }
    }

    // epilogue: combine inter+intra; cross-wc GroupNorm stats via LDS; *gate; frag-pack gg
    float vv[16];
#pragma unroll
    for (int r = 0; r < 16; ++r) {
        int row = (r & 3) + 8 * (r >> 2) + 4 * hi;
        int nloc = ws * 32 + row;
        float sc = exp2f(lgf * (float)nloc);
        vv[r] = acc[r] + sc * qs[r];
    }
#pragma unroll
    for (int r = 0; r < 16; ++r) {
        float s = vv[r], ss = vv[r] * vv[r];
#pragma unroll
        for (int off = 1; off < 32; off <<= 1) {
            s  += __shfl_xor(s, off);
            ss += __shfl_xor(ss, off);
        }
        if (c31 == 0) {
            int nloc = ws * 32 + (r & 3) + 8 * (r >> 2) + 4 * hi;
            stats[nloc][wc][0] = s;
            stats[nloc][wc][1] = ss;
        }
    }
    __syncthreads();   // stats ready; all sBuf (K/V) reads also done -> safe to alias gT

    float* gT = (float*)sBuf;           // [64][65] f32
    const float gwv = gw[h * HS + wc * 32 + c31];
    const float gbv = gb[h * HS + wc * 32 + c31];
#pragma unroll
    for (int r = 0; r < 16; ++r) {
        int nloc = ws * 32 + (r & 3) + 8 * (r >> 2) + 4 * hi;
        float s  = stats[nloc][0][0] + stats[nloc][1][0];
        float ss = stats[nloc][0][1] + stats[nloc][1][1];
        float mean = s * (1.f / 64.f);
        float var = ss * (1.f / 64.f) - mean * mean;
        float inv = rsqrtf(var + 1e-5f);
        size_t o = (size_t)(l0q + nloc) * DD + h * HS + wc * 32 + c31;
        float g = ((vv[r] - mean) * inv * gwv + gbv) * bf2f(gate16[o]);
        gT[nloc * 65 + wc * 32 + c31] = g;
    }
    __syncthreads();
#pragma unroll
    for (int i = 0; i < 2; ++i) {
        int u = t + i * 256;            // 0..511
        int rbl = u >> 8;
        int ks = (u >> 6) & 3;
        int ln = u & 63;
        int row = rbl * 32 + (ln & 31);
        int ch = ks * 16 + (ln >> 5) * 8;
        s8v pk;
#pragma unroll
        for (int j = 0; j < 8; ++j) pk[j] = (short)f2bf(gT[row * 65 + ch + j]);
        size_t off = ((((size_t)(c * 2 + rbl) * 8 + h) * 4 + ks) * 64 + ln) * 8;
        *(s8v*)(Gf + off) = pk;
    }
}

// ---------------- out = gg @ W_O (both operands frag-direct, sched-pinned) ----------------
__global__ __launch_bounds__(256) void k_out(
    const u16* __restrict__ Gf, const u16* __restrict__ Wf,
    float* __restrict__ out) {
    const int t = threadIdx.x;
    const int l0 = blockIdx.x * 128;
    const int c0 = blockIdx.y * 64;
    const int wv = t >> 6;
    const int lane = t & 63;
    const int c31 = lane & 31;
    const int hi = lane >> 5;

    const int rb = blockIdx.x * 4 + wv;
    const u16* pA  = Gf + (size_t)rb * 16384 + lane * 8;
    const u16* pB0 = Wf + (size_t)(64 + (c0 >> 5)) * 16384 + lane * 8;
    const u16* pB1 = pB0 + 16384;

    f16v acc0, acc1;
#pragma unroll
    for (int i = 0; i < 16; ++i) { acc0[i] = 0.f; acc1[i] = 0.f; }

    s8v aA[4], b0A[4], b1A[4], aB[4], b0B[4], b1B[4];
#define LOADO(S, KT)                                                      \
    { _Pragma("unroll") for (int ks = 0; ks < 4; ++ks) {                  \
        a##S[ks]  = *(const s8v*)(pA  + (KT) * 2048 + ks * 512);          \
        b0##S[ks] = *(const s8v*)(pB0 + (KT) * 2048 + ks * 512);          \
        b1##S[ks] = *(const s8v*)(pB1 + (KT) * 2048 + ks * 512); } }
#define MFMAO(S)                                                                            \
    { _Pragma("unroll") for (int ks = 0; ks < 4; ++ks) {                                    \
        acc0 = __builtin_amdgcn_mfma_f32_32x32x16_bf16(a##S[ks], b0##S[ks], acc0, 0, 0, 0); \
        acc1 = __builtin_amdgcn_mfma_f32_32x32x16_bf16(a##S[ks], b1##S[ks], acc1, 0, 0, 0); } }
    LOADO(A, 0)
#pragma unroll
    for (int kp = 0; kp < 4; ++kp) {
        LOADO(B, 2 * kp + 1)
        __builtin_amdgcn_sched_barrier(0);
        MFMAO(A)
        if (kp < 3) { LOADO(A, 2 * kp + 2) }
        __builtin_amdgcn_sched_barrier(0);
        MFMAO(B)
    }
#undef LOADO
#undef MFMAO

#pragma unroll
    for (int n = 0; n < 2; ++n) {
        const f16v acc = n ? acc1 : acc0;
        int C = c0 + n * 32 + c31;
#pragma unroll
        for (int r = 0; r < 16; ++r) {
            int lrow = wv * 32 + (r & 3) + 8 * (r >> 2) + 4 * hi;
            out[(size_t)(l0 + lrow) * DD + C] = acc[r];
        }
    }
}

extern "C" void kernel_launch(void* const* d_in, const int* in_sizes, int n_in,
                              void* d_out, int out_size, void* d_ws, size_t ws_size,
                              hipStream_t stream) {
    const float* X   = (const float*)d_in[0];
    const float* W_Q = (const float*)d_in[1];
    const float* W_K = (const float*)d_in[2];
    const float* W_V = (const float*)d_in[3];
    const float* W_G = (const float*)d_in[4];
    const float* W_O = (const float*)d_in[5];
    const float* gnw = (const float*)d_in[6];
    const float* gnb = (const float*)d_in[7];

    float* ws   = (float*)d_ws;
    u16* qhp  = (u16*)(ws + WS_QH);
    u16* qlp  = (u16*)(ws + WS_QL);
    u16* khp  = (u16*)(ws + WS_KH);
    u16* klp  = (u16*)(ws + WS_KL);
    u16* vtp  = (u16*)(ws + WS_VT);
    u16* xfh  = (u16*)(ws + WS_XFH);
    u16* xfl  = (u16*)(ws + WS_XFL);
    u16* wf   = (u16*)(ws + WS_WF);
    u16* gate16 = (u16*)(ws + WS_GATE);
    float* tab  = ws + WS_TAB;
    u16* ktwh = (u16*)(ws + WS_KTWH);
    u16* ktwl = (u16*)(ws + WS_KTWL);
    float* Abuf = ws + WS_XFH;         // A_state over dead Xf (2M floats)
    u16* sthp = (u16*)(ws + WS_KTWH);  // St over dead ktw
    u16* stlp = (u16*)(ws + WS_KTWL);
    u16* Gfp  = (u16*)(ws + WS_XFH);   // frag-packed gg over dead A_state
    float* out  = (float*)d_out;

    k_pre<<<2816, 256, 0, stream>>>(X, W_Q, W_K, W_V, W_G, W_O, tab, xfh, xfl, wf);
    k_fused<<<1024, 256, 0, stream>>>(xfh, xfl, wf, tab, qhp, qlp, khp, klp, vtp, gate16, ktwh, ktwl);
    k_ret1<<<dim3(64, 8), 256, 0, stream>>>(vtp, ktwh, ktwl, Abuf);
    k_scan<<<128, 256, 0, stream>>>(Abuf, sthp, stlp);
    k_ret3<<<dim3(64, 8), 256, 0, stream>>>(qhp, qlp, khp, klp, vtp, sthp, stlp,
                                            gate16, gnw, gnb, Gfp);
    k_out<<<dim3(32, 8), 256, 0, stream>>>(Gfp, wf, out);
}

// Round 9
// 78.541 us; speedup vs baseline: 2.3528x; 1.0792x over previous
//
#include <hip/hip_runtime.h>
#include <math.h>

#define LQ 4096
#define DD 512
#define NH 8
#define HS 64
#define HALF 32

typedef unsigned short u16;
typedef unsigned int u32;
typedef __attribute__((ext_vector_type(8)))  short s8v;   // 8 x bf16 (MFMA A/B frag)
typedef __attribute__((ext_vector_type(4)))  float f4v;
typedef __attribute__((ext_vector_type(4)))  u32  u32x4;
typedef __attribute__((ext_vector_type(16))) float f16v;  // 32x32 MFMA C/D

// workspace offsets (in floats)
#define WS_QH   0u
#define WS_QL   1048576u
#define WS_KH   2097152u
#define WS_KL   3145728u
#define WS_VT   4194304u
#define WS_XFH  5242880u    // frag-packed X hi; later A_state spans XFH+XFL; later Gf
#define WS_XFL  6291456u    // frag-packed X lo
#define WS_WF   7340032u    // frag-packed W single bf16
#define WS_GATE 8650752u    // gate as bf16 (u16)
#define WS_TAB  10747904u
#define WS_KTWH 11272192u   // ktw_hi; later St_hi
#define WS_KTWL 12320768u   // ktw_lo; later St_lo

__device__ inline u16 f2bf(float x) {
    unsigned int u = __float_as_uint(x);
    return (u16)((u + 0x7fffu + ((u >> 16) & 1u)) >> 16);
}
__device__ inline float bf2f(u16 h) { return __uint_as_float(((unsigned int)h) << 16); }

__device__ __forceinline__ void gld16(void* lds, const void* g) {
    __builtin_amdgcn_global_load_lds(
        (const __attribute__((address_space(1))) void*)g,
        (__attribute__((address_space(3))) void*)lds, 16, 0, 0);
}

// ---------------- merged prep: xPos tables | X->frag hi/lo | W->frag single bf16 ----------------
__global__ __launch_bounds__(256) void k_pre(
    const float* __restrict__ X,
    const float* __restrict__ Wq, const float* __restrict__ Wk, const float* __restrict__ Wv,
    const float* __restrict__ Wg, const float* __restrict__ Wo,
    float* __restrict__ tab, u16* __restrict__ Xfh, u16* __restrict__ Xfl,
    u16* __restrict__ Wf) {
    __shared__ float tile[32][33];
    const int b = blockIdx.x;
    const int t = threadIdx.x;
    if (b < 512) {
        int idx = b * 256 + t;
        if (idx >= LQ * HALF) return;
        int l = idx >> 5;
        int i = idx & 31;
        // scale = sv^(l/512): double log2 once, float exp2 (arg tiny -> fp32 exact enough)
        double log2sv = log2((2.0 * i + 25.6) / 89.6);
        double e = (double)l * log2sv * (1.0 / 512.0);
        float sc  = exp2f((float)e);
        float sci = exp2f((float)(-e));
        // theta = l * 10000^(-i/32): invf in double (rel 1e-16), exact range reduction
        double invf = exp2((double)i * (-13.287712379549449 / 32.0));
        double th = (double)l * invf;
        double r = th - 6.283185307179586 * floor(th * 0.15915494309189535);
        float c = cosf((float)r), sn = sinf((float)r);
        tab[idx]                 = c * sc;
        tab[LQ*HALF + idx]       = sn * sc;
        tab[2*LQ*HALF + idx]     = c * sci;
        tab[3*LQ*HALF + idx]     = sn * sci;
    } else if (b < 1536) {
        // X -> fragment-packed hi/lo: Xf[rb:128][kt:8][ks:4][lane:64][8]
        int g = (b - 512) * 256 + t;
        int l = g >> 6;
        int d = (g & 63) * 8;
        const float* xp = X + (size_t)l * DD + d;
        f4v x0 = *(const f4v*)xp;
        f4v x1 = *(const f4v*)(xp + 4);
        s8v ph, pl;
#pragma unroll
        for (int j = 0; j < 4; ++j) {
            u16 hb = f2bf(x0[j]);
            ph[j] = (short)hb; pl[j] = (short)f2bf(x0[j] - bf2f(hb));
            u16 hb2 = f2bf(x1[j]);
            ph[j+4] = (short)hb2; pl[j+4] = (short)f2bf(x1[j] - bf2f(hb2));
        }
        int rb = l >> 5, kt = d >> 6, ks = (d >> 4) & 3, kh2 = (d >> 3) & 1;
        int lane = kh2 * 32 + (l & 31);
        size_t off = (((size_t)(rb * 8 + kt) * 4 + ks) * 64 + lane) * 8;
        *(s8v*)(Xfh + off) = ph;
        *(s8v*)(Xfl + off) = pl;
    } else {
        // weights -> fragment-packed single bf16: Wf[nb:80][kt:8][ks:4][lane:64][8]
        int bb = b - 1536;
        int d0 = (bb & 15) * 32, C0 = (bb >> 4) * 32;
        int proj = C0 >> 9;
        int tc = t & 31, tr = t >> 5;
#pragma unroll
        for (int rr = 0; rr < 4; ++rr) {
            int dl = tr + rr * 8;
            int d = d0 + dl;
            int C = C0 + tc;
            float val;
            if (proj < 3) {
                const float* W = (proj == 0) ? Wq : ((proj == 1) ? Wk : Wv);
                int h = (C & 511) >> 6, hs = C & 63;
                val = W[(size_t)h * (DD * HS) + (size_t)d * HS + hs];
            } else if (proj == 3) {
                val = Wg[(size_t)d * DD + (C & 511)];
            } else {
                val = Wo[(size_t)d * DD + (C - 2048)];
            }
            tile[dl][tc] = val;
        }
        __syncthreads();
        if (t < 128) {
            int cl = t & 31, dgq = t >> 5;
            int dl = dgq * 8;
            s8v pk;
#pragma unroll
            for (int j = 0; j < 8; ++j) pk[j] = (short)f2bf(tile[dl + j][cl]);
            int C = C0 + cl;
            int da = d0 + dl;
            int nb = C >> 5, kt = da >> 6, ks = (da >> 4) & 3, kh2 = (da >> 3) & 1;
            int lane = kh2 * 32 + (C & 31);
            size_t off = (((size_t)(nb * 8 + kt) * 4 + ks) * 64 + lane) * 8;
            *(s8v*)(Wf + off) = pk;
        }
    }
}

// ---------------- fused MFMA GEMM: A frag-direct pinned, B LDS-shared (2 phases) ----------------
// grid 1024 (chunked XCD swizzle), block 256 (4 waves, each 32l x 64c).
__global__ __launch_bounds__(256) void k_fused(
    const u16* __restrict__ Xfh, const u16* __restrict__ Xfl,
    const u16* __restrict__ Wf,
    const float* __restrict__ tab,
    u16* __restrict__ qh, u16* __restrict__ ql,
    u16* __restrict__ kh, u16* __restrict__ kl,
    u16* __restrict__ vt, u16* __restrict__ gate16,
    u16* __restrict__ ktwh, u16* __restrict__ ktwl) {
    __shared__ __align__(16) char smem[33024];   // B stage 32KB (2 segs x 16KB); vbuf alias after loop
    const int t = threadIdx.x;
    const int b = blockIdx.x;
    const int mb = (b & 7) * 4 + (b >> 8);   // 0..31
    const int cb = (b >> 3) & 31;            // 0..31
    const int l0 = mb * 128;
    const int c0 = cb * 64;
    const int wv = t >> 6;
    const int lane = t & 63;
    const int c31 = lane & 31;
    const int hi = lane >> 5;

    const int rb = mb * 4 + wv;
    const u16* pAh = Xfh + (size_t)rb * 16384 + lane * 8;
    const u16* pAl = Xfl + (size_t)rb * 16384 + lane * 8;
    const char* gB = (const char*)(Wf + (size_t)(cb * 2) * 16384);

    f16v acc0, acc1;
#pragma unroll
    for (int i = 0; i < 16; ++i) { acc0[i] = 0.f; acc1[i] = 0.f; }

    // stage B for kt in [PH*4, PH*4+4): 2 nb segs x 16KB, linear copy
#define STAGEB(PH)                                                             \
    { _Pragma("unroll") for (int j = 0; j < 8; ++j) {                          \
        int seg = j >> 2, q4 = j & 3;                                          \
        gld16(smem + seg * 16384 + q4 * 4096 + wv * 1024,                      \
              gB + seg * 32768 + (PH) * 16384 + q4 * 4096 + t * 16); } }

    if (c0 < 1024) {
        s8v ahA[4], alA[4], ahB[4], alB[4];
#define LOADQ(S, KT)                                                      \
        { _Pragma("unroll") for (int ks = 0; ks < 4; ++ks) {              \
            ah##S[ks] = *(const s8v*)(pAh + (KT) * 2048 + ks * 512);      \
            al##S[ks] = *(const s8v*)(pAl + (KT) * 2048 + ks * 512); } }
#define MFMAQ(S, KT)                                                                        \
        { const char* bbq = smem + ((KT) & 3) * 4096;                                       \
          _Pragma("unroll") for (int ks = 0; ks < 4; ++ks) {                                \
            s8v b0 = *(const s8v*)(bbq + ks * 1024 + lane * 16);                            \
            s8v b1 = *(const s8v*)(bbq + 16384 + ks * 1024 + lane * 16);                    \
            acc0 = __builtin_amdgcn_mfma_f32_32x32x16_bf16(ah##S[ks], b0, acc0, 0, 0, 0);   \
            acc0 = __builtin_amdgcn_mfma_f32_32x32x16_bf16(al##S[ks], b0, acc0, 0, 0, 0);   \
            acc1 = __builtin_amdgcn_mfma_f32_32x32x16_bf16(ah##S[ks], b1, acc1, 0, 0, 0);   \
            acc1 = __builtin_amdgcn_mfma_f32_32x32x16_bf16(al##S[ks], b1, acc1, 0, 0, 0); } }
        STAGEB(0)
        LOADQ(A, 0)
        asm volatile("s_waitcnt vmcnt(0)" ::: "memory");
        __syncthreads();
        LOADQ(B, 1)
        __builtin_amdgcn_sched_barrier(0);
        MFMAQ(A, 0)
        LOADQ(A, 2)
        __builtin_amdgcn_sched_barrier(0);
        MFMAQ(B, 1)
        LOADQ(B, 3)
        __builtin_amdgcn_sched_barrier(0);
        MFMAQ(A, 2)
        LOADQ(A, 4)
        __builtin_amdgcn_sched_barrier(0);
        MFMAQ(B, 3)
        __syncthreads();                 // all waves done reading phase-0 B
        STAGEB(1)
        asm volatile("s_waitcnt vmcnt(0)" ::: "memory");
        __syncthreads();
        LOADQ(B, 5)
        __builtin_amdgcn_sched_barrier(0);
        MFMAQ(A, 4)
        LOADQ(A, 6)
        __builtin_amdgcn_sched_barrier(0);
        MFMAQ(B, 5)
        LOADQ(B, 7)
        __builtin_amdgcn_sched_barrier(0);
        MFMAQ(A, 6)
        __builtin_amdgcn_sched_barrier(0);
        MFMAQ(B, 7)
#undef LOADQ
#undef MFMAQ
    } else {
        s8v ahA[4], ahB[4];
#define LOADS(S, KT)                                                      \
        { _Pragma("unroll") for (int ks = 0; ks < 4; ++ks) {              \
            ah##S[ks] = *(const s8v*)(pAh + (KT) * 2048 + ks * 512); } }
#define MFMAS(S, KT)                                                                        \
        { const char* bbq = smem + ((KT) & 3) * 4096;                                       \
          _Pragma("unroll") for (int ks = 0; ks < 4; ++ks) {                                \
            s8v b0 = *(const s8v*)(bbq + ks * 1024 + lane * 16);                            \
            s8v b1 = *(const s8v*)(bbq + 16384 + ks * 1024 + lane * 16);                    \
            acc0 = __builtin_amdgcn_mfma_f32_32x32x16_bf16(ah##S[ks], b0, acc0, 0, 0, 0);   \
            acc1 = __builtin_amdgcn_mfma_f32_32x32x16_bf16(ah##S[ks], b1, acc1, 0, 0, 0); } }
        STAGEB(0)
        LOADS(A, 0)
        asm volatile("s_waitcnt vmcnt(0)" ::: "memory");
        __syncthreads();
        LOADS(B, 1)
        __builtin_amdgcn_sched_barrier(0);
        MFMAS(A, 0)
        LOADS(A, 2)
        __builtin_amdgcn_sched_barrier(0);
        MFMAS(B, 1)
        LOADS(B, 3)
        __builtin_amdgcn_sched_barrier(0);
        MFMAS(A, 2)
        LOADS(A, 4)
        __builtin_amdgcn_sched_barrier(0);
        MFMAS(B, 3)
        __syncthreads();
        STAGEB(1)
        asm volatile("s_waitcnt vmcnt(0)" ::: "memory");
        __syncthreads();
        LOADS(B, 5)
        __builtin_amdgcn_sched_barrier(0);
        MFMAS(A, 4)
        LOADS(A, 6)
        __builtin_amdgcn_sched_barrier(0);
        MFMAS(B, 5)
        LOADS(B, 7)
        __builtin_amdgcn_sched_barrier(0);
        MFMAS(A, 6)
        __builtin_amdgcn_sched_barrier(0);
        MFMAS(B, 7)
#undef LOADS
#undef MFMAS
    }
#undef STAGEB
    __syncthreads();                     // B LDS dead; safe to alias vbuf below

    float* vbuf = (float*)smem;          // [64][129] f32
    const int proj = c0 >> 9;
    if (proj < 2) {
        const float* ct = tab + (proj ? 2 * LQ * HALF : 0);
        const float* st = tab + (proj ? 3 * LQ * HALF : LQ * HALF);
        u16* oh = proj ? kh : qh;
        u16* ol = proj ? kl : ql;
        const int hh = (c0 & 511) >> 6;
        float lgf = 0.f;
        if (proj == 1) {
            double lg = -3.4657359027997265 + (double)hh * (-2.772588722239781 / 7.0);
            lgf = (float)(log(1.0 - exp(lg)) * 1.4426950408889634);
        }
#pragma unroll
        for (int n = 0; n < 2; ++n) {
            const f16v acc = n ? acc1 : acc0;
            int C = c0 + n * 32 + c31;
            int hs = C & 63, i2 = hs >> 1;
            float sgn = (hs & 1) ? 1.f : -1.f;
#pragma unroll
            for (int r = 0; r < 16; ++r) {
                int lrow = wv * 32 + (r & 3) + 8 * (r >> 2) + 4 * hi;
                int pos = l0 + lrow;
                float val = acc[r];
                float part = __shfl_xor(val, 1);
                float res = val * ct[pos * HALF + i2] + sgn * part * st[pos * HALF + i2];
                u16 hb = f2bf(res);
                size_t o = ((size_t)hh * LQ + pos) * HS + hs;
                oh[o] = hb;
                ol[o] = f2bf(res - bf2f(hb));
                if (proj == 1) {
                    float wf = exp2f(lgf * (float)(64 - (pos & 63)));   // gamma^(64-m')
                    vbuf[(n * 32 + c31) * 129 + lrow] = res * wf;
                }
            }
        }
        if (proj == 1) {
            __syncthreads();
            int cl = t >> 2, lseg = (t & 3) * 32;
            size_t o = ((size_t)hh * HS + cl) * LQ + l0 + lseg;
#pragma unroll
            for (int ch4 = 0; ch4 < 4; ++ch4) {
                s8v pkh, pkl;
#pragma unroll
                for (int j = 0; j < 8; ++j) {
                    float v = vbuf[cl * 129 + lseg + ch4 * 8 + j];
                    u16 hb = f2bf(v);
                    pkh[j] = (short)hb;
                    pkl[j] = (short)f2bf(v - bf2f(hb));
                }
                *(s8v*)(ktwh + o + ch4 * 8) = pkh;
                *(s8v*)(ktwl + o + ch4 * 8) = pkl;
            }
        }
    } else if (proj == 2) {
#pragma unroll
        for (int n = 0; n < 2; ++n) {
            const f16v acc = n ? acc1 : acc0;
            int cl = n * 32 + c31;
#pragma unroll
            for (int r = 0; r < 16; ++r) {
                int lrow = wv * 32 + (r & 3) + 8 * (r >> 2) + 4 * hi;
                vbuf[cl * 129 + lrow] = acc[r];
            }
        }
        __syncthreads();
        int h = (c0 & 511) >> 6;
        int cl = t >> 2, lseg = (t & 3) * 32;
        size_t o = ((size_t)h * HS + cl) * LQ + l0 + lseg;
#pragma unroll
        for (int ch = 0; ch < 4; ++ch) {
            s8v pk;
#pragma unroll
            for (int j = 0; j < 8; ++j) pk[j] = (short)f2bf(vbuf[cl * 129 + lseg + ch * 8 + j]);
            *(s8v*)(vt + o + ch * 8) = pk;
        }
    } else {
#pragma unroll
        for (int n = 0; n < 2; ++n) {
            const f16v acc = n ? acc1 : acc0;
            int C = (c0 & 511) + n * 32 + c31;
#pragma unroll
            for (int r = 0; r < 16; ++r) {
                int lrow = wv * 32 + (r & 3) + 8 * (r >> 2) + 4 * hi;
                float vv = acc[r];
                gate16[(size_t)(l0 + lrow) * DD + C] = f2bf(vv / (1.f + expf(-vv)));
            }
        }
    }
}

// ---------------- pass1: per-chunk state A^T[ch][d], 4 waves/chunk ----------------
__global__ __launch_bounds__(256) void k_ret1(
    const u16* __restrict__ vt, const u16* __restrict__ ktwh, const u16* __restrict__ ktwl,
    float* __restrict__ A) {
    const int t = threadIdx.x;
    const int c = blockIdx.x;
    const int h = blockIdx.y;
    const int wv = t >> 6, lane = t & 63, c31 = lane & 31, hi = lane >> 5;
    const int wch = wv >> 1, wd = wv & 1;

    s8v va[4];
    const u16* vp = vt + ((size_t)h * 64 + wch * 32 + c31) * LQ + c * 64 + hi * 8;
#pragma unroll
    for (int ks = 0; ks < 4; ++ks) va[ks] = *(const s8v*)(vp + ks * 16);

    f16v a;
#pragma unroll
    for (int i = 0; i < 16; ++i) a[i] = 0.f;

    const size_t kbase = ((size_t)h * 64 + wd * 32 + c31) * LQ + c * 64 + hi * 8;
#pragma unroll
    for (int ks = 0; ks < 4; ++ks) {
        s8v b_h = *(const s8v*)(ktwh + kbase + ks * 16);
        s8v b_l = *(const s8v*)(ktwl + kbase + ks * 16);
        a = __builtin_amdgcn_mfma_f32_32x32x16_bf16(va[ks], b_h, a, 0, 0, 0);
        a = __builtin_amdgcn_mfma_f32_32x32x16_bf16(va[ks], b_l, a, 0, 0, 0);
    }

    float* Ab = A + ((size_t)h * 64 + c) * 4096;
#pragma unroll
    for (int r = 0; r < 16; ++r) {
        int ch = wch * 32 + (r & 3) + 8 * (r >> 2) + 4 * hi;
        Ab[ch * 64 + wd * 32 + c31] = a[r];
    }
}

// ---------------- pass2: weighted prefix scan over chunks (register-prefetched) ----------------
__global__ __launch_bounds__(256) void k_scan(
    const float* __restrict__ A, u16* __restrict__ sth, u16* __restrict__ stl) {
    const int bx = blockIdx.x;
    const int h = bx >> 4;
    const int e = (bx & 15) * 256 + threadIdx.x;
    double lg = -3.4657359027997265 + (double)h * (-2.772588722239781 / 7.0);
    double gamma = 1.0 - exp(lg);
    float g64 = (float)pow(gamma, 64.0);
    const float* Ab = A + (size_t)h * 64 * 4096 + e;
    u16* shb = sth + (size_t)h * 64 * 4096 + e;
    u16* slb = stl + (size_t)h * 64 * 4096 + e;
    float av[64];
#pragma unroll
    for (int cc = 0; cc < 64; ++cc) av[cc] = Ab[(size_t)cc * 4096];
    float s = 0.f;
#pragma unroll
    for (int cc = 0; cc < 64; ++cc) {
        if (cc) {
            u16 hb = f2bf(s);
            shb[(size_t)cc * 4096] = hb;
            slb[(size_t)cc * 4096] = f2bf(s - bf2f(hb));
        }
        s = fmaf(g64, s, av[cc]);
    }
}

// ---------------- pass3: retention chunk + fused GroupNorm*gate -> frag-packed gg ----------------
// grid (64, 8), block 256 (4 waves). wave = (ws = row strip, wc = output col half).
__global__ __launch_bounds__(256) void k_ret3(
    const u16* __restrict__ qh, const u16* __restrict__ ql,
    const u16* __restrict__ kh, const u16* __restrict__ kl,
    const u16* __restrict__ vt,
    const u16* __restrict__ sth, const u16* __restrict__ stl,
    const u16* __restrict__ gate16,
    const float* __restrict__ gw, const float* __restrict__ gb,
    u16* __restrict__ Gf) {
    __shared__ __align__(16) char sBuf[24576];   // KH 8K | KL 8K | VT 8K; later gT[64][65] f32
    __shared__ float stats[64][2][2];            // [row][wc][s,ss]
    const int t = threadIdx.x;
    const int c = blockIdx.x;
    const int h = blockIdx.y;
    const int wv = t >> 6, lane = t & 63, c31 = lane & 31, hi = lane >> 5;
    const int ws = wv >> 1, wc = wv & 1;
    const int l0q = c * 64;

    double lg = -3.4657359027997265 + (double)h * (-2.772588722239781 / 7.0);
    double gamma = 1.0 - exp(lg);
    float lgf = (float)(log(gamma) * 1.4426950408889634);
    float c1a[4], c8a[4];
#pragma unroll
    for (int m = 0; m < 4; ++m) { c1a[m] = exp2f(-lgf * (float)m); c8a[m] = exp2f(-lgf * (float)(8 * m)); }

    // Q fragments for this wave's row strip
    s8v qhf[4], qlf[4];
    {
        const u16* qph = qh + ((size_t)h * LQ + l0q + ws * 32 + c31) * HS + hi * 8;
        const u16* qpl = ql + ((size_t)h * LQ + l0q + ws * 32 + c31) * HS + hi * 8;
#pragma unroll
        for (int ks = 0; ks < 4; ++ks) {
            qhf[ks] = *(const s8v*)(qph + ks * 16);
            qlf[ks] = *(const s8v*)(qpl + ks * 16);
        }
    }

    // stage K hi/lo + VT (pre-swizzled source, linear LDS dest), 6 x 16B per thread
    {
        const char* gKH = (const char*)kh + ((size_t)h * LQ + l0q) * 128;
        const char* gKL = (const char*)kl + ((size_t)h * LQ + l0q) * 128;
        const char* gVT = (const char*)vt + ((size_t)h * 64) * 8192 + l0q * 2;
#pragma unroll
        for (int i_ = 0; i_ < 6; ++i_) {
            int boff = i_ * 4096 + t * 16;
            int seg = boff >> 13;
            int o_ = boff & 8191;
            int osrc = o_ ^ (((o_ >> 7) & 7) << 4);
            const char* src = (seg == 0) ? gKH + osrc
                            : (seg == 1) ? gKL + osrc
                            : gVT + (size_t)(osrc >> 7) * 8192 + (osrc & 127);
            gld16(sBuf + (i_ & ~0) * 4096 + (t >> 6) * 1024, src);
        }
    }

    // inter-chunk: qs = Q @ S^T for this wave's col half
    f16v qs;
#pragma unroll
    for (int i = 0; i < 16; ++i) qs[i] = 0.f;
    if (c > 0) {
        const u16* sbh = sth + ((size_t)h * 64 + c) * 4096;
        const u16* sbl = stl + ((size_t)h * 64 + c) * 4096;
#pragma unroll
        for (int ks = 0; ks < 4; ++ks) {
            int off = (wc * 32 + c31) * 64 + ks * 16 + hi * 8;
            s8v b_h = *(const s8v*)(sbh + off);
            s8v b_l = *(const s8v*)(sbl + off);
            qs = __builtin_amdgcn_mfma_f32_32x32x16_bf16(qhf[ks], b_h, qs, 0, 0, 0);
            qs = __builtin_amdgcn_mfma_f32_32x32x16_bf16(qhf[ks], b_l, qs, 0, 0, 0);
            qs = __builtin_amdgcn_mfma_f32_32x32x16_bf16(qlf[ks], b_h, qs, 0, 0, 0);
        }
    }

    asm volatile("s_waitcnt vmcnt(0)" ::: "memory");
    __syncthreads();

    // intra-chunk masked tile (QK^T duplicated across wc; PV split by wc)
    f16v acc;
#pragma unroll
    for (int i = 0; i < 16; ++i) acc[i] = 0.f;
    const char* bKH = sBuf;
    const char* bKL = sBuf + 8192;
    const char* bVT = sBuf + 16384;

#pragma unroll
    for (int jt = 0; jt < 2; ++jt) {
        if (ws == 0 && jt == 1) break;
        f16v sacc;
#pragma unroll
        for (int i = 0; i < 16; ++i) sacc[i] = 0.f;
#pragma unroll
        for (int ks = 0; ks < 4; ++ks) {
            int krow = jt * 32 + c31;
            int ph = krow * 128 + ((ks * 32 + hi * 16) ^ ((krow & 7) << 4));
            s8v ah = *(const s8v*)(bKH + ph);
            s8v al = *(const s8v*)(bKL + ph);
            sacc = __builtin_amdgcn_mfma_f32_32x32x16_bf16(ah, qhf[ks], sacc, 0, 0, 0);
            sacc = __builtin_amdgcn_mfma_f32_32x32x16_bf16(ah, qlf[ks], sacc, 0, 0, 0);
            sacc = __builtin_amdgcn_mfma_f32_32x32x16_bf16(al, qhf[ks], sacc, 0, 0, 0);
        }
        const int D0 = (ws * 32 + c31) - jt * 32;
        float base = exp2f(lgf * (float)(D0 - 4 * hi));
        u32 w[8];
#pragma unroll
        for (int g = 0; g < 4; ++g) {
            float wg = base * c8a[g];
            float v0 = sacc[4 * g + 0] * (wg * c1a[0]);
            float v1 = sacc[4 * g + 1] * (wg * c1a[1]);
            float v2 = sacc[4 * g + 2] * (wg * c1a[2]);
            float v3 = sacc[4 * g + 3] * (wg * c1a[3]);
            int jr = 8 * g + 4 * hi;
            if (D0 - (jr + 0) < 0) v0 = 0.f;
            if (D0 - (jr + 1) < 0) v1 = 0.f;
            if (D0 - (jr + 2) < 0) v2 = 0.f;
            if (D0 - (jr + 3) < 0) v3 = 0.f;
            w[2 * g]     = (u32)f2bf(v0) | ((u32)f2bf(v1) << 16);
            w[2 * g + 1] = (u32)f2bf(v2) | ((u32)f2bf(v3) << 16);
        }
        u32 e0 = __shfl_xor(hi ? w[0] : w[2], 32);
        u32 e1 = __shfl_xor(hi ? w[1] : w[3], 32);
        u32 e2 = __shfl_xor(hi ? w[4] : w[6], 32);
        u32 e3 = __shfl_xor(hi ? w[5] : w[7], 32);
        u32x4 a0v = { hi ? e0 : w[0], hi ? e1 : w[1], hi ? w[2] : e0, hi ? w[3] : e1 };
        u32x4 a1v = { hi ? e2 : w[4], hi ? e3 : w[5], hi ? w[6] : e2, hi ? w[7] : e3 };
        s8v af0 = __builtin_bit_cast(s8v, a0v);
        s8v af1 = __builtin_bit_cast(s8v, a1v);
#pragma unroll
        for (int ksl = 0; ksl < 2; ++ksl) {
            s8v af = ksl ? af1 : af0;
            int cb = (jt * 2 + ksl) * 32 + hi * 16;
            int rv = wc * 32 + c31;
            s8v vb = *(const s8v*)(bVT + rv * 128 + (cb ^ ((rv & 7) << 4)));
            acc = __builtin_amdgcn_mfma_f32_32x32x16_bf16(af, vb, acc, 0, 0, 0);
        }
    }

    // epilogue: combine inter+intra; cross-wc GroupNorm stats via LDS; *gate; frag-pack gg
    float vv[16];
#pragma unroll
    for (int r = 0; r < 16; ++r) {
        int row = (r & 3) + 8 * (r >> 2) + 4 * hi;
        int nloc = ws * 32 + row;
        float sc = exp2f(lgf * (float)nloc);
        vv[r] = acc[r] + sc * qs[r];
    }
#pragma unroll
    for (int r = 0; r < 16; ++r) {
        float s = vv[r], ss = vv[r] * vv[r];
#pragma unroll
        for (int off = 1; off < 32; off <<= 1) {
            s  += __shfl_xor(s, off);
            ss += __shfl_xor(ss, off);
        }
        if (c31 == 0) {
            int nloc = ws * 32 + (r & 3) + 8 * (r >> 2) + 4 * hi;
            stats[nloc][wc][0] = s;
            stats[nloc][wc][1] = ss;
        }
    }
    __syncthreads();   // stats ready; all sBuf (K/V) reads also done -> safe to alias gT

    float* gT = (float*)sBuf;           // [64][65] f32
    const float gwv = gw[h * HS + wc * 32 + c31];
    const float gbv = gb[h * HS + wc * 32 + c31];
#pragma unroll
    for (int r = 0; r < 16; ++r) {
        int nloc = ws * 32 + (r & 3) + 8 * (r >> 2) + 4 * hi;
        float s  = stats[nloc][0][0] + stats[nloc][1][0];
        float ss = stats[nloc][0][1] + stats[nloc][1][1];
        float mean = s * (1.f / 64.f);
        float var = ss * (1.f / 64.f) - mean * mean;
        float inv = rsqrtf(var + 1e-5f);
        size_t o = (size_t)(l0q + nloc) * DD + h * HS + wc * 32 + c31;
        float g = ((vv[r] - mean) * inv * gwv + gbv) * bf2f(gate16[o]);
        gT[nloc * 65 + wc * 32 + c31] = g;
    }
    __syncthreads();
#pragma unroll
    for (int i = 0; i < 2; ++i) {
        int u = t + i * 256;            // 0..511
        int rbl = u >> 8;
        int ks = (u >> 6) & 3;
        int ln = u & 63;
        int row = rbl * 32 + (ln & 31);
        int ch = ks * 16 + (ln >> 5) * 8;
        s8v pk;
#pragma unroll
        for (int j = 0; j < 8; ++j) pk[j] = (short)f2bf(gT[row * 65 + ch + j]);
        size_t off = ((((size_t)(c * 2 + rbl) * 8 + h) * 4 + ks) * 64 + ln) * 8;
        *(s8v*)(Gf + off) = pk;
    }
}

// ---------------- out = gg @ W_O (A frag-direct pinned, B LDS-shared 2 phases) ----------------
__global__ __launch_bounds__(256) void k_out(
    const u16* __restrict__ Gf, const u16* __restrict__ Wf,
    float* __restrict__ out) {
    __shared__ __align__(16) char smem[32768];
    const int t = threadIdx.x;
    const int l0 = blockIdx.x * 128;
    const int c0 = blockIdx.y * 64;
    const int wv = t >> 6;
    const int lane = t & 63;
    const int c31 = lane & 31;
    const int hi = lane >> 5;

    const int rb = blockIdx.x * 4 + wv;
    const u16* pA  = Gf + (size_t)rb * 16384 + lane * 8;
    const char* gB = (const char*)(Wf + (size_t)(64 + blockIdx.y * 2) * 16384);

    f16v acc0, acc1;
#pragma unroll
    for (int i = 0; i < 16; ++i) { acc0[i] = 0.f; acc1[i] = 0.f; }

#define STAGEB(PH)                                                             \
    { _Pragma("unroll") for (int j = 0; j < 8; ++j) {                          \
        int seg = j >> 2, q4 = j & 3;                                          \
        gld16(smem + seg * 16384 + q4 * 4096 + wv * 1024,                      \
              gB + seg * 32768 + (PH) * 16384 + q4 * 4096 + t * 16); } }
    s8v aA[4], aB[4];
#define LOADO(S, KT)                                                      \
    { _Pragma("unroll") for (int ks = 0; ks < 4; ++ks) {                  \
        a##S[ks] = *(const s8v*)(pA + (KT) * 2048 + ks * 512); } }
#define MFMAO(S, KT)                                                                        \
    { const char* bbq = smem + ((KT) & 3) * 4096;                                           \
      _Pragma("unroll") for (int ks = 0; ks < 4; ++ks) {                                    \
        s8v b0 = *(const s8v*)(bbq + ks * 1024 + lane * 16);                                \
        s8v b1 = *(const s8v*)(bbq + 16384 + ks * 1024 + lane * 16);                        \
        acc0 = __builtin_amdgcn_mfma_f32_32x32x16_bf16(a##S[ks], b0, acc0, 0, 0, 0);        \
        acc1 = __builtin_amdgcn_mfma_f32_32x32x16_bf16(a##S[ks], b1, acc1, 0, 0, 0); } }
    STAGEB(0)
    LOADO(A, 0)
    asm volatile("s_waitcnt vmcnt(0)" ::: "memory");
    __syncthreads();
    LOADO(B, 1)
    __builtin_amdgcn_sched_barrier(0);
    MFMAO(A, 0)
    LOADO(A, 2)
    __builtin_amdgcn_sched_barrier(0);
    MFMAO(B, 1)
    LOADO(B, 3)
    __builtin_amdgcn_sched_barrier(0);
    MFMAO(A, 2)
    LOADO(A, 4)
    __builtin_amdgcn_sched_barrier(0);
    MFMAO(B, 3)
    __syncthreads();
    STAGEB(1)
    asm volatile("s_waitcnt vmcnt(0)" ::: "memory");
    __syncthreads();
    LOADO(B, 5)
    __builtin_amdgcn_sched_barrier(0);
    MFMAO(A, 4)
    LOADO(A, 6)
    __builtin_amdgcn_sched_barrier(0);
    MFMAO(B, 5)
    LOADO(B, 7)
    __builtin_amdgcn_sched_barrier(0);
    MFMAO(A, 6)
    __builtin_amdgcn_sched_barrier(0);
    MFMAO(B, 7)
#undef LOADO
#undef MFMAO
#undef STAGEB

#pragma unroll
    for (int n = 0; n < 2; ++n) {
        const f16v acc = n ? acc1 : acc0;
        int C = c0 + n * 32 + c31;
#pragma unroll
        for (int r = 0; r < 16; ++r) {
            int lrow = wv * 32 + (r & 3) + 8 * (r >> 2) + 4 * hi;
            out[(size_t)(l0 + lrow) * DD + C] = acc[r];
        }
    }
}

extern "C" void kernel_launch(void* const* d_in, const int* in_sizes, int n_in,
                              void* d_out, int out_size, void* d_ws, size_t ws_size,
                              hipStream_t stream) {
    const float* X   = (const float*)d_in[0];
    const float* W_Q = (const float*)d_in[1];
    const float* W_K = (const float*)d_in[2];
    const float* W_V = (const float*)d_in[3];
    const float* W_G = (const float*)d_in[4];
    const float* W_O = (const float*)d_in[5];
    const float* gnw = (const float*)d_in[6];
    const float* gnb = (const float*)d_in[7];

    float* ws   = (float*)d_ws;
    u16* qhp  = (u16*)(ws + WS_QH);
    u16* qlp  = (u16*)(ws + WS_QL);
    u16* khp  = (u16*)(ws + WS_KH);
    u16* klp  = (u16*)(ws + WS_KL);
    u16* vtp  = (u16*)(ws + WS_VT);
    u16* xfh  = (u16*)(ws + WS_XFH);
    u16* xfl  = (u16*)(ws + WS_XFL);
    u16* wf   = (u16*)(ws + WS_WF);
    u16* gate16 = (u16*)(ws + WS_GATE);
    float* tab  = ws + WS_TAB;
    u16* ktwh = (u16*)(ws + WS_KTWH);
    u16* ktwl = (u16*)(ws + WS_KTWL);
    float* Abuf = ws + WS_XFH;         // A_state over dead Xf (2M floats)
    u16* sthp = (u16*)(ws + WS_KTWH);  // St over dead ktw
    u16* stlp = (u16*)(ws + WS_KTWL);
    u16* Gfp  = (u16*)(ws + WS_XFH);   // frag-packed gg over dead A_state
    float* out  = (float*)d_out;

    k_pre<<<2816, 256, 0, stream>>>(X, W_Q, W_K, W_V, W_G, W_O, tab, xfh, xfl, wf);
    k_fused<<<1024, 256, 0, stream>>>(xfh, xfl, wf, tab, qhp, qlp, khp, klp, vtp, gate16, ktwh, ktwl);
    k_ret1<<<dim3(64, 8), 256, 0, stream>>>(vtp, ktwh, ktwl, Abuf);
    k_scan<<<128, 256, 0, stream>>>(Abuf, sthp, stlp);
    k_ret3<<<dim3(64, 8), 256, 0, stream>>>(qhp, qlp, khp, klp, vtp, sthp, stlp,
                                            gate16, gnw, gnb, Gfp);
    k_out<<<dim3(32, 8), 256, 0, stream>>>(Gfp, wf, out);
}

// Round 10
// 66.620 us; speedup vs baseline: 2.7739x; 1.1789x over previous
//
#include <hip/hip_runtime.h>
#include <math.h>

#define LQ 4096
#define DD 512
#define NH 8
#define HS 64
#define HALF 32

typedef unsigned short u16;
typedef unsigned int u32;
typedef __attribute__((ext_vector_type(8)))  short s8v;   // 8 x bf16 (MFMA A/B frag)
typedef __attribute__((ext_vector_type(4)))  float f4v;
typedef __attribute__((ext_vector_type(4)))  u32  u32x4;
typedef __attribute__((ext_vector_type(16))) float f16v;  // 32x32 MFMA C/D

// workspace offsets (in floats)
#define WS_QH   0u
#define WS_KH   2097152u    // (QL slot now unused; kept for layout stability)
#define WS_KL   3145728u    // unused
#define WS_VT   4194304u
#define WS_XFH  5242880u    // frag-packed X (single bf16); later A_state spans XFH+XFL; later Gf
#define WS_XFL  6291456u    // (A_state tail region)
#define WS_WF   7340032u    // frag-packed W single bf16
#define WS_GATE 8650752u    // gate as bf16 (u16)
#define WS_TAB  10747904u
#define WS_KTWH 11272192u   // ktw (single); later St (single)

__device__ inline u16 f2bf(float x) {
    unsigned int u = __float_as_uint(x);
    return (u16)((u + 0x7fffu + ((u >> 16) & 1u)) >> 16);
}
__device__ inline float bf2f(u16 h) { return __uint_as_float(((unsigned int)h) << 16); }

__device__ __forceinline__ void gld16(void* lds, const void* g) {
    __builtin_amdgcn_global_load_lds(
        (const __attribute__((address_space(1))) void*)g,
        (__attribute__((address_space(3))) void*)lds, 16, 0, 0);
}

// ---------------- merged prep: xPos tables | X->frag bf16 | W->frag bf16 ----------------
__global__ __launch_bounds__(256) void k_pre(
    const float* __restrict__ X,
    const float* __restrict__ Wq, const float* __restrict__ Wk, const float* __restrict__ Wv,
    const float* __restrict__ Wg, const float* __restrict__ Wo,
    float* __restrict__ tab, u16* __restrict__ Xf, u16* __restrict__ Wf) {
    __shared__ float tile[32][33];
    const int b = blockIdx.x;
    const int t = threadIdx.x;
    if (b < 512) {
        int idx = b * 256 + t;
        if (idx >= LQ * HALF) return;
        int l = idx >> 5;
        int i = idx & 31;
        double log2sv = log2((2.0 * i + 25.6) / 89.6);
        double e = (double)l * log2sv * (1.0 / 512.0);
        float sc  = exp2f((float)e);
        float sci = exp2f((float)(-e));
        double invf = exp2((double)i * (-13.287712379549449 / 32.0));
        double th = (double)l * invf;
        double r = th - 6.283185307179586 * floor(th * 0.15915494309189535);
        float c = cosf((float)r), sn = sinf((float)r);
        tab[idx]                 = c * sc;
        tab[LQ*HALF + idx]       = sn * sc;
        tab[2*LQ*HALF + idx]     = c * sci;
        tab[3*LQ*HALF + idx]     = sn * sci;
    } else if (b < 1536) {
        // X -> fragment-packed bf16: Xf[rb:128][kt:8][ks:4][lane:64][8]
        int g = (b - 512) * 256 + t;
        int l = g >> 6;
        int d = (g & 63) * 8;
        const float* xp = X + (size_t)l * DD + d;
        f4v x0 = *(const f4v*)xp;
        f4v x1 = *(const f4v*)(xp + 4);
        s8v ph;
#pragma unroll
        for (int j = 0; j < 4; ++j) {
            ph[j]   = (short)f2bf(x0[j]);
            ph[j+4] = (short)f2bf(x1[j]);
        }
        int rb = l >> 5, kt = d >> 6, ks = (d >> 4) & 3, kh2 = (d >> 3) & 1;
        int lane = kh2 * 32 + (l & 31);
        size_t off = (((size_t)(rb * 8 + kt) * 4 + ks) * 64 + lane) * 8;
        *(s8v*)(Xf + off) = ph;
    } else {
        // weights -> fragment-packed bf16: Wf[nb:80][kt:8][ks:4][lane:64][8]
        int bb = b - 1536;
        int d0 = (bb & 15) * 32, C0 = (bb >> 4) * 32;
        int proj = C0 >> 9;
        int tc = t & 31, tr = t >> 5;
#pragma unroll
        for (int rr = 0; rr < 4; ++rr) {
            int dl = tr + rr * 8;
            int d = d0 + dl;
            int C = C0 + tc;
            float val;
            if (proj < 3) {
                const float* W = (proj == 0) ? Wq : ((proj == 1) ? Wk : Wv);
                int h = (C & 511) >> 6, hs = C & 63;
                val = W[(size_t)h * (DD * HS) + (size_t)d * HS + hs];
            } else if (proj == 3) {
                val = Wg[(size_t)d * DD + (C & 511)];
            } else {
                val = Wo[(size_t)d * DD + (C - 2048)];
            }
            tile[dl][tc] = val;
        }
        __syncthreads();
        if (t < 128) {
            int cl = t & 31, dgq = t >> 5;
            int dl = dgq * 8;
            s8v pk;
#pragma unroll
            for (int j = 0; j < 8; ++j) pk[j] = (short)f2bf(tile[dl + j][cl]);
            int C = C0 + cl;
            int da = d0 + dl;
            int nb = C >> 5, kt = da >> 6, ks = (da >> 4) & 3, kh2 = (da >> 3) & 1;
            int lane = kh2 * 32 + (C & 31);
            size_t off = (((size_t)(nb * 8 + kt) * 4 + ks) * 64 + lane) * 8;
            *(s8v*)(Wf + off) = pk;
        }
    }
}

// ---------------- fused MFMA GEMM: A frag-direct pinned, B LDS-shared (2 phases) ----------------
// grid 1024 (chunked XCD swizzle), block 256 (4 waves, each 32l x 64c). All single bf16, 8 MFMA/kt.
__global__ __launch_bounds__(256) void k_fused(
    const u16* __restrict__ Xf, const u16* __restrict__ Wf,
    const float* __restrict__ tab,
    u16* __restrict__ qh, u16* __restrict__ kh,
    u16* __restrict__ vt, u16* __restrict__ gate16,
    u16* __restrict__ ktw) {
    __shared__ __align__(16) char smem[33024];   // B stage 32KB; vbuf alias after loop
    const int t = threadIdx.x;
    const int b = blockIdx.x;
    const int mb = (b & 7) * 4 + (b >> 8);   // 0..31
    const int cb = (b >> 3) & 31;            // 0..31
    const int l0 = mb * 128;
    const int c0 = cb * 64;
    const int wv = t >> 6;
    const int lane = t & 63;
    const int c31 = lane & 31;
    const int hi = lane >> 5;

    const int rb = mb * 4 + wv;
    const u16* pA = Xf + (size_t)rb * 16384 + lane * 8;
    const char* gB = (const char*)(Wf + (size_t)(cb * 2) * 16384);

    f16v acc0, acc1;
#pragma unroll
    for (int i = 0; i < 16; ++i) { acc0[i] = 0.f; acc1[i] = 0.f; }

#define STAGEB(PH)                                                             \
    { _Pragma("unroll") for (int j = 0; j < 8; ++j) {                          \
        int seg = j >> 2, q4 = j & 3;                                          \
        gld16(smem + seg * 16384 + q4 * 4096 + wv * 1024,                      \
              gB + seg * 32768 + (PH) * 16384 + q4 * 4096 + t * 16); } }
    s8v aA[4], aB[4];
#define LOADA(S, KT)                                                      \
    { _Pragma("unroll") for (int ks = 0; ks < 4; ++ks) {                  \
        a##S[ks] = *(const s8v*)(pA + (KT) * 2048 + ks * 512); } }
#define MFMAX(S, KT)                                                                        \
    { const char* bbq = smem + ((KT) & 3) * 4096;                                           \
      _Pragma("unroll") for (int ks = 0; ks < 4; ++ks) {                                    \
        s8v b0 = *(const s8v*)(bbq + ks * 1024 + lane * 16);                                \
        s8v b1 = *(const s8v*)(bbq + 16384 + ks * 1024 + lane * 16);                        \
        acc0 = __builtin_amdgcn_mfma_f32_32x32x16_bf16(a##S[ks], b0, acc0, 0, 0, 0);        \
        acc1 = __builtin_amdgcn_mfma_f32_32x32x16_bf16(a##S[ks], b1, acc1, 0, 0, 0); } }
    STAGEB(0)
    LOADA(A, 0)
    asm volatile("s_waitcnt vmcnt(0)" ::: "memory");
    __syncthreads();
    LOADA(B, 1)
    __builtin_amdgcn_sched_barrier(0);
    MFMAX(A, 0)
    LOADA(A, 2)
    __builtin_amdgcn_sched_barrier(0);
    MFMAX(B, 1)
    LOADA(B, 3)
    __builtin_amdgcn_sched_barrier(0);
    MFMAX(A, 2)
    LOADA(A, 4)
    __builtin_amdgcn_sched_barrier(0);
    MFMAX(B, 3)
    __syncthreads();                 // all waves done reading phase-0 B
    STAGEB(1)
    asm volatile("s_waitcnt vmcnt(0)" ::: "memory");
    __syncthreads();
    LOADA(B, 5)
    __builtin_amdgcn_sched_barrier(0);
    MFMAX(A, 4)
    LOADA(A, 6)
    __builtin_amdgcn_sched_barrier(0);
    MFMAX(B, 5)
    LOADA(B, 7)
    __builtin_amdgcn_sched_barrier(0);
    MFMAX(A, 6)
    __builtin_amdgcn_sched_barrier(0);
    MFMAX(B, 7)
#undef LOADA
#undef MFMAX
#undef STAGEB
    __syncthreads();                     // B LDS dead; safe to alias vbuf below

    float* vbuf = (float*)smem;          // [64][129] f32
    const int proj = c0 >> 9;
    if (proj < 2) {
        const float* ct = tab + (proj ? 2 * LQ * HALF : 0);
        const float* st = tab + (proj ? 3 * LQ * HALF : LQ * HALF);
        u16* oh = proj ? kh : qh;
        const int hh = (c0 & 511) >> 6;
        float lgf = 0.f;
        if (proj == 1) {
            double lg = -3.4657359027997265 + (double)hh * (-2.772588722239781 / 7.0);
            lgf = (float)(log(1.0 - exp(lg)) * 1.4426950408889634);
        }
#pragma unroll
        for (int n = 0; n < 2; ++n) {
            const f16v acc = n ? acc1 : acc0;
            int C = c0 + n * 32 + c31;
            int hs = C & 63, i2 = hs >> 1;
            float sgn = (hs & 1) ? 1.f : -1.f;
#pragma unroll
            for (int r = 0; r < 16; ++r) {
                int lrow = wv * 32 + (r & 3) + 8 * (r >> 2) + 4 * hi;
                int pos = l0 + lrow;
                float val = acc[r];
                float part = __shfl_xor(val, 1);
                float res = val * ct[pos * HALF + i2] + sgn * part * st[pos * HALF + i2];
                size_t o = ((size_t)hh * LQ + pos) * HS + hs;
                oh[o] = f2bf(res);
                if (proj == 1) {
                    float wf = exp2f(lgf * (float)(64 - (pos & 63)));   // gamma^(64-m')
                    vbuf[(n * 32 + c31) * 129 + lrow] = res * wf;
                }
            }
        }
        if (proj == 1) {
            __syncthreads();
            int cl = t >> 2, lseg = (t & 3) * 32;
            size_t o = ((size_t)hh * HS + cl) * LQ + l0 + lseg;
#pragma unroll
            for (int ch4 = 0; ch4 < 4; ++ch4) {
                s8v pkh;
#pragma unroll
                for (int j = 0; j < 8; ++j) pkh[j] = (short)f2bf(vbuf[cl * 129 + lseg + ch4 * 8 + j]);
                *(s8v*)(ktw + o + ch4 * 8) = pkh;
            }
        }
    } else if (proj == 2) {
#pragma unroll
        for (int n = 0; n < 2; ++n) {
            const f16v acc = n ? acc1 : acc0;
            int cl = n * 32 + c31;
#pragma unroll
            for (int r = 0; r < 16; ++r) {
                int lrow = wv * 32 + (r & 3) + 8 * (r >> 2) + 4 * hi;
                vbuf[cl * 129 + lrow] = acc[r];
            }
        }
        __syncthreads();
        int h = (c0 & 511) >> 6;
        int cl = t >> 2, lseg = (t & 3) * 32;
        size_t o = ((size_t)h * HS + cl) * LQ + l0 + lseg;
#pragma unroll
        for (int ch = 0; ch < 4; ++ch) {
            s8v pk;
#pragma unroll
            for (int j = 0; j < 8; ++j) pk[j] = (short)f2bf(vbuf[cl * 129 + lseg + ch * 8 + j]);
            *(s8v*)(vt + o + ch * 8) = pk;
        }
    } else {
#pragma unroll
        for (int n = 0; n < 2; ++n) {
            const f16v acc = n ? acc1 : acc0;
            int C = (c0 & 511) + n * 32 + c31;
#pragma unroll
            for (int r = 0; r < 16; ++r) {
                int lrow = wv * 32 + (r & 3) + 8 * (r >> 2) + 4 * hi;
                float vv = acc[r];
                gate16[(size_t)(l0 + lrow) * DD + C] = f2bf(vv / (1.f + expf(-vv)));
            }
        }
    }
}

// ---------------- pass1: per-chunk state A^T[ch][d], 4 waves/chunk, single bf16 ----------------
__global__ __launch_bounds__(256) void k_ret1(
    const u16* __restrict__ vt, const u16* __restrict__ ktw,
    float* __restrict__ A) {
    const int t = threadIdx.x;
    const int c = blockIdx.x;
    const int h = blockIdx.y;
    const int wv = t >> 6, lane = t & 63, c31 = lane & 31, hi = lane >> 5;
    const int wch = wv >> 1, wd = wv & 1;

    s8v va[4];
    const u16* vp = vt + ((size_t)h * 64 + wch * 32 + c31) * LQ + c * 64 + hi * 8;
#pragma unroll
    for (int ks = 0; ks < 4; ++ks) va[ks] = *(const s8v*)(vp + ks * 16);

    f16v a;
#pragma unroll
    for (int i = 0; i < 16; ++i) a[i] = 0.f;

    const size_t kbase = ((size_t)h * 64 + wd * 32 + c31) * LQ + c * 64 + hi * 8;
#pragma unroll
    for (int ks = 0; ks < 4; ++ks) {
        s8v b_h = *(const s8v*)(ktw + kbase + ks * 16);
        a = __builtin_amdgcn_mfma_f32_32x32x16_bf16(va[ks], b_h, a, 0, 0, 0);
    }

    float* Ab = A + ((size_t)h * 64 + c) * 4096;
#pragma unroll
    for (int r = 0; r < 16; ++r) {
        int ch = wch * 32 + (r & 3) + 8 * (r >> 2) + 4 * hi;
        Ab[ch * 64 + wd * 32 + c31] = a[r];
    }
}

// ---------------- pass2: weighted prefix scan over chunks -> S^T single bf16 ----------------
__global__ __launch_bounds__(256) void k_scan(
    const float* __restrict__ A, u16* __restrict__ sth) {
    const int bx = blockIdx.x;
    const int h = bx >> 4;
    const int e = (bx & 15) * 256 + threadIdx.x;
    double lg = -3.4657359027997265 + (double)h * (-2.772588722239781 / 7.0);
    double gamma = 1.0 - exp(lg);
    float g64 = (float)pow(gamma, 64.0);
    const float* Ab = A + (size_t)h * 64 * 4096 + e;
    u16* shb = sth + (size_t)h * 64 * 4096 + e;
    float av[64];
#pragma unroll
    for (int cc = 0; cc < 64; ++cc) av[cc] = Ab[(size_t)cc * 4096];
    float s = 0.f;
#pragma unroll
    for (int cc = 0; cc < 64; ++cc) {
        if (cc) shb[(size_t)cc * 4096] = f2bf(s);
        s = fmaf(g64, s, av[cc]);
    }
}

// ---------------- pass3: retention chunk + fused GroupNorm*gate -> frag-packed gg ----------------
// grid (64, 8), block 256 (4 waves). wave = (ws = row strip, wc = output col half). single bf16.
__global__ __launch_bounds__(256) void k_ret3(
    const u16* __restrict__ qh, const u16* __restrict__ kh,
    const u16* __restrict__ vt, const u16* __restrict__ sth,
    const u16* __restrict__ gate16,
    const float* __restrict__ gw, const float* __restrict__ gb,
    u16* __restrict__ Gf) {
    __shared__ __align__(16) char sBuf[16640];   // KH 8K | VT 8K; later gT[64][65] f32 (16640B)
    __shared__ float stats[64][2][2];            // [row][wc][s,ss]
    const int t = threadIdx.x;
    const int c = blockIdx.x;
    const int h = blockIdx.y;
    const int wv = t >> 6, lane = t & 63, c31 = lane & 31, hi = lane >> 5;
    const int ws = wv >> 1, wc = wv & 1;
    const int l0q = c * 64;

    double lg = -3.4657359027997265 + (double)h * (-2.772588722239781 / 7.0);
    double gamma = 1.0 - exp(lg);
    float lgf = (float)(log(gamma) * 1.4426950408889634);
    float c1a[4], c8a[4];
#pragma unroll
    for (int m = 0; m < 4; ++m) { c1a[m] = exp2f(-lgf * (float)m); c8a[m] = exp2f(-lgf * (float)(8 * m)); }

    // Q fragments for this wave's row strip (single bf16)
    s8v qhf[4];
    {
        const u16* qph = qh + ((size_t)h * LQ + l0q + ws * 32 + c31) * HS + hi * 8;
#pragma unroll
        for (int ks = 0; ks < 4; ++ks) qhf[ks] = *(const s8v*)(qph + ks * 16);
    }

    // stage K + VT (pre-swizzled source, linear LDS dest), 4 x 16B per thread
    {
        const char* gKH = (const char*)kh + ((size_t)h * LQ + l0q) * 128;
        const char* gVT = (const char*)vt + ((size_t)h * 64) * 8192 + l0q * 2;
#pragma unroll
        for (int i_ = 0; i_ < 4; ++i_) {
            int boff = i_ * 4096 + t * 16;
            int seg = boff >> 13;
            int o_ = boff & 8191;
            int osrc = o_ ^ (((o_ >> 7) & 7) << 4);
            const char* src = (seg == 0) ? gKH + osrc
                            : gVT + (size_t)(osrc >> 7) * 8192 + (osrc & 127);
            gld16(sBuf + boff, src);
        }
    }

    // inter-chunk: qs = Q @ S^T for this wave's col half (single bf16)
    f16v qs;
#pragma unroll
    for (int i = 0; i < 16; ++i) qs[i] = 0.f;
    if (c > 0) {
        const u16* sbh = sth + ((size_t)h * 64 + c) * 4096;
#pragma unroll
        for (int ks = 0; ks < 4; ++ks) {
            int off = (wc * 32 + c31) * 64 + ks * 16 + hi * 8;
            s8v b_h = *(const s8v*)(sbh + off);
            qs = __builtin_amdgcn_mfma_f32_32x32x16_bf16(qhf[ks], b_h, qs, 0, 0, 0);
        }
    }

    asm volatile("s_waitcnt vmcnt(0)" ::: "memory");
    __syncthreads();

    // intra-chunk masked tile (QK^T duplicated across wc; PV split by wc)
    f16v acc;
#pragma unroll
    for (int i = 0; i < 16; ++i) acc[i] = 0.f;
    const char* bKH = sBuf;
    const char* bVT = sBuf + 8192;

#pragma unroll
    for (int jt = 0; jt < 2; ++jt) {
        if (ws == 0 && jt == 1) break;
        f16v sacc;
#pragma unroll
        for (int i = 0; i < 16; ++i) sacc[i] = 0.f;
#pragma unroll
        for (int ks = 0; ks < 4; ++ks) {
            int krow = jt * 32 + c31;
            int ph = krow * 128 + ((ks * 32 + hi * 16) ^ ((krow & 7) << 4));
            s8v ah = *(const s8v*)(bKH + ph);
            sacc = __builtin_amdgcn_mfma_f32_32x32x16_bf16(ah, qhf[ks], sacc, 0, 0, 0);
        }
        const int D0 = (ws * 32 + c31) - jt * 32;
        float base = exp2f(lgf * (float)(D0 - 4 * hi));
        u32 w[8];
#pragma unroll
        for (int g = 0; g < 4; ++g) {
            float wg = base * c8a[g];
            float v0 = sacc[4 * g + 0] * (wg * c1a[0]);
            float v1 = sacc[4 * g + 1] * (wg * c1a[1]);
            float v2 = sacc[4 * g + 2] * (wg * c1a[2]);
            float v3 = sacc[4 * g + 3] * (wg * c1a[3]);
            int jr = 8 * g + 4 * hi;
            if (D0 - (jr + 0) < 0) v0 = 0.f;
            if (D0 - (jr + 1) < 0) v1 = 0.f;
            if (D0 - (jr + 2) < 0) v2 = 0.f;
            if (D0 - (jr + 3) < 0) v3 = 0.f;
            w[2 * g]     = (u32)f2bf(v0) | ((u32)f2bf(v1) << 16);
            w[2 * g + 1] = (u32)f2bf(v2) | ((u32)f2bf(v3) << 16);
        }
        u32 e0 = __shfl_xor(hi ? w[0] : w[2], 32);
        u32 e1 = __shfl_xor(hi ? w[1] : w[3], 32);
        u32 e2 = __shfl_xor(hi ? w[4] : w[6], 32);
        u32 e3 = __shfl_xor(hi ? w[5] : w[7], 32);
        u32x4 a0v = { hi ? e0 : w[0], hi ? e1 : w[1], hi ? w[2] : e0, hi ? w[3] : e1 };
        u32x4 a1v = { hi ? e2 : w[4], hi ? e3 : w[5], hi ? w[6] : e2, hi ? w[7] : e3 };
        s8v af0 = __builtin_bit_cast(s8v, a0v);
        s8v af1 = __builtin_bit_cast(s8v, a1v);
#pragma unroll
        for (int ksl = 0; ksl < 2; ++ksl) {
            s8v af = ksl ? af1 : af0;
            int cb = (jt * 2 + ksl) * 32 + hi * 16;
            int rv = wc * 32 + c31;
            s8v vb = *(const s8v*)(bVT + rv * 128 + (cb ^ ((rv & 7) << 4)));
            acc = __builtin_amdgcn_mfma_f32_32x32x16_bf16(af, vb, acc, 0, 0, 0);
        }
    }

    // epilogue: combine inter+intra; cross-wc GroupNorm stats via LDS; *gate; frag-pack gg
    float vv[16];
#pragma unroll
    for (int r = 0; r < 16; ++r) {
        int row = (r & 3) + 8 * (r >> 2) + 4 * hi;
        int nloc = ws * 32 + row;
        float sc = exp2f(lgf * (float)nloc);
        vv[r] = acc[r] + sc * qs[r];
    }
#pragma unroll
    for (int r = 0; r < 16; ++r) {
        float s = vv[r], ss = vv[r] * vv[r];
#pragma unroll
        for (int off = 1; off < 32; off <<= 1) {
            s  += __shfl_xor(s, off);
            ss += __shfl_xor(ss, off);
        }
        if (c31 == 0) {
            int nloc = ws * 32 + (r & 3) + 8 * (r >> 2) + 4 * hi;
            stats[nloc][wc][0] = s;
            stats[nloc][wc][1] = ss;
        }
    }
    __syncthreads();   // stats ready; all sBuf (K/V) reads also done -> safe to alias gT

    float* gT = (float*)sBuf;           // [64][65] f32 = 16640B
    const float gwv = gw[h * HS + wc * 32 + c31];
    const float gbv = gb[h * HS + wc * 32 + c31];
#pragma unroll
    for (int r = 0; r < 16; ++r) {
        int nloc = ws * 32 + (r & 3) + 8 * (r >> 2) + 4 * hi;
        float s  = stats[nloc][0][0] + stats[nloc][1][0];
        float ss = stats[nloc][0][1] + stats[nloc][1][1];
        float mean = s * (1.f / 64.f);
        float var = ss * (1.f / 64.f) - mean * mean;
        float inv = rsqrtf(var + 1e-5f);
        size_t o = (size_t)(l0q + nloc) * DD + h * HS + wc * 32 + c31;
        float g = ((vv[r] - mean) * inv * gwv + gbv) * bf2f(gate16[o]);
        gT[nloc * 65 + wc * 32 + c31] = g;
    }
    __syncthreads();
#pragma unroll
    for (int i = 0; i < 2; ++i) {
        int u = t + i * 256;            // 0..511
        int rbl = u >> 8;
        int ks = (u >> 6) & 3;
        int ln = u & 63;
        int row = rbl * 32 + (ln & 31);
        int ch = ks * 16 + (ln >> 5) * 8;
        s8v pk;
#pragma unroll
        for (int j = 0; j < 8; ++j) pk[j] = (short)f2bf(gT[row * 65 + ch + j]);
        size_t off = ((((size_t)(c * 2 + rbl) * 8 + h) * 4 + ks) * 64 + ln) * 8;
        *(s8v*)(Gf + off) = pk;
    }
}

// ---------------- out = gg @ W_O (A frag-direct pinned, B LDS-shared 2 phases) ----------------
__global__ __launch_bounds__(256) void k_out(
    const u16* __restrict__ Gf, const u16* __restrict__ Wf,
    float* __restrict__ out) {
    __shared__ __align__(16) char smem[32768];
    const int t = threadIdx.x;
    const int l0 = blockIdx.x * 128;
    const int c0 = blockIdx.y * 64;
    const int wv = t >> 6;
    const int lane = t & 63;
    const int c31 = lane & 31;
    const int hi = lane >> 5;

    const int rb = blockIdx.x * 4 + wv;
    const u16* pA  = Gf + (size_t)rb * 16384 + lane * 8;
    const char* gB = (const char*)(Wf + (size_t)(64 + blockIdx.y * 2) * 16384);

    f16v acc0, acc1;
#pragma unroll
    for (int i = 0; i < 16; ++i) { acc0[i] = 0.f; acc1[i] = 0.f; }

#define STAGEB(PH)                                                             \
    { _Pragma("unroll") for (int j = 0; j < 8; ++j) {                          \
        int seg = j >> 2, q4 = j & 3;                                          \
        gld16(smem + seg * 16384 + q4 * 4096 + wv * 1024,                      \
              gB + seg * 32768 + (PH) * 16384 + q4 * 4096 + t * 16); } }
    s8v aA[4], aB[4];
#define LOADO(S, KT)                                                      \
    { _Pragma("unroll") for (int ks = 0; ks < 4; ++ks) {                  \
        a##S[ks] = *(const s8v*)(pA + (KT) * 2048 + ks * 512); } }
#define MFMAO(S, KT)                                                                        \
    { const char* bbq = smem + ((KT) & 3) * 4096;                                           \
      _Pragma("unroll") for (int ks = 0; ks < 4; ++ks) {                                    \
        s8v b0 = *(const s8v*)(bbq + ks * 1024 + lane * 16);                                \
        s8v b1 = *(const s8v*)(bbq + 16384 + ks * 1024 + lane * 16);                        \
        acc0 = __builtin_amdgcn_mfma_f32_32x32x16_bf16(a##S[ks], b0, acc0, 0, 0, 0);        \
        acc1 = __builtin_amdgcn_mfma_f32_32x32x16_bf16(a##S[ks], b1, acc1, 0, 0, 0); } }
    STAGEB(0)
    LOADO(A, 0)
    asm volatile("s_waitcnt vmcnt(0)" ::: "memory");
    __syncthreads();
    LOADO(B, 1)
    __builtin_amdgcn_sched_barrier(0);
    MFMAO(A, 0)
    LOADO(A, 2)
    __builtin_amdgcn_sched_barrier(0);
    MFMAO(B, 1)
    LOADO(B, 3)
    __builtin_amdgcn_sched_barrier(0);
    MFMAO(A, 2)
    LOADO(A, 4)
    __builtin_amdgcn_sched_barrier(0);
    MFMAO(B, 3)
    __syncthreads();
    STAGEB(1)
    asm volatile("s_waitcnt vmcnt(0)" ::: "memory");
    __syncthreads();
    LOADO(B, 5)
    __builtin_amdgcn_sched_barrier(0);
    MFMAO(A, 4)
    LOADO(A, 6)
    __builtin_amdgcn_sched_barrier(0);
    MFMAO(B, 5)
    LOADO(B, 7)
    __builtin_amdgcn_sched_barrier(0);
    MFMAO(A, 6)
    __builtin_amdgcn_sched_barrier(0);
    MFMAO(B, 7)
#undef LOADO
#undef MFMAO
#undef STAGEB

#pragma unroll
    for (int n = 0; n < 2; ++n) {
        const f16v acc = n ? acc1 : acc0;
        int C = c0 + n * 32 + c31;
#pragma unroll
        for (int r = 0; r < 16; ++r) {
            int lrow = wv * 32 + (r & 3) + 8 * (r >> 2) + 4 * hi;
            out[(size_t)(l0 + lrow) * DD + C] = acc[r];
        }
    }
}

extern "C" void kernel_launch(void* const* d_in, const int* in_sizes, int n_in,
                              void* d_out, int out_size, void* d_ws, size_t ws_size,
                              hipStream_t stream) {
    const float* X   = (const float*)d_in[0];
    const float* W_Q = (const float*)d_in[1];
    const float* W_K = (const float*)d_in[2];
    const float* W_V = (const float*)d_in[3];
    const float* W_G = (const float*)d_in[4];
    const float* W_O = (const float*)d_in[5];
    const float* gnw = (const float*)d_in[6];
    const float* gnb = (const float*)d_in[7];

    float* ws   = (float*)d_ws;
    u16* qhp  = (u16*)(ws + WS_QH);
    u16* khp  = (u16*)(ws + WS_KH);
    u16* vtp  = (u16*)(ws + WS_VT);
    u16* xfp  = (u16*)(ws + WS_XFH);
    u16* wf   = (u16*)(ws + WS_WF);
    u16* gate16 = (u16*)(ws + WS_GATE);
    float* tab  = ws + WS_TAB;
    u16* ktwp = (u16*)(ws + WS_KTWH);
    float* Abuf = ws + WS_XFH;         // A_state over dead Xf (2M floats, spans XFH+XFL)
    u16* sthp = (u16*)(ws + WS_KTWH);  // St over dead ktw
    u16* Gfp  = (u16*)(ws + WS_XFH);   // frag-packed gg over dead A_state
    float* out  = (float*)d_out;

    k_pre<<<2816, 256, 0, stream>>>(X, W_Q, W_K, W_V, W_G, W_O, tab, xfp, wf);
    k_fused<<<1024, 256, 0, stream>>>(xfp, wf, tab, qhp, khp, vtp, gate16, ktwp);
    k_ret1<<<dim3(64, 8), 256, 0, stream>>>(vtp, ktwp, Abuf);
    k_scan<<<128, 256, 0, stream>>>(Abuf, sthp);
    k_ret3<<<dim3(64, 8), 256, 0, stream>>>(qhp, khp, vtp, sthp, gate16, gnw, gnb, Gfp);
    k_out<<<dim3(32, 8), 256, 0, stream>>>(Gfp, wf, out);
}